// Round 1
// baseline (1259.912 us; speedup 1.0000x reference)
//
#include <hip/hip_runtime.h>

#define N_ATOMS  80000
#define N_BLOCKS 16000
#define N_EDGES  320000
#define N_GRAPHS 128
#define HS       128

typedef unsigned short ushortT;
typedef __attribute__((ext_vector_type(8))) __bf16 bf16x8;
typedef __attribute__((ext_vector_type(8))) unsigned short ushort8;
typedef __attribute__((ext_vector_type(4))) float f32x4;

__device__ __forceinline__ unsigned short f2bf(float f){
  unsigned int u = __builtin_bit_cast(unsigned int, f);
  u = (u + 0x7FFFu + ((u >> 16) & 1u)) >> 16;
  return (unsigned short)u;
}
__device__ __forceinline__ bf16x8 load8bf(const ushortT* p){
  uint4 u = *reinterpret_cast<const uint4*>(p);
  return __builtin_bit_cast(bf16x8, u);
}
__device__ __forceinline__ bf16x8 load8f_bf(const float* p){
  float4 a = *reinterpret_cast<const float4*>(p);
  float4 b = *reinterpret_cast<const float4*>(p + 4);
  ushort8 u = { f2bf(a.x), f2bf(a.y), f2bf(a.z), f2bf(a.w),
                f2bf(b.x), f2bf(b.y), f2bf(b.z), f2bf(b.w) };
  return __builtin_bit_cast(bf16x8, u);
}
__device__ __forceinline__ float silu(float v){ return v / (1.f + __expf(-v)); }

// ---- weight transpose + bf16 convert: src [L][K][N] f32 -> dst [L][N][Kpad] bf16 (zero-pad k>=K)
__global__ void transpose_cvt_kernel(const float* __restrict__ src, ushortT* __restrict__ dst,
                                     int K, int N, int Kpad, int L){
  int idx = blockIdx.x * 256 + threadIdx.x;
  int tot = L * N * Kpad;
  if (idx >= tot) return;
  int k = idx % Kpad;
  int rem = idx / Kpad;
  int n = rem % N;
  int l = rem / N;
  float v = (k < K) ? src[((size_t)l * K + k) * N + n] : 0.f;
  dst[idx] = f2bf(v);
}

// ---- block segment starts via binary search (block_id sorted)
__global__ void block_start_kernel(const int* __restrict__ bid, int* __restrict__ start){
  int b = blockIdx.x * 256 + threadIdx.x;
  if (b > N_BLOCKS) return;
  int lo = 0, hi = N_ATOMS;
  while (lo < hi){ int mid = (lo + hi) >> 1; if (bid[mid] < b) lo = mid + 1; else hi = mid; }
  start[b] = lo;
}

__global__ void edge_count_kernel(const int* __restrict__ rows, int* __restrict__ cnt){
  int e = blockIdx.x * 256 + threadIdx.x;
  if (e < N_EDGES) atomicAdd(&cnt[rows[e]], 1);
}

// ---- atom -> block pooling (seg mean). Hm f32 to d_out, x f32 to ws.
__global__ void pool_kernel(const float* __restrict__ H, const float* __restrict__ Z,
                            const int* __restrict__ start,
                            float* __restrict__ Hm, float* __restrict__ x){
  int b = blockIdx.x;
  int t = threadIdx.x;            // 128 threads
  int s = start[b], e = start[b + 1];
  float inv = 1.f / (float)((e - s) > 0 ? (e - s) : 1);
  float sum = 0.f;
  for (int a = s; a < e; a++) sum += H[(size_t)a * HS + t];
  Hm[(size_t)b * HS + t] = sum * inv;
  if (t < 3){
    float sz = 0.f;
    for (int a = s; a < e; a++) sz += Z[a * 3 + t];
    x[b * 3 + t] = sz * inv;
  }
}

// ---- generic MFMA GEMM: C[M x 128] = act(A[M x K] @ Wt^T + bias) (+resid)
// A f32 (row stride 128; if K==256, second half from A2), Wt bf16 [128][K]
__global__ __launch_bounds__(256) void gemm_kernel(
    const float* __restrict__ A, const float* __restrict__ A2,
    const ushortT* __restrict__ Wt, const float* __restrict__ bias,
    const float* __restrict__ resid, float* __restrict__ Cf, ushortT* __restrict__ Cbf,
    int K, int act){
  int t = threadIdx.x; int lane = t & 63; int wv = t >> 6;
  int l15 = lane & 15, lg = lane >> 4;
  int base = blockIdx.x * 64 + wv * 16;
  f32x4 zero = {0.f, 0.f, 0.f, 0.f};
  f32x4 acc[8];
#pragma unroll
  for (int n = 0; n < 8; n++) acc[n] = zero;
  int row = base + l15;
  int nks = K >> 5;
  for (int ks = 0; ks < nks; ks++){
    int k0 = ks * 32 + lg * 8;
    const float* ap = (A2 && k0 >= 128) ? (A2 + (size_t)row * HS + (k0 - 128))
                                        : (A  + (size_t)row * HS + k0);
    bf16x8 af = load8f_bf(ap);
#pragma unroll
    for (int n = 0; n < 8; n++){
      bf16x8 bf = load8bf(Wt + (size_t)(16 * n + l15) * K + k0);
      acc[n] = __builtin_amdgcn_mfma_f32_16x16x32_bf16(af, bf, acc[n], 0, 0, 0);
    }
  }
#pragma unroll
  for (int n = 0; n < 8; n++){
    int col = 16 * n + l15;
    float bv = bias[col];
#pragma unroll
    for (int r = 0; r < 4; r++){
      int ro = base + lg * 4 + r;
      float v = acc[n][r] + bv;
      if (act) v = silu(v);
      if (resid) v += resid[(size_t)ro * HS + col];
      Cf[(size_t)ro * HS + col] = v;
      if (Cbf) Cbf[(size_t)ro * HS + col] = f2bf(v);
    }
  }
}

// ---- the fused edge kernel: 64 edges per workgroup, 4 waves, full edge MLP + scatters
__global__ __launch_bounds__(256) void edge_kernel(
    const int* __restrict__ edges, const float* __restrict__ edge_attr,
    const float* __restrict__ x, const ushortT* __restrict__ hbf,
    const ushortT* __restrict__ W1t, const ushortT* __restrict__ W2t,
    const ushortT* __restrict__ CW1t,
    const float* __restrict__ b1, const float* __restrict__ b2,
    const float* __restrict__ cb1, const float* __restrict__ cw3,
    float* __restrict__ xacc, float* __restrict__ agg){
  __shared__ int    rid[64], cid[64];
  __shared__ float  dif[64][3];
  __shared__ float  radsh[64];
  __shared__ ushortT Atail[64][32];
  __shared__ ushortT S1[64 * 128];
  __shared__ ushortT S2[64 * 128];
  __shared__ float  wsh[64];

  const int t = threadIdx.x;
  const int lane = t & 63;
  const int wv = t >> 6;
  const int tile = blockIdx.x * 64;
  const int l15 = lane & 15, lg = lane >> 4;
  const int m16 = wv * 16;

  if (t < 64){
    int e = tile + t;
    int r = edges[e], c = edges[N_EDGES + e];
    rid[t] = r; cid[t] = c;
    float dx = x[r * 3 + 0] - x[c * 3 + 0];
    float dy = x[r * 3 + 1] - x[c * 3 + 1];
    float dz = x[r * 3 + 2] - x[c * 3 + 2];
    dif[t][0] = dx; dif[t][1] = dy; dif[t][2] = dz;
    radsh[t] = dx * dx + dy * dy + dz * dz;
  }
  __syncthreads();
  for (int i = t; i < 64 * 32; i += 256){
    int e = i >> 5, k = i & 31;
    float v = (k == 0) ? radsh[e] : (k <= 16 ? edge_attr[(size_t)(tile + e) * 16 + (k - 1)] : 0.f);
    Atail[e][k] = f2bf(v);
  }
  __syncthreads();

  f32x4 zero = {0.f, 0.f, 0.f, 0.f};
  f32x4 acc[8];
#pragma unroll
  for (int n = 0; n < 8; n++) acc[n] = zero;

  // ---- GEMM1: e_in [64x288] @ W1t^T -> m1 [64x128]
  {
    int ra = rid[m16 + l15], ca = cid[m16 + l15];
#pragma unroll
    for (int ks = 0; ks < 4; ks++){
      int k0 = ks * 32 + lg * 8;
      bf16x8 af = load8bf(hbf + (size_t)ra * HS + k0);
#pragma unroll
      for (int n = 0; n < 8; n++){
        bf16x8 bf = load8bf(W1t + (size_t)(16 * n + l15) * 288 + k0);
        acc[n] = __builtin_amdgcn_mfma_f32_16x16x32_bf16(af, bf, acc[n], 0, 0, 0);
      }
    }
#pragma unroll
    for (int ks = 0; ks < 4; ks++){
      int k0 = ks * 32 + lg * 8;
      bf16x8 af = load8bf(hbf + (size_t)ca * HS + k0);
#pragma unroll
      for (int n = 0; n < 8; n++){
        bf16x8 bf = load8bf(W1t + (size_t)(16 * n + l15) * 288 + 128 + k0);
        acc[n] = __builtin_amdgcn_mfma_f32_16x16x32_bf16(af, bf, acc[n], 0, 0, 0);
      }
    }
    {
      bf16x8 af = load8bf(&Atail[m16 + l15][lg * 8]);
      int k0 = 256 + lg * 8;
#pragma unroll
      for (int n = 0; n < 8; n++){
        bf16x8 bf = load8bf(W1t + (size_t)(16 * n + l15) * 288 + k0);
        acc[n] = __builtin_amdgcn_mfma_f32_16x16x32_bf16(af, bf, acc[n], 0, 0, 0);
      }
    }
  }
  // epilogue 1 -> S1 (silu, bf16, XOR-swizzled rows)
#pragma unroll
  for (int n = 0; n < 8; n++){
    int col = 16 * n + l15;
    float bv = b1[col];
#pragma unroll
    for (int r = 0; r < 4; r++){
      int er = m16 + lg * 4 + r;
      float v = silu(acc[n][r] + bv);
      S1[(er * 128 + col) ^ ((er & 7) << 3)] = f2bf(v);
    }
  }
  __syncthreads();

  // ---- GEMM2: m = silu(S1 @ W2t^T + b2)
#pragma unroll
  for (int n = 0; n < 8; n++) acc[n] = zero;
#pragma unroll
  for (int ks = 0; ks < 4; ks++){
    int k0 = ks * 32 + lg * 8;
    int er = m16 + l15;
    bf16x8 af = load8bf(&S1[(er * 128 + k0) ^ ((er & 7) << 3)]);
#pragma unroll
    for (int n = 0; n < 8; n++){
      bf16x8 bf = load8bf(W2t + (size_t)(16 * n + l15) * 128 + k0);
      acc[n] = __builtin_amdgcn_mfma_f32_16x16x32_bf16(af, bf, acc[n], 0, 0, 0);
    }
  }
  // epilogue 2: write S2 + atomic agg
#pragma unroll
  for (int n = 0; n < 8; n++){
    int col = 16 * n + l15;
    float bv = b2[col];
#pragma unroll
    for (int r = 0; r < 4; r++){
      int er = m16 + lg * 4 + r;
      float v = silu(acc[n][r] + bv);
      S2[(er * 128 + col) ^ ((er & 7) << 3)] = f2bf(v);
      atomicAdd(&agg[(size_t)rid[er] * HS + col], v);
    }
  }
  __syncthreads();

  // ---- coord GEMM: w = silu(S2 @ CW1t^T + cb1) . cw3
#pragma unroll
  for (int n = 0; n < 8; n++) acc[n] = zero;
#pragma unroll
  for (int ks = 0; ks < 4; ks++){
    int k0 = ks * 32 + lg * 8;
    int er = m16 + l15;
    bf16x8 af = load8bf(&S2[(er * 128 + k0) ^ ((er & 7) << 3)]);
#pragma unroll
    for (int n = 0; n < 8; n++){
      bf16x8 bf = load8bf(CW1t + (size_t)(16 * n + l15) * 128 + k0);
      acc[n] = __builtin_amdgcn_mfma_f32_16x16x32_bf16(af, bf, acc[n], 0, 0, 0);
    }
  }
  {
    float rp[4] = {0.f, 0.f, 0.f, 0.f};
#pragma unroll
    for (int n = 0; n < 8; n++){
      int col = 16 * n + l15;
      float bv = cb1[col];
      float c3 = cw3[col];
#pragma unroll
      for (int r = 0; r < 4; r++){
        rp[r] += silu(acc[n][r] + bv) * c3;
      }
    }
#pragma unroll
    for (int off = 1; off < 16; off <<= 1){
#pragma unroll
      for (int r = 0; r < 4; r++) rp[r] += __shfl_xor(rp[r], off, 64);
    }
    if (l15 == 0){
#pragma unroll
      for (int r = 0; r < 4; r++) wsh[m16 + lg * 4 + r] = rp[r];
    }
  }
  __syncthreads();

  // ---- coordinate scatter
  if (t < 192){
    int e = t / 3, c2 = t % 3;
    atomicAdd(&xacc[(size_t)rid[e] * 3 + c2], dif[e][c2] * wsh[e]);
  }
}

__global__ void x_update_kernel(float* __restrict__ x, const float* __restrict__ xacc,
                                const int* __restrict__ cnt){
  int i = blockIdx.x * 256 + threadIdx.x;
  if (i < N_BLOCKS * 3){
    int b = i / 3;
    int c = cnt[b];
    x[i] += xacc[i] / (float)(c > 0 ? c : 1);
  }
}

// ---- block normalize + graph accumulate
__global__ void norm_block_kernel(const float* __restrict__ hin, const int* __restrict__ batch_id,
                                  float* __restrict__ brep, float* __restrict__ gsum){
  int wv = threadIdx.x >> 6, lane = threadIdx.x & 63;
  int b = blockIdx.x * 4 + wv;
  if (b >= N_BLOCKS) return;
  float v0 = hin[(size_t)b * HS + lane];
  float v1 = hin[(size_t)b * HS + 64 + lane];
  float ss = v0 * v0 + v1 * v1;
#pragma unroll
  for (int o = 1; o < 64; o <<= 1) ss += __shfl_xor(ss, o, 64);
  float s = 1.f / fmaxf(sqrtf(ss), 1e-12f);
  v0 *= s; v1 *= s;
  brep[(size_t)b * HS + lane] = v0;
  brep[(size_t)b * HS + 64 + lane] = v1;
  int g = batch_id[b];
  atomicAdd(&gsum[g * HS + lane], v0);
  atomicAdd(&gsum[g * HS + 64 + lane], v1);
}

__global__ void norm_graph_kernel(const float* __restrict__ gsum, float* __restrict__ grep){
  int wv = threadIdx.x >> 6, lane = threadIdx.x & 63;
  int g = blockIdx.x * 4 + wv;
  if (g >= N_GRAPHS) return;
  float v0 = gsum[g * HS + lane];
  float v1 = gsum[g * HS + 64 + lane];
  float ss = v0 * v0 + v1 * v1;
#pragma unroll
  for (int o = 1; o < 64; o <<= 1) ss += __shfl_xor(ss, o, 64);
  float s = 1.f / fmaxf(sqrtf(ss), 1e-12f);
  grep[(size_t)g * HS + lane] = v0 * s;
  grep[(size_t)g * HS + 64 + lane] = v1 * s;
}

extern "C" void kernel_launch(void* const* d_in, const int* in_sizes, int n_in,
                              void* d_out, int out_size, void* d_ws, size_t ws_size,
                              hipStream_t stream){
  const float* H         = (const float*)d_in[0];
  const float* Z         = (const float*)d_in[1];
  const int*   block_id  = (const int*)d_in[2];
  const int*   batch_id  = (const int*)d_in[3];
  const int*   edges     = (const int*)d_in[4];
  const float* edge_attr = (const float*)d_in[5];
  const float* emb_in_w  = (const float*)d_in[6];
  const float* emb_in_b  = (const float*)d_in[7];
  const float* emb_out_w = (const float*)d_in[8];
  const float* emb_out_b = (const float*)d_in[9];
  const float* edge_w1   = (const float*)d_in[10];
  const float* edge_b1   = (const float*)d_in[11];
  const float* edge_w2   = (const float*)d_in[12];
  const float* edge_b2   = (const float*)d_in[13];
  const float* node_w1   = (const float*)d_in[14];
  const float* node_b1   = (const float*)d_in[15];
  const float* node_w2   = (const float*)d_in[16];
  const float* node_b2   = (const float*)d_in[17];
  const float* coord_w1  = (const float*)d_in[18];
  const float* coord_b1  = (const float*)d_in[19];
  const float* coord_w3  = (const float*)d_in[20];

  float* out  = (float*)d_out;
  float* Hm   = out;                          // [16000 x 128]
  float* brep = out + (size_t)N_BLOCKS * HS;  // [16000 x 128]
  float* grep = out + (size_t)2 * N_BLOCKS * HS; // [128 x 128]

  char* base = (char*)d_ws;
  size_t off = 0;
  auto take = [&](size_t bytes) -> char* {
    char* p = base + off;
    off += (bytes + 255) & ~(size_t)255;
    return p;
  };
  float*   x     = (float*)  take((size_t)N_BLOCKS * 3 * 4);
  float*   xacc  = (float*)  take((size_t)N_BLOCKS * 3 * 4);
  float*   h     = (float*)  take((size_t)N_BLOCKS * HS * 4);
  ushortT* hbf   = (ushortT*)take((size_t)N_BLOCKS * HS * 2);
  float*   agg   = (float*)  take((size_t)N_BLOCKS * HS * 4);
  float*   T1    = (float*)  take((size_t)N_BLOCKS * HS * 4);
  float*   gsum  = (float*)  take((size_t)N_GRAPHS * HS * 4);
  int*     bstart= (int*)    take((size_t)(N_BLOCKS + 1) * 4);
  int*     cnt   = (int*)    take((size_t)N_BLOCKS * 4);
  ushortT* W1t   = (ushortT*)take((size_t)3 * 128 * 288 * 2);
  ushortT* W2t   = (ushortT*)take((size_t)3 * 128 * 128 * 2);
  ushortT* CW1t  = (ushortT*)take((size_t)3 * 128 * 128 * 2);
  ushortT* NW1t  = (ushortT*)take((size_t)3 * 128 * 256 * 2);
  ushortT* NW2t  = (ushortT*)take((size_t)3 * 128 * 128 * 2);
  ushortT* Eint  = (ushortT*)take((size_t)128 * 128 * 2);
  ushortT* Eoutt = (ushortT*)take((size_t)128 * 128 * 2);

  // weight prep
  transpose_cvt_kernel<<<(3 * 128 * 288 + 255) / 256, 256, 0, stream>>>(edge_w1, W1t, 273, 128, 288, 3);
  transpose_cvt_kernel<<<(3 * 128 * 128 + 255) / 256, 256, 0, stream>>>(edge_w2, W2t, 128, 128, 128, 3);
  transpose_cvt_kernel<<<(3 * 128 * 128 + 255) / 256, 256, 0, stream>>>(coord_w1, CW1t, 128, 128, 128, 3);
  transpose_cvt_kernel<<<(3 * 128 * 256 + 255) / 256, 256, 0, stream>>>(node_w1, NW1t, 256, 128, 256, 3);
  transpose_cvt_kernel<<<(3 * 128 * 128 + 255) / 256, 256, 0, stream>>>(node_w2, NW2t, 128, 128, 128, 3);
  transpose_cvt_kernel<<<(128 * 128 + 255) / 256, 256, 0, stream>>>(emb_in_w, Eint, 128, 128, 128, 1);
  transpose_cvt_kernel<<<(128 * 128 + 255) / 256, 256, 0, stream>>>(emb_out_w, Eoutt, 128, 128, 128, 1);

  block_start_kernel<<<(N_BLOCKS + 1 + 255) / 256, 256, 0, stream>>>(block_id, bstart);
  hipMemsetAsync(cnt, 0, (size_t)N_BLOCKS * 4, stream);
  edge_count_kernel<<<N_EDGES / 256, 256, 0, stream>>>(edges, cnt);

  pool_kernel<<<N_BLOCKS, 128, 0, stream>>>(H, Z, bstart, Hm, x);

  // h = Hm @ emb_in_w + b
  gemm_kernel<<<N_BLOCKS / 64, 256, 0, stream>>>(Hm, nullptr, Eint, emb_in_b, nullptr, h, hbf, 128, 0);

  for (int l = 0; l < 3; l++){
    hipMemsetAsync(agg, 0, (size_t)N_BLOCKS * HS * 4, stream);
    hipMemsetAsync(xacc, 0, (size_t)N_BLOCKS * 3 * 4, stream);
    edge_kernel<<<N_EDGES / 64, 256, 0, stream>>>(
        edges, edge_attr, x, hbf,
        W1t + (size_t)l * 128 * 288, W2t + (size_t)l * 128 * 128, CW1t + (size_t)l * 128 * 128,
        edge_b1 + l * 128, edge_b2 + l * 128, coord_b1 + l * 128, coord_w3 + l * 128,
        xacc, agg);
    x_update_kernel<<<(N_BLOCKS * 3 + 255) / 256, 256, 0, stream>>>(x, xacc, cnt);
    // node MLP: T1 = silu([h|agg] @ nw1 + nb1);  h = h + (T1 @ nw2 + nb2)
    gemm_kernel<<<N_BLOCKS / 64, 256, 0, stream>>>(h, agg, NW1t + (size_t)l * 128 * 256,
                                                   node_b1 + l * 128, nullptr, T1, nullptr, 256, 1);
    gemm_kernel<<<N_BLOCKS / 64, 256, 0, stream>>>(T1, nullptr, NW2t + (size_t)l * 128 * 128,
                                                   node_b2 + l * 128, h, h, hbf, 128, 0);
  }

  // h_final = h @ emb_out_w + b  -> T1
  gemm_kernel<<<N_BLOCKS / 64, 256, 0, stream>>>(h, nullptr, Eoutt, emb_out_b, nullptr, T1, nullptr, 128, 0);

  hipMemsetAsync(gsum, 0, (size_t)N_GRAPHS * HS * 4, stream);
  norm_block_kernel<<<N_BLOCKS / 4, 256, 0, stream>>>(T1, batch_id, brep, gsum);
  norm_graph_kernel<<<N_GRAPHS / 4, 256, 0, stream>>>(gsum, grep);
}

// Round 2
// 1045.952 us; speedup vs baseline: 1.2046x; 1.2046x over previous
//
#include <hip/hip_runtime.h>

#define N_ATOMS  80000
#define N_BLOCKS 16000
#define N_EDGES  320000
#define N_GRAPHS 128
#define HS       128

typedef unsigned short ushortT;
typedef __attribute__((ext_vector_type(8))) __bf16 bf16x8;
typedef __attribute__((ext_vector_type(8))) unsigned short ushort8;
typedef __attribute__((ext_vector_type(4))) float f32x4;

__device__ __forceinline__ unsigned short f2bf(float f){
  unsigned int u = __builtin_bit_cast(unsigned int, f);
  u = (u + 0x7FFFu + ((u >> 16) & 1u)) >> 16;
  return (unsigned short)u;
}
__device__ __forceinline__ float bf2f(ushortT u){
  unsigned int v = ((unsigned int)u) << 16;
  return __builtin_bit_cast(float, v);
}
__device__ __forceinline__ bf16x8 load8bf(const ushortT* p){
  uint4 u = *reinterpret_cast<const uint4*>(p);
  return __builtin_bit_cast(bf16x8, u);
}
__device__ __forceinline__ bf16x8 load8f_bf(const float* p){
  float4 a = *reinterpret_cast<const float4*>(p);
  float4 b = *reinterpret_cast<const float4*>(p + 4);
  ushort8 u = { f2bf(a.x), f2bf(a.y), f2bf(a.z), f2bf(a.w),
                f2bf(b.x), f2bf(b.y), f2bf(b.z), f2bf(b.w) };
  return __builtin_bit_cast(bf16x8, u);
}
__device__ __forceinline__ float silu(float v){ return v / (1.f + __expf(-v)); }

// ---- weight transpose + bf16 convert: src [L][K][N] f32 -> dst [L][N][Kpad] bf16 (zero-pad k>=K)
__global__ void transpose_cvt_kernel(const float* __restrict__ src, ushortT* __restrict__ dst,
                                     int K, int N, int Kpad, int L){
  int idx = blockIdx.x * 256 + threadIdx.x;
  int tot = L * N * Kpad;
  if (idx >= tot) return;
  int k = idx % Kpad;
  int rem = idx / Kpad;
  int n = rem % N;
  int l = rem / N;
  float v = (k < K) ? src[((size_t)l * K + k) * N + n] : 0.f;
  dst[idx] = f2bf(v);
}

// ---- block segment starts via binary search (block_id sorted)
__global__ void block_start_kernel(const int* __restrict__ bid, int* __restrict__ start){
  int b = blockIdx.x * 256 + threadIdx.x;
  if (b > N_BLOCKS) return;
  int lo = 0, hi = N_ATOMS;
  while (lo < hi){ int mid = (lo + hi) >> 1; if (bid[mid] < b) lo = mid + 1; else hi = mid; }
  start[b] = lo;
}

// ---- edge counting-sort by row: histogram
__global__ void hist_kernel(const int* __restrict__ edges, int* __restrict__ hist){
  int e = blockIdx.x * 256 + threadIdx.x;
  if (e < N_EDGES) atomicAdd(&hist[edges[e]], 1);
}

// ---- exclusive prefix scan over hist[N_BLOCKS] -> estart[N_BLOCKS+1], single block
__global__ void scan_kernel(const int* __restrict__ hist, int* __restrict__ estart){
  __shared__ int ps[256];
  int t = threadIdx.x;
  const int chunk = (N_BLOCKS + 255) / 256;
  int lo = t * chunk, hi = lo + chunk;
  if (hi > N_BLOCKS) hi = N_BLOCKS;
  int s = 0;
  for (int i = lo; i < hi; i++) s += hist[i];
  ps[t] = s;
  __syncthreads();
  for (int off = 1; off < 256; off <<= 1){
    int v = (t >= off) ? ps[t - off] : 0;
    __syncthreads();
    ps[t] += v;
    __syncthreads();
  }
  int base = (t == 0) ? 0 : ps[t - 1];
  for (int i = lo; i < hi; i++){ estart[i] = base; base += hist[i]; }
  if (t == 255) estart[N_BLOCKS] = base;
}

// ---- scatter into sorted order + gather edge_attr as bf16
__global__ void scatter_kernel(const int* __restrict__ edges, const float* __restrict__ attr,
                               int* __restrict__ ecur,
                               int* __restrict__ srow, int* __restrict__ scol,
                               ushortT* __restrict__ sattr){
  int e = blockIdx.x * 256 + threadIdx.x;
  if (e >= N_EDGES) return;
  int r = edges[e], c = edges[N_EDGES + e];
  int p = atomicAdd(&ecur[r], 1);
  srow[p] = r; scol[p] = c;
#pragma unroll
  for (int k = 0; k < 16; k++) sattr[(size_t)p * 16 + k] = f2bf(attr[(size_t)e * 16 + k]);
}

// ---- atom -> block pooling (seg mean). Hm f32 to d_out, x f32 to ws.
__global__ void pool_kernel(const float* __restrict__ H, const float* __restrict__ Z,
                            const int* __restrict__ start,
                            float* __restrict__ Hm, float* __restrict__ x){
  int b = blockIdx.x;
  int t = threadIdx.x;            // 128 threads
  int s = start[b], e = start[b + 1];
  float inv = 1.f / (float)((e - s) > 0 ? (e - s) : 1);
  float sum = 0.f;
  for (int a = s; a < e; a++) sum += H[(size_t)a * HS + t];
  Hm[(size_t)b * HS + t] = sum * inv;
  if (t < 3){
    float sz = 0.f;
    for (int a = s; a < e; a++) sz += Z[a * 3 + t];
    x[b * 3 + t] = sz * inv;
  }
}

// ---- generic MFMA GEMM: C[M x 128] = act(A[M x K] @ Wt^T + bias) (+resid)
__global__ __launch_bounds__(256) void gemm_kernel(
    const float* __restrict__ A, const float* __restrict__ A2,
    const ushortT* __restrict__ Wt, const float* __restrict__ bias,
    const float* __restrict__ resid, float* __restrict__ Cf, ushortT* __restrict__ Cbf,
    int K, int act){
  int t = threadIdx.x; int lane = t & 63; int wv = t >> 6;
  int l15 = lane & 15, lg = lane >> 4;
  int base = blockIdx.x * 64 + wv * 16;
  f32x4 zero = {0.f, 0.f, 0.f, 0.f};
  f32x4 acc[8];
#pragma unroll
  for (int n = 0; n < 8; n++) acc[n] = zero;
  int row = base + l15;
  int nks = K >> 5;
  for (int ks = 0; ks < nks; ks++){
    int k0 = ks * 32 + lg * 8;
    const float* ap = (A2 && k0 >= 128) ? (A2 + (size_t)row * HS + (k0 - 128))
                                        : (A  + (size_t)row * HS + k0);
    bf16x8 af = load8f_bf(ap);
#pragma unroll
    for (int n = 0; n < 8; n++){
      bf16x8 bf = load8bf(Wt + (size_t)(16 * n + l15) * K + k0);
      acc[n] = __builtin_amdgcn_mfma_f32_16x16x32_bf16(af, bf, acc[n], 0, 0, 0);
    }
  }
#pragma unroll
  for (int n = 0; n < 8; n++){
    int col = 16 * n + l15;
    float bv = bias[col];
#pragma unroll
    for (int r = 0; r < 4; r++){
      int ro = base + lg * 4 + r;
      float v = acc[n][r] + bv;
      if (act) v = silu(v);
      if (resid) v += resid[(size_t)ro * HS + col];
      Cf[(size_t)ro * HS + col] = v;
      if (Cbf) Cbf[(size_t)ro * HS + col] = f2bf(v);
    }
  }
}

// ---- fused edge kernel: 64 sorted edges per workgroup, 4 waves, ALL LDS wave-private,
// NO barriers. Segmented atomic flush for agg/xacc (rows sorted -> wave-uniform branch).
__global__ __launch_bounds__(256) void edge_kernel(
    const int* __restrict__ srow, const int* __restrict__ scol,
    const ushortT* __restrict__ sattr,
    const float* __restrict__ x, const ushortT* __restrict__ hbf,
    const ushortT* __restrict__ W1t, const ushortT* __restrict__ W2t,
    const ushortT* __restrict__ CW1t,
    const float* __restrict__ b1, const float* __restrict__ b2,
    const float* __restrict__ cb1, const float* __restrict__ cw3,
    float* __restrict__ xacc, float* __restrict__ agg){
  __shared__ int    rid_s[4][16];
  __shared__ int    cid_s[4][16];
  __shared__ float  dif_s[4][16][3];
  __shared__ __align__(16) ushortT atail_s[4][16][32];
  __shared__ __align__(16) ushortT s1_s[4][2048];
  __shared__ __align__(16) ushortT s2_s[4][2048];
  __shared__ float  wsh_s[4][16];

  const int t = threadIdx.x;
  const int lane = t & 63;
  const int wv = t >> 6;
  const int l15 = lane & 15, lg = lane >> 4;
  const int ebase = blockIdx.x * 64 + wv * 16;   // this wave's 16 edges

  int* rid = rid_s[wv];
  int* cid = cid_s[wv];
  ushortT* S1 = s1_s[wv];
  ushortT* S2 = s2_s[wv];

  // stage edge meta (wave-private)
  if (lg == 0){
    int e = ebase + l15;
    int r = srow[e], c = scol[e];
    rid[l15] = r; cid[l15] = c;
    float dx = x[r * 3 + 0] - x[c * 3 + 0];
    float dy = x[r * 3 + 1] - x[c * 3 + 1];
    float dz = x[r * 3 + 2] - x[c * 3 + 2];
    dif_s[wv][l15][0] = dx; dif_s[wv][l15][1] = dy; dif_s[wv][l15][2] = dz;
    atail_s[wv][l15][0] = f2bf(dx * dx + dy * dy + dz * dz);
  } else if (lg == 1){
#pragma unroll
    for (int k = 17; k < 32; k++) atail_s[wv][l15][k] = 0;
  }
  // stage attr: 16 edges x 16 = 256 contiguous ushorts from sattr
#pragma unroll
  for (int j = 0; j < 4; j++){
    int i = lane * 4 + j;                 // 0..255
    atail_s[wv][i >> 4][(i & 15) + 1] = sattr[(size_t)ebase * 16 + i];
  }

  f32x4 zero = {0.f, 0.f, 0.f, 0.f};
  f32x4 acc[8];
#pragma unroll
  for (int n = 0; n < 8; n++) acc[n] = zero;

  // ---- GEMM1: e_in [16x288] @ W1t^T -> m1 [16x128]
  {
    int ra = rid[l15], ca = cid[l15];
#pragma unroll
    for (int ks = 0; ks < 4; ks++){
      int k0 = ks * 32 + lg * 8;
      bf16x8 af = load8bf(hbf + (size_t)ra * HS + k0);
#pragma unroll
      for (int n = 0; n < 8; n++){
        bf16x8 bf = load8bf(W1t + (size_t)(16 * n + l15) * 288 + k0);
        acc[n] = __builtin_amdgcn_mfma_f32_16x16x32_bf16(af, bf, acc[n], 0, 0, 0);
      }
    }
#pragma unroll
    for (int ks = 0; ks < 4; ks++){
      int k0 = ks * 32 + lg * 8;
      bf16x8 af = load8bf(hbf + (size_t)ca * HS + k0);
#pragma unroll
      for (int n = 0; n < 8; n++){
        bf16x8 bf = load8bf(W1t + (size_t)(16 * n + l15) * 288 + 128 + k0);
        acc[n] = __builtin_amdgcn_mfma_f32_16x16x32_bf16(af, bf, acc[n], 0, 0, 0);
      }
    }
    {
      bf16x8 af = load8bf(&atail_s[wv][l15][lg * 8]);
      int k0 = 256 + lg * 8;
#pragma unroll
      for (int n = 0; n < 8; n++){
        bf16x8 bf = load8bf(W1t + (size_t)(16 * n + l15) * 288 + k0);
        acc[n] = __builtin_amdgcn_mfma_f32_16x16x32_bf16(af, bf, acc[n], 0, 0, 0);
      }
    }
  }
  // epilogue 1 -> S1 (silu, bf16, XOR-swizzled rows)
#pragma unroll
  for (int n = 0; n < 8; n++){
    int col = 16 * n + l15;
    float bv = b1[col];
#pragma unroll
    for (int r = 0; r < 4; r++){
      int er = lg * 4 + r;
      float v = silu(acc[n][r] + bv);
      S1[(er * 128 + col) ^ ((er & 7) << 3)] = f2bf(v);
    }
  }

  // ---- GEMM2: m = silu(S1 @ W2t^T + b2)
#pragma unroll
  for (int n = 0; n < 8; n++) acc[n] = zero;
#pragma unroll
  for (int ks = 0; ks < 4; ks++){
    int k0 = ks * 32 + lg * 8;
    bf16x8 af = load8bf(&S1[(l15 * 128 + k0) ^ ((l15 & 7) << 3)]);
#pragma unroll
    for (int n = 0; n < 8; n++){
      bf16x8 bf = load8bf(W2t + (size_t)(16 * n + l15) * 128 + k0);
      acc[n] = __builtin_amdgcn_mfma_f32_16x16x32_bf16(af, bf, acc[n], 0, 0, 0);
    }
  }
  // epilogue 2: S2 (bf16)
#pragma unroll
  for (int n = 0; n < 8; n++){
    int col = 16 * n + l15;
    float bv = b2[col];
#pragma unroll
    for (int r = 0; r < 4; r++){
      int er = lg * 4 + r;
      float v = silu(acc[n][r] + bv);
      S2[(er * 128 + col) ^ ((er & 7) << 3)] = f2bf(v);
    }
  }

  // ---- coord GEMM: w = silu(S2 @ CW1t^T + cb1) . cw3
#pragma unroll
  for (int n = 0; n < 8; n++) acc[n] = zero;
#pragma unroll
  for (int ks = 0; ks < 4; ks++){
    int k0 = ks * 32 + lg * 8;
    bf16x8 af = load8bf(&S2[(l15 * 128 + k0) ^ ((l15 & 7) << 3)]);
#pragma unroll
    for (int n = 0; n < 8; n++){
      bf16x8 bf = load8bf(CW1t + (size_t)(16 * n + l15) * 128 + k0);
      acc[n] = __builtin_amdgcn_mfma_f32_16x16x32_bf16(af, bf, acc[n], 0, 0, 0);
    }
  }
  {
    float rp[4] = {0.f, 0.f, 0.f, 0.f};
#pragma unroll
    for (int n = 0; n < 8; n++){
      int col = 16 * n + l15;
      float bv = cb1[col];
      float c3 = cw3[col];
#pragma unroll
      for (int r = 0; r < 4; r++){
        rp[r] += silu(acc[n][r] + bv) * c3;
      }
    }
#pragma unroll
    for (int off = 1; off < 16; off <<= 1){
#pragma unroll
      for (int r = 0; r < 4; r++) rp[r] += __shfl_xor(rp[r], off, 64);
    }
    if (l15 == 0){
#pragma unroll
      for (int r = 0; r < 4; r++) wsh_s[wv][lg * 4 + r] = rp[r];
    }
  }

  // ---- segmented agg flush: cols lane & lane+64, wave-uniform row-change branch
  {
    float run0 = 0.f, run1 = 0.f;
    int prev = __builtin_amdgcn_readfirstlane(rid[0]);
#pragma unroll
    for (int e = 0; e < 16; e++){
      int r = __builtin_amdgcn_readfirstlane(rid[e]);
      if (r != prev){
        atomicAdd(&agg[(size_t)prev * HS + lane], run0);
        atomicAdd(&agg[(size_t)prev * HS + 64 + lane], run1);
        run0 = 0.f; run1 = 0.f; prev = r;
      }
      run0 += bf2f(S2[(e * 128 + lane) ^ ((e & 7) << 3)]);
      run1 += bf2f(S2[(e * 128 + 64 + lane) ^ ((e & 7) << 3)]);
    }
    atomicAdd(&agg[(size_t)prev * HS + lane], run0);
    atomicAdd(&agg[(size_t)prev * HS + 64 + lane], run1);
  }

  // ---- segmented coordinate flush (lanes 0..2)
  if (lane < 3){
    float run = 0.f;
    int prev = rid[0];
#pragma unroll
    for (int e = 0; e < 16; e++){
      int r = rid[e];
      if (r != prev){
        atomicAdd(&xacc[(size_t)prev * 3 + lane], run);
        run = 0.f; prev = r;
      }
      run += dif_s[wv][e][lane] * wsh_s[wv][e];
    }
    atomicAdd(&xacc[(size_t)prev * 3 + lane], run);
  }
}

__global__ void x_update_kernel(float* __restrict__ x, const float* __restrict__ xacc,
                                const int* __restrict__ estart){
  int i = blockIdx.x * 256 + threadIdx.x;
  if (i < N_BLOCKS * 3){
    int b = i / 3;
    int c = estart[b + 1] - estart[b];
    x[i] += xacc[i] / (float)(c > 0 ? c : 1);
  }
}

// ---- block normalize + graph accumulate
__global__ void norm_block_kernel(const float* __restrict__ hin, const int* __restrict__ batch_id,
                                  float* __restrict__ brep, float* __restrict__ gsum){
  int wv = threadIdx.x >> 6, lane = threadIdx.x & 63;
  int b = blockIdx.x * 4 + wv;
  if (b >= N_BLOCKS) return;
  float v0 = hin[(size_t)b * HS + lane];
  float v1 = hin[(size_t)b * HS + 64 + lane];
  float ss = v0 * v0 + v1 * v1;
#pragma unroll
  for (int o = 1; o < 64; o <<= 1) ss += __shfl_xor(ss, o, 64);
  float s = 1.f / fmaxf(sqrtf(ss), 1e-12f);
  v0 *= s; v1 *= s;
  brep[(size_t)b * HS + lane] = v0;
  brep[(size_t)b * HS + 64 + lane] = v1;
  int g = batch_id[b];
  atomicAdd(&gsum[g * HS + lane], v0);
  atomicAdd(&gsum[g * HS + 64 + lane], v1);
}

__global__ void norm_graph_kernel(const float* __restrict__ gsum, float* __restrict__ grep){
  int wv = threadIdx.x >> 6, lane = threadIdx.x & 63;
  int g = blockIdx.x * 4 + wv;
  if (g >= N_GRAPHS) return;
  float v0 = gsum[g * HS + lane];
  float v1 = gsum[g * HS + 64 + lane];
  float ss = v0 * v0 + v1 * v1;
#pragma unroll
  for (int o = 1; o < 64; o <<= 1) ss += __shfl_xor(ss, o, 64);
  float s = 1.f / fmaxf(sqrtf(ss), 1e-12f);
  grep[(size_t)g * HS + lane] = v0 * s;
  grep[(size_t)g * HS + 64 + lane] = v1 * s;
}

extern "C" void kernel_launch(void* const* d_in, const int* in_sizes, int n_in,
                              void* d_out, int out_size, void* d_ws, size_t ws_size,
                              hipStream_t stream){
  const float* H         = (const float*)d_in[0];
  const float* Z         = (const float*)d_in[1];
  const int*   block_id  = (const int*)d_in[2];
  const int*   batch_id  = (const int*)d_in[3];
  const int*   edges     = (const int*)d_in[4];
  const float* edge_attr = (const float*)d_in[5];
  const float* emb_in_w  = (const float*)d_in[6];
  const float* emb_in_b  = (const float*)d_in[7];
  const float* emb_out_w = (const float*)d_in[8];
  const float* emb_out_b = (const float*)d_in[9];
  const float* edge_w1   = (const float*)d_in[10];
  const float* edge_b1   = (const float*)d_in[11];
  const float* edge_w2   = (const float*)d_in[12];
  const float* edge_b2   = (const float*)d_in[13];
  const float* node_w1   = (const float*)d_in[14];
  const float* node_b1   = (const float*)d_in[15];
  const float* node_w2   = (const float*)d_in[16];
  const float* node_b2   = (const float*)d_in[17];
  const float* coord_w1  = (const float*)d_in[18];
  const float* coord_b1  = (const float*)d_in[19];
  const float* coord_w3  = (const float*)d_in[20];

  float* out  = (float*)d_out;
  float* Hm   = out;                               // [16000 x 128]
  float* brep = out + (size_t)N_BLOCKS * HS;       // [16000 x 128]
  float* grep = out + (size_t)2 * N_BLOCKS * HS;   // [128 x 128]

  char* base = (char*)d_ws;
  size_t off = 0;
  auto take = [&](size_t bytes) -> char* {
    char* p = base + off;
    off += (bytes + 255) & ~(size_t)255;
    return p;
  };
  float*   x     = (float*)  take((size_t)N_BLOCKS * 3 * 4);
  float*   xacc  = (float*)  take((size_t)N_BLOCKS * 3 * 4);
  float*   h     = (float*)  take((size_t)N_BLOCKS * HS * 4);
  ushortT* hbf   = (ushortT*)take((size_t)N_BLOCKS * HS * 2);
  float*   agg   = (float*)  take((size_t)N_BLOCKS * HS * 4);
  float*   T1    = (float*)  take((size_t)N_BLOCKS * HS * 4);
  float*   gsum  = (float*)  take((size_t)N_GRAPHS * HS * 4);
  int*     bstart= (int*)    take((size_t)(N_BLOCKS + 1) * 4);
  int*     hist  = (int*)    take((size_t)N_BLOCKS * 4);
  int*     estart= (int*)    take((size_t)(N_BLOCKS + 1) * 4);
  int*     ecur  = (int*)    take((size_t)N_BLOCKS * 4);
  int*     srow  = (int*)    take((size_t)N_EDGES * 4);
  int*     scol  = (int*)    take((size_t)N_EDGES * 4);
  ushortT* sattr = (ushortT*)take((size_t)N_EDGES * 16 * 2);
  ushortT* W1t   = (ushortT*)take((size_t)3 * 128 * 288 * 2);
  ushortT* W2t   = (ushortT*)take((size_t)3 * 128 * 128 * 2);
  ushortT* CW1t  = (ushortT*)take((size_t)3 * 128 * 128 * 2);
  ushortT* NW1t  = (ushortT*)take((size_t)3 * 128 * 256 * 2);
  ushortT* NW2t  = (ushortT*)take((size_t)3 * 128 * 128 * 2);
  ushortT* Eint  = (ushortT*)take((size_t)128 * 128 * 2);
  ushortT* Eoutt = (ushortT*)take((size_t)128 * 128 * 2);

  // weight prep
  transpose_cvt_kernel<<<(3 * 128 * 288 + 255) / 256, 256, 0, stream>>>(edge_w1, W1t, 273, 128, 288, 3);
  transpose_cvt_kernel<<<(3 * 128 * 128 + 255) / 256, 256, 0, stream>>>(edge_w2, W2t, 128, 128, 128, 3);
  transpose_cvt_kernel<<<(3 * 128 * 128 + 255) / 256, 256, 0, stream>>>(coord_w1, CW1t, 128, 128, 128, 3);
  transpose_cvt_kernel<<<(3 * 128 * 256 + 255) / 256, 256, 0, stream>>>(node_w1, NW1t, 256, 128, 256, 3);
  transpose_cvt_kernel<<<(3 * 128 * 128 + 255) / 256, 256, 0, stream>>>(node_w2, NW2t, 128, 128, 128, 3);
  transpose_cvt_kernel<<<(128 * 128 + 255) / 256, 256, 0, stream>>>(emb_in_w, Eint, 128, 128, 128, 1);
  transpose_cvt_kernel<<<(128 * 128 + 255) / 256, 256, 0, stream>>>(emb_out_w, Eoutt, 128, 128, 128, 1);

  // edge counting-sort by row
  hipMemsetAsync(hist, 0, (size_t)N_BLOCKS * 4, stream);
  hist_kernel<<<N_EDGES / 256, 256, 0, stream>>>(edges, hist);
  scan_kernel<<<1, 256, 0, stream>>>(hist, estart);
  hipMemcpyAsync(ecur, estart, (size_t)N_BLOCKS * 4, hipMemcpyDeviceToDevice, stream);
  scatter_kernel<<<N_EDGES / 256, 256, 0, stream>>>(edges, edge_attr, ecur, srow, scol, sattr);

  block_start_kernel<<<(N_BLOCKS + 1 + 255) / 256, 256, 0, stream>>>(block_id, bstart);
  pool_kernel<<<N_BLOCKS, 128, 0, stream>>>(H, Z, bstart, Hm, x);

  // h = Hm @ emb_in_w + b
  gemm_kernel<<<N_BLOCKS / 64, 256, 0, stream>>>(Hm, nullptr, Eint, emb_in_b, nullptr, h, hbf, 128, 0);

  for (int l = 0; l < 3; l++){
    hipMemsetAsync(agg, 0, (size_t)N_BLOCKS * HS * 4, stream);
    hipMemsetAsync(xacc, 0, (size_t)N_BLOCKS * 3 * 4, stream);
    edge_kernel<<<N_EDGES / 64, 256, 0, stream>>>(
        srow, scol, sattr, x, hbf,
        W1t + (size_t)l * 128 * 288, W2t + (size_t)l * 128 * 128, CW1t + (size_t)l * 128 * 128,
        edge_b1 + l * 128, edge_b2 + l * 128, coord_b1 + l * 128, coord_w3 + l * 128,
        xacc, agg);
    x_update_kernel<<<(N_BLOCKS * 3 + 255) / 256, 256, 0, stream>>>(x, xacc, estart);
    // node MLP: T1 = silu([h|agg] @ nw1 + nb1);  h = h + (T1 @ nw2 + nb2)
    gemm_kernel<<<N_BLOCKS / 64, 256, 0, stream>>>(h, agg, NW1t + (size_t)l * 128 * 256,
                                                   node_b1 + l * 128, nullptr, T1, nullptr, 256, 1);
    gemm_kernel<<<N_BLOCKS / 64, 256, 0, stream>>>(T1, nullptr, NW2t + (size_t)l * 128 * 128,
                                                   node_b2 + l * 128, h, h, hbf, 128, 0);
  }

  // h_final = h @ emb_out_w + b  -> T1
  gemm_kernel<<<N_BLOCKS / 64, 256, 0, stream>>>(h, nullptr, Eoutt, emb_out_b, nullptr, T1, nullptr, 128, 0);

  hipMemsetAsync(gsum, 0, (size_t)N_GRAPHS * HS * 4, stream);
  norm_block_kernel<<<N_BLOCKS / 4, 256, 0, stream>>>(T1, batch_id, brep, gsum);
  norm_graph_kernel<<<N_GRAPHS / 4, 256, 0, stream>>>(gsum, grep);
}

// Round 3
// 1008.362 us; speedup vs baseline: 1.2495x; 1.0373x over previous
//
#include <hip/hip_runtime.h>

#define N_ATOMS  80000
#define N_BLOCKS 16000
#define N_EDGES  320000
#define N_GRAPHS 128
#define HS       128

typedef unsigned short ushortT;
typedef __attribute__((ext_vector_type(8))) __bf16 bf16x8;
typedef __attribute__((ext_vector_type(8))) unsigned short ushort8;
typedef __attribute__((ext_vector_type(4))) float f32x4;

__device__ __forceinline__ unsigned short f2bf(float f){
  unsigned int u = __builtin_bit_cast(unsigned int, f);
  u = (u + 0x7FFFu + ((u >> 16) & 1u)) >> 16;
  return (unsigned short)u;
}
__device__ __forceinline__ float bf2f(ushortT u){
  unsigned int v = ((unsigned int)u) << 16;
  return __builtin_bit_cast(float, v);
}
__device__ __forceinline__ bf16x8 load8bf(const ushortT* p){
  uint4 u = *reinterpret_cast<const uint4*>(p);
  return __builtin_bit_cast(bf16x8, u);
}
__device__ __forceinline__ bf16x8 load8f_bf(const float* p){
  float4 a = *reinterpret_cast<const float4*>(p);
  float4 b = *reinterpret_cast<const float4*>(p + 4);
  ushort8 u = { f2bf(a.x), f2bf(a.y), f2bf(a.z), f2bf(a.w),
                f2bf(b.x), f2bf(b.y), f2bf(b.z), f2bf(b.w) };
  return __builtin_bit_cast(bf16x8, u);
}
__device__ __forceinline__ float silu(float v){ return v / (1.f + __expf(-v)); }

// pi-permutation: C-fragment register (n,r) of lane-group lg holds natural col
// c = 16n + lg*4 + r; the B-fragment position p = ks*32 + lg*8 + j with
// n = 2ks + (j>>2), r = j&3. c_of_p maps storage position p -> natural col c.
__device__ __forceinline__ int c_of_p(int p){
  int ks = p >> 5, lg = (p >> 3) & 3, j = p & 7;
  return 16 * (ks * 2 + (j >> 2)) + lg * 4 + (j & 3);
}

// ---- weight transpose + bf16 convert:
// dst[l][n][k] = src[(l*srcK + row_off + kk)*N + nn], kk/nn optionally pi-permuted
__global__ void transpose_cvt_kernel(const float* __restrict__ src, ushortT* __restrict__ dst,
                                     int srcK, int row_off, int K, int N, int Kpad, int L,
                                     int perm_n, int perm_k){
  int idx = blockIdx.x * 256 + threadIdx.x;
  int tot = L * N * Kpad;
  if (idx >= tot) return;
  int k = idx % Kpad;
  int rem = idx / Kpad;
  int n = rem % N;
  int l = rem / N;
  float v = 0.f;
  if (k < K){
    int kk = perm_k ? c_of_p(k) : k;
    int nn = perm_n ? c_of_p(n) : n;
    v = src[((size_t)l * srcK + row_off + kk) * N + nn];
  }
  dst[idx] = f2bf(v);
}

__global__ void perm_bias_kernel(const float* __restrict__ src, float* __restrict__ dst, int L){
  int i = blockIdx.x * 256 + threadIdx.x;
  if (i >= L * 128) return;
  int l = i >> 7, p = i & 127;
  dst[i] = src[l * 128 + c_of_p(p)];
}

// ---- block segment starts via binary search (block_id sorted)
__global__ void block_start_kernel(const int* __restrict__ bid, int* __restrict__ start){
  int b = blockIdx.x * 256 + threadIdx.x;
  if (b > N_BLOCKS) return;
  int lo = 0, hi = N_ATOMS;
  while (lo < hi){ int mid = (lo + hi) >> 1; if (bid[mid] < b) lo = mid + 1; else hi = mid; }
  start[b] = lo;
}

__global__ void hist_kernel(const int* __restrict__ edges, int* __restrict__ hist){
  int e = blockIdx.x * 256 + threadIdx.x;
  if (e < N_EDGES) atomicAdd(&hist[edges[e]], 1);
}

__global__ void scan_kernel(const int* __restrict__ hist, int* __restrict__ estart){
  __shared__ int ps[256];
  int t = threadIdx.x;
  const int chunk = (N_BLOCKS + 255) / 256;
  int lo = t * chunk, hi = lo + chunk;
  if (hi > N_BLOCKS) hi = N_BLOCKS;
  int s = 0;
  for (int i = lo; i < hi; i++) s += hist[i];
  ps[t] = s;
  __syncthreads();
  for (int off = 1; off < 256; off <<= 1){
    int v = (t >= off) ? ps[t - off] : 0;
    __syncthreads();
    ps[t] += v;
    __syncthreads();
  }
  int base = (t == 0) ? 0 : ps[t - 1];
  for (int i = lo; i < hi; i++){ estart[i] = base; base += hist[i]; }
  if (t == 255) estart[N_BLOCKS] = base;
}

__global__ void scatter_kernel(const int* __restrict__ edges, const float* __restrict__ attr,
                               int* __restrict__ ecur,
                               int* __restrict__ srow, int* __restrict__ scol,
                               ushortT* __restrict__ sattr){
  int e = blockIdx.x * 256 + threadIdx.x;
  if (e >= N_EDGES) return;
  int r = edges[e], c = edges[N_EDGES + e];
  int p = atomicAdd(&ecur[r], 1);
  srow[p] = r; scol[p] = c;
#pragma unroll
  for (int k = 0; k < 16; k++) sattr[(size_t)p * 16 + k] = f2bf(attr[(size_t)e * 16 + k]);
}

__global__ void pool_kernel(const float* __restrict__ H, const float* __restrict__ Z,
                            const int* __restrict__ start,
                            float* __restrict__ Hm, float* __restrict__ x){
  int b = blockIdx.x;
  int t = threadIdx.x;            // 128 threads
  int s = start[b], e = start[b + 1];
  float inv = 1.f / (float)((e - s) > 0 ? (e - s) : 1);
  float sum = 0.f;
  for (int a = s; a < e; a++) sum += H[(size_t)a * HS + t];
  Hm[(size_t)b * HS + t] = sum * inv;
  if (t < 3){
    float sz = 0.f;
    for (int a = s; a < e; a++) sz += Z[a * 3 + t];
    x[b * 3 + t] = sz * inv;
  }
}

// ---- generic MFMA GEMM: C[M x 128] = act(A[M x K] @ Wt^T + bias) (+resid)
__global__ __launch_bounds__(256) void gemm_kernel(
    const float* __restrict__ A, const float* __restrict__ A2,
    const ushortT* __restrict__ Wt, const float* __restrict__ bias,
    const float* __restrict__ resid, float* __restrict__ Cf, ushortT* __restrict__ Cbf,
    int K, int act){
  int t = threadIdx.x; int lane = t & 63; int wv = t >> 6;
  int l15 = lane & 15, lg = lane >> 4;
  int base = blockIdx.x * 64 + wv * 16;
  f32x4 zero = {0.f, 0.f, 0.f, 0.f};
  f32x4 acc[8];
#pragma unroll
  for (int n = 0; n < 8; n++) acc[n] = zero;
  int row = base + l15;
  int nks = K >> 5;
  for (int ks = 0; ks < nks; ks++){
    int k0 = ks * 32 + lg * 8;
    const float* ap = (A2 && k0 >= 128) ? (A2 + (size_t)row * HS + (k0 - 128))
                                        : (A  + (size_t)row * HS + k0);
    bf16x8 af = load8f_bf(ap);
#pragma unroll
    for (int n = 0; n < 8; n++){
      bf16x8 bf = load8bf(Wt + (size_t)(16 * n + l15) * K + k0);
      acc[n] = __builtin_amdgcn_mfma_f32_16x16x32_bf16(af, bf, acc[n], 0, 0, 0);
    }
  }
#pragma unroll
  for (int n = 0; n < 8; n++){
    int col = 16 * n + l15;
    float bv = bias[col];
#pragma unroll
    for (int r = 0; r < 4; r++){
      int ro = base + lg * 4 + r;
      float v = acc[n][r] + bv;
      if (act) v = silu(v);
      if (resid) v += resid[(size_t)ro * HS + col];
      if (Cf)  Cf[(size_t)ro * HS + col] = v;
      if (Cbf) Cbf[(size_t)ro * HS + col] = f2bf(v);
    }
  }
}

// ---- fused edge kernel v3: swapped-operand MFMAs, pi-permuted k-dim, P/Q precomputed.
// 16 sorted edges per wave, 4 waves/WG, no barriers, wave-private LDS.
__global__ __launch_bounds__(256) void edge_kernel(
    const int* __restrict__ srow, const int* __restrict__ scol,
    const ushortT* __restrict__ sattr,
    const float* __restrict__ x,
    const ushortT* __restrict__ Pbf, const ushortT* __restrict__ Qbf,
    const ushortT* __restrict__ W1ct, const ushortT* __restrict__ W2tp,
    const ushortT* __restrict__ CW1tp,
    const float* __restrict__ b2, const float* __restrict__ cb1,
    const float* __restrict__ cw3,
    float* __restrict__ xacc, float* __restrict__ agg){
  __shared__ int    rid_s[4][16];
  __shared__ int    cid_s[4][16];
  __shared__ float  dif_s[4][16][3];
  __shared__ __align__(16) ushortT atail_s[4][16][32];
  __shared__ __align__(16) ushortT s2_s[4][2048];
  __shared__ float  wsh_s[4][16];

  const int t = threadIdx.x;
  const int lane = t & 63;
  const int wv = t >> 6;
  const int l15 = lane & 15, lg = lane >> 4;
  const int ebase = blockIdx.x * 64 + wv * 16;

  int* rid = rid_s[wv];
  int* cid = cid_s[wv];
  ushortT* S2 = s2_s[wv];

  // stage edge meta (wave-private)
  if (lg == 0){
    int e = ebase + l15;
    int r = srow[e], c = scol[e];
    rid[l15] = r; cid[l15] = c;
    float dx = x[r * 3 + 0] - x[c * 3 + 0];
    float dy = x[r * 3 + 1] - x[c * 3 + 1];
    float dz = x[r * 3 + 2] - x[c * 3 + 2];
    dif_s[wv][l15][0] = dx; dif_s[wv][l15][1] = dy; dif_s[wv][l15][2] = dz;
    atail_s[wv][l15][0] = f2bf(dx * dx + dy * dy + dz * dz);
  } else if (lg == 1){
#pragma unroll
    for (int k = 17; k < 32; k++) atail_s[wv][l15][k] = 0;
  }
#pragma unroll
  for (int j = 0; j < 4; j++){
    int i = lane * 4 + j;
    atail_s[wv][i >> 4][(i & 15) + 1] = sattr[(size_t)ebase * 16 + i];
  }

  f32x4 zero = {0.f, 0.f, 0.f, 0.f};

  // ---- tail MFMA (swapped): accT[n] = W1c[16n.., k] @ atail^T; C col = edge(l15), row = c-low
  f32x4 accT[8];
#pragma unroll
  for (int n = 0; n < 8; n++) accT[n] = zero;
  {
    bf16x8 tailf = load8bf(&atail_s[wv][l15][lg * 8]);
#pragma unroll
    for (int n = 0; n < 8; n++){
      bf16x8 wf = load8bf(W1ct + (size_t)(16 * n + l15) * 32 + lg * 8);
      accT[n] = __builtin_amdgcn_mfma_f32_16x16x32_bf16(wf, tailf, accT[n], 0, 0, 0);
    }
  }

  // ---- GEMM2 (swapped): m^T = W2^T @ m1^T, m1 = silu(P[row] + Q[col] + tail)
  const int prow = rid[l15], qrow = cid[l15];
  f32x4 acc2[8];
#pragma unroll
  for (int n = 0; n < 8; n++) acc2[n] = zero;
#pragma unroll
  for (int ks = 0; ks < 4; ks++){
    ushort8 pv = __builtin_bit_cast(ushort8, load8bf(Pbf + (size_t)prow * HS + ks * 32 + lg * 8));
    ushort8 qv = __builtin_bit_cast(ushort8, load8bf(Qbf + (size_t)qrow * HS + ks * 32 + lg * 8));
    ushort8 af;
#pragma unroll
    for (int j = 0; j < 8; j++){
      float tv = accT[ks * 2 + (j >> 2)][j & 3];
      float v = tv + bf2f(pv[j]) + bf2f(qv[j]);
      af[j] = f2bf(silu(v));
    }
    bf16x8 afb = __builtin_bit_cast(bf16x8, af);
#pragma unroll
    for (int n = 0; n < 8; n++){
      bf16x8 wf = load8bf(W2tp + (size_t)(16 * n + l15) * HS + ks * 32 + lg * 8);
      acc2[n] = __builtin_amdgcn_mfma_f32_16x16x32_bf16(wf, afb, acc2[n], 0, 0, 0);
    }
  }

  // ---- m = silu(acc2 + b2): build coord B-frags (pi order) + write S2 for agg flush
  ushort8 mfb[4];
  {
    float4 b2v[8];
#pragma unroll
    for (int n = 0; n < 8; n++) b2v[n] = *reinterpret_cast<const float4*>(b2 + 16 * n + lg * 4);
#pragma unroll
    for (int ks = 0; ks < 4; ks++){
      ushort8 mm;
#pragma unroll
      for (int j = 0; j < 8; j++){
        int n = ks * 2 + (j >> 2), r = j & 3;
        float v = silu(acc2[n][r] + (&b2v[n].x)[r]);
        mm[j] = f2bf(v);
      }
      mfb[ks] = mm;
      uint4 u = __builtin_bit_cast(uint4, mm);
      int i0 = (l15 * 128 + ks * 32 + lg * 4) ^ ((l15 & 7) << 3);
      int i1 = (l15 * 128 + ks * 32 + 16 + lg * 4) ^ ((l15 & 7) << 3);
      *reinterpret_cast<uint2*>(&S2[i0]) = make_uint2(u.x, u.y);
      *reinterpret_cast<uint2*>(&S2[i1]) = make_uint2(u.z, u.w);
    }
  }

  // ---- coord GEMM (swapped): wout^T = CW1^T @ m^T
  f32x4 acc3[8];
#pragma unroll
  for (int n = 0; n < 8; n++) acc3[n] = zero;
#pragma unroll
  for (int ks = 0; ks < 4; ks++){
    bf16x8 mb = __builtin_bit_cast(bf16x8, mfb[ks]);
#pragma unroll
    for (int n = 0; n < 8; n++){
      bf16x8 wf = load8bf(CW1tp + (size_t)(16 * n + l15) * HS + ks * 32 + lg * 8);
      acc3[n] = __builtin_amdgcn_mfma_f32_16x16x32_bf16(wf, mb, acc3[n], 0, 0, 0);
    }
  }
  {
    float wsum = 0.f;
#pragma unroll
    for (int n = 0; n < 8; n++){
      float4 cbv = *reinterpret_cast<const float4*>(cb1 + 16 * n + lg * 4);
      float4 cwv = *reinterpret_cast<const float4*>(cw3 + 16 * n + lg * 4);
#pragma unroll
      for (int r = 0; r < 4; r++){
        wsum += silu(acc3[n][r] + (&cbv.x)[r]) * (&cwv.x)[r];
      }
    }
    wsum += __shfl_xor(wsum, 16, 64);
    wsum += __shfl_xor(wsum, 32, 64);
    if (lg == 0) wsh_s[wv][l15] = wsum;
  }

  // ---- segmented agg flush: cols lane & lane+64, wave-uniform row-change branch
  {
    float run0 = 0.f, run1 = 0.f;
    int prev = __builtin_amdgcn_readfirstlane(rid[0]);
#pragma unroll
    for (int e = 0; e < 16; e++){
      int r = __builtin_amdgcn_readfirstlane(rid[e]);
      if (r != prev){
        atomicAdd(&agg[(size_t)prev * HS + lane], run0);
        atomicAdd(&agg[(size_t)prev * HS + 64 + lane], run1);
        run0 = 0.f; run1 = 0.f; prev = r;
      }
      run0 += bf2f(S2[(e * 128 + lane) ^ ((e & 7) << 3)]);
      run1 += bf2f(S2[(e * 128 + 64 + lane) ^ ((e & 7) << 3)]);
    }
    atomicAdd(&agg[(size_t)prev * HS + lane], run0);
    atomicAdd(&agg[(size_t)prev * HS + 64 + lane], run1);
  }

  // ---- segmented coordinate flush (lanes 0..2)
  if (lane < 3){
    float run = 0.f;
    int prev = rid[0];
#pragma unroll
    for (int e = 0; e < 16; e++){
      int r = rid[e];
      if (r != prev){
        atomicAdd(&xacc[(size_t)prev * 3 + lane], run);
        run = 0.f; prev = r;
      }
      run += dif_s[wv][e][lane] * wsh_s[wv][e];
    }
    atomicAdd(&xacc[(size_t)prev * 3 + lane], run);
  }
}

__global__ void x_update_kernel(float* __restrict__ x, const float* __restrict__ xacc,
                                const int* __restrict__ estart){
  int i = blockIdx.x * 256 + threadIdx.x;
  if (i < N_BLOCKS * 3){
    int b = i / 3;
    int c = estart[b + 1] - estart[b];
    x[i] += xacc[i] / (float)(c > 0 ? c : 1);
  }
}

__global__ void norm_block_kernel(const float* __restrict__ hin, const int* __restrict__ batch_id,
                                  float* __restrict__ brep, float* __restrict__ gsum){
  int wv = threadIdx.x >> 6, lane = threadIdx.x & 63;
  int b = blockIdx.x * 4 + wv;
  if (b >= N_BLOCKS) return;
  float v0 = hin[(size_t)b * HS + lane];
  float v1 = hin[(size_t)b * HS + 64 + lane];
  float ss = v0 * v0 + v1 * v1;
#pragma unroll
  for (int o = 1; o < 64; o <<= 1) ss += __shfl_xor(ss, o, 64);
  float s = 1.f / fmaxf(sqrtf(ss), 1e-12f);
  v0 *= s; v1 *= s;
  brep[(size_t)b * HS + lane] = v0;
  brep[(size_t)b * HS + 64 + lane] = v1;
  int g = batch_id[b];
  atomicAdd(&gsum[g * HS + lane], v0);
  atomicAdd(&gsum[g * HS + 64 + lane], v1);
}

__global__ void norm_graph_kernel(const float* __restrict__ gsum, float* __restrict__ grep){
  int wv = threadIdx.x >> 6, lane = threadIdx.x & 63;
  int g = blockIdx.x * 4 + wv;
  if (g >= N_GRAPHS) return;
  float v0 = gsum[g * HS + lane];
  float v1 = gsum[g * HS + 64 + lane];
  float ss = v0 * v0 + v1 * v1;
#pragma unroll
  for (int o = 1; o < 64; o <<= 1) ss += __shfl_xor(ss, o, 64);
  float s = 1.f / fmaxf(sqrtf(ss), 1e-12f);
  grep[(size_t)g * HS + lane] = v0 * s;
  grep[(size_t)g * HS + 64 + lane] = v1 * s;
}

extern "C" void kernel_launch(void* const* d_in, const int* in_sizes, int n_in,
                              void* d_out, int out_size, void* d_ws, size_t ws_size,
                              hipStream_t stream){
  const float* H         = (const float*)d_in[0];
  const float* Z         = (const float*)d_in[1];
  const int*   block_id  = (const int*)d_in[2];
  const int*   batch_id  = (const int*)d_in[3];
  const int*   edges     = (const int*)d_in[4];
  const float* edge_attr = (const float*)d_in[5];
  const float* emb_in_w  = (const float*)d_in[6];
  const float* emb_in_b  = (const float*)d_in[7];
  const float* emb_out_w = (const float*)d_in[8];
  const float* emb_out_b = (const float*)d_in[9];
  const float* edge_w1   = (const float*)d_in[10];
  const float* edge_b1   = (const float*)d_in[11];
  const float* edge_w2   = (const float*)d_in[12];
  const float* edge_b2   = (const float*)d_in[13];
  const float* node_w1   = (const float*)d_in[14];
  const float* node_b1   = (const float*)d_in[15];
  const float* node_w2   = (const float*)d_in[16];
  const float* node_b2   = (const float*)d_in[17];
  const float* coord_w1  = (const float*)d_in[18];
  const float* coord_b1  = (const float*)d_in[19];
  const float* coord_w3  = (const float*)d_in[20];

  float* out  = (float*)d_out;
  float* Hm   = out;                               // [16000 x 128]
  float* brep = out + (size_t)N_BLOCKS * HS;       // [16000 x 128]
  float* grep = out + (size_t)2 * N_BLOCKS * HS;   // [128 x 128]

  char* base = (char*)d_ws;
  size_t off = 0;
  auto take = [&](size_t bytes) -> char* {
    char* p = base + off;
    off += (bytes + 255) & ~(size_t)255;
    return p;
  };
  float*   x     = (float*)  take((size_t)N_BLOCKS * 3 * 4);
  float*   xacc  = (float*)  take((size_t)N_BLOCKS * 3 * 4);
  float*   h     = (float*)  take((size_t)N_BLOCKS * HS * 4);
  float*   agg   = (float*)  take((size_t)N_BLOCKS * HS * 4);
  float*   T1    = (float*)  take((size_t)N_BLOCKS * HS * 4);
  float*   gsum  = (float*)  take((size_t)N_GRAPHS * HS * 4);
  int*     bstart= (int*)    take((size_t)(N_BLOCKS + 1) * 4);
  int*     hist  = (int*)    take((size_t)N_BLOCKS * 4);
  int*     estart= (int*)    take((size_t)(N_BLOCKS + 1) * 4);
  int*     ecur  = (int*)    take((size_t)N_BLOCKS * 4);
  int*     srow  = (int*)    take((size_t)N_EDGES * 4);
  int*     scol  = (int*)    take((size_t)N_EDGES * 4);
  ushortT* sattr = (ushortT*)take((size_t)N_EDGES * 16 * 2);
  ushortT* Pbf   = (ushortT*)take((size_t)N_BLOCKS * HS * 2);
  ushortT* Qbf   = (ushortT*)take((size_t)N_BLOCKS * HS * 2);
  ushortT* W1atp = (ushortT*)take((size_t)3 * 128 * 128 * 2);
  ushortT* W1btp = (ushortT*)take((size_t)3 * 128 * 128 * 2);
  ushortT* W1ct  = (ushortT*)take((size_t)3 * 128 * 32 * 2);
  ushortT* W2tp  = (ushortT*)take((size_t)3 * 128 * 128 * 2);
  ushortT* CW1tp = (ushortT*)take((size_t)3 * 128 * 128 * 2);
  ushortT* NW1t  = (ushortT*)take((size_t)3 * 128 * 256 * 2);
  ushortT* NW2t  = (ushortT*)take((size_t)3 * 128 * 128 * 2);
  ushortT* Eint  = (ushortT*)take((size_t)128 * 128 * 2);
  ushortT* Eoutt = (ushortT*)take((size_t)128 * 128 * 2);
  float*   b1p   = (float*)  take((size_t)3 * 128 * 4);
  float*   zbias = (float*)  take((size_t)128 * 4);

  // weight prep
  transpose_cvt_kernel<<<(3*128*128 + 255)/256, 256, 0, stream>>>(edge_w1, W1atp, 273,   0, 128, 128, 128, 3, 1, 0);
  transpose_cvt_kernel<<<(3*128*128 + 255)/256, 256, 0, stream>>>(edge_w1, W1btp, 273, 128, 128, 128, 128, 3, 1, 0);
  transpose_cvt_kernel<<<(3*128*32  + 255)/256, 256, 0, stream>>>(edge_w1, W1ct,  273, 256,  17, 128,  32, 3, 0, 0);
  transpose_cvt_kernel<<<(3*128*128 + 255)/256, 256, 0, stream>>>(edge_w2, W2tp,  128,   0, 128, 128, 128, 3, 0, 1);
  transpose_cvt_kernel<<<(3*128*128 + 255)/256, 256, 0, stream>>>(coord_w1, CW1tp,128,   0, 128, 128, 128, 3, 0, 1);
  transpose_cvt_kernel<<<(3*128*256 + 255)/256, 256, 0, stream>>>(node_w1, NW1t,  256,   0, 256, 128, 256, 3, 0, 0);
  transpose_cvt_kernel<<<(3*128*128 + 255)/256, 256, 0, stream>>>(node_w2, NW2t,  128,   0, 128, 128, 128, 3, 0, 0);
  transpose_cvt_kernel<<<(128*128 + 255)/256, 256, 0, stream>>>(emb_in_w,  Eint,  128,   0, 128, 128, 128, 1, 0, 0);
  transpose_cvt_kernel<<<(128*128 + 255)/256, 256, 0, stream>>>(emb_out_w, Eoutt, 128,   0, 128, 128, 128, 1, 0, 0);
  perm_bias_kernel<<<2, 256, 0, stream>>>(edge_b1, b1p, 3);
  hipMemsetAsync(zbias, 0, 128 * 4, stream);

  // edge counting-sort by row
  hipMemsetAsync(hist, 0, (size_t)N_BLOCKS * 4, stream);
  hist_kernel<<<N_EDGES / 256, 256, 0, stream>>>(edges, hist);
  scan_kernel<<<1, 256, 0, stream>>>(hist, estart);
  hipMemcpyAsync(ecur, estart, (size_t)N_BLOCKS * 4, hipMemcpyDeviceToDevice, stream);
  scatter_kernel<<<N_EDGES / 256, 256, 0, stream>>>(edges, edge_attr, ecur, srow, scol, sattr);

  block_start_kernel<<<(N_BLOCKS + 1 + 255) / 256, 256, 0, stream>>>(block_id, bstart);
  pool_kernel<<<N_BLOCKS, 128, 0, stream>>>(H, Z, bstart, Hm, x);

  // h = Hm @ emb_in_w + b
  gemm_kernel<<<N_BLOCKS / 64, 256, 0, stream>>>(Hm, nullptr, Eint, emb_in_b, nullptr, h, nullptr, 128, 0);

  for (int l = 0; l < 3; l++){
    // P = h @ W1a + b1 (pi-permuted cols, bf16); Q = h @ W1b (pi-permuted cols, bf16)
    gemm_kernel<<<N_BLOCKS / 64, 256, 0, stream>>>(h, nullptr, W1atp + (size_t)l * 128 * 128,
                                                   b1p + l * 128, nullptr, nullptr, Pbf, 128, 0);
    gemm_kernel<<<N_BLOCKS / 64, 256, 0, stream>>>(h, nullptr, W1btp + (size_t)l * 128 * 128,
                                                   zbias, nullptr, nullptr, Qbf, 128, 0);
    hipMemsetAsync(agg, 0, (size_t)N_BLOCKS * HS * 4, stream);
    hipMemsetAsync(xacc, 0, (size_t)N_BLOCKS * 3 * 4, stream);
    edge_kernel<<<N_EDGES / 64, 256, 0, stream>>>(
        srow, scol, sattr, x, Pbf, Qbf,
        W1ct + (size_t)l * 128 * 32, W2tp + (size_t)l * 128 * 128, CW1tp + (size_t)l * 128 * 128,
        edge_b2 + l * 128, coord_b1 + l * 128, coord_w3 + l * 128,
        xacc, agg);
    x_update_kernel<<<(N_BLOCKS * 3 + 255) / 256, 256, 0, stream>>>(x, xacc, estart);
    // node MLP: T1 = silu([h|agg] @ nw1 + nb1);  h = h + (T1 @ nw2 + nb2)
    gemm_kernel<<<N_BLOCKS / 64, 256, 0, stream>>>(h, agg, NW1t + (size_t)l * 128 * 256,
                                                   node_b1 + l * 128, nullptr, T1, nullptr, 256, 1);
    gemm_kernel<<<N_BLOCKS / 64, 256, 0, stream>>>(T1, nullptr, NW2t + (size_t)l * 128 * 128,
                                                   node_b2 + l * 128, h, h, nullptr, 128, 0);
  }

  // h_final = h @ emb_out_w + b  -> T1
  gemm_kernel<<<N_BLOCKS / 64, 256, 0, stream>>>(h, nullptr, Eoutt, emb_out_b, nullptr, T1, nullptr, 128, 0);

  hipMemsetAsync(gsum, 0, (size_t)N_GRAPHS * HS * 4, stream);
  norm_block_kernel<<<N_BLOCKS / 4, 256, 0, stream>>>(T1, batch_id, brep, gsum);
  norm_graph_kernel<<<N_GRAPHS / 4, 256, 0, stream>>>(gsum, grep);
}

// Round 5
// 982.694 us; speedup vs baseline: 1.2821x; 1.0261x over previous
//
#include <hip/hip_runtime.h>

#define N_ATOMS  80000
#define N_BLOCKS 16000
#define N_EDGES  320000
#define N_GRAPHS 128
#define HS       128
#define TILES    4

typedef unsigned short ushortT;
typedef __attribute__((ext_vector_type(8))) __bf16 bf16x8;
typedef __attribute__((ext_vector_type(8))) unsigned short ushort8;
typedef __attribute__((ext_vector_type(4))) float f32x4;

__device__ __forceinline__ unsigned short f2bf(float f){
  unsigned int u = __builtin_bit_cast(unsigned int, f);
  u = (u + 0x7FFFu + ((u >> 16) & 1u)) >> 16;
  return (unsigned short)u;
}
// fast path: native cvt (RNE on gfx950)
__device__ __forceinline__ ushortT f2bff(float f){
  __bf16 b = (__bf16)f;
  return __builtin_bit_cast(ushortT, b);
}
__device__ __forceinline__ float bf2f(ushortT u){
  unsigned int v = ((unsigned int)u) << 16;
  return __builtin_bit_cast(float, v);
}
__device__ __forceinline__ bf16x8 load8bf(const ushortT* p){
  uint4 u = *reinterpret_cast<const uint4*>(p);
  return __builtin_bit_cast(bf16x8, u);
}
__device__ __forceinline__ bf16x8 load8f_bf(const float* p){
  float4 a = *reinterpret_cast<const float4*>(p);
  float4 b = *reinterpret_cast<const float4*>(p + 4);
  ushort8 u = { f2bff(a.x), f2bff(a.y), f2bff(a.z), f2bff(a.w),
                f2bff(b.x), f2bff(b.y), f2bff(b.z), f2bff(b.w) };
  return __builtin_bit_cast(bf16x8, u);
}
__device__ __forceinline__ float silu(float v){ return v / (1.f + __expf(-v)); }

// pi-permutation: C-fragment register (n,r) of lane-group lg holds natural col
// c = 16n + lg*4 + r; B-fragment position p = ks*32 + lg*8 + j, n = 2ks + (j>>2), r = j&3.
__device__ __forceinline__ int c_of_p(int p){
  int ks = p >> 5, lg = (p >> 3) & 3, j = p & 7;
  return 16 * (ks * 2 + (j >> 2)) + lg * 4 + (j & 3);
}

// ---- weight transpose + bf16 convert
__global__ void transpose_cvt_kernel(const float* __restrict__ src, ushortT* __restrict__ dst,
                                     int srcK, int row_off, int K, int N, int Kpad, int L,
                                     int perm_n, int perm_k){
  int idx = blockIdx.x * 256 + threadIdx.x;
  int tot = L * N * Kpad;
  if (idx >= tot) return;
  int k = idx % Kpad;
  int rem = idx / Kpad;
  int n = rem % N;
  int l = rem / N;
  float v = 0.f;
  if (k < K){
    int kk = perm_k ? c_of_p(k) : k;
    int nn = perm_n ? c_of_p(n) : n;
    v = src[((size_t)l * srcK + row_off + kk) * N + nn];
  }
  dst[idx] = f2bf(v);
}

__global__ void perm_bias_kernel(const float* __restrict__ src, float* __restrict__ dst, int L){
  int i = blockIdx.x * 256 + threadIdx.x;
  if (i >= L * 128) return;
  int l = i >> 7, p = i & 127;
  dst[i] = src[l * 128 + c_of_p(p)];
}

__global__ void block_start_kernel(const int* __restrict__ bid, int* __restrict__ start){
  int b = blockIdx.x * 256 + threadIdx.x;
  if (b > N_BLOCKS) return;
  int lo = 0, hi = N_ATOMS;
  while (lo < hi){ int mid = (lo + hi) >> 1; if (bid[mid] < b) lo = mid + 1; else hi = mid; }
  start[b] = lo;
}

__global__ void hist_kernel(const int* __restrict__ edges, int* __restrict__ hist){
  int e = blockIdx.x * 256 + threadIdx.x;
  if (e < N_EDGES) atomicAdd(&hist[edges[e]], 1);
}

// scan also initializes ecur (saves a d2d copy)
__global__ void scan_kernel(const int* __restrict__ hist, int* __restrict__ estart,
                            int* __restrict__ ecur){
  __shared__ int ps[256];
  int t = threadIdx.x;
  const int chunk = (N_BLOCKS + 255) / 256;
  int lo = t * chunk, hi = lo + chunk;
  if (hi > N_BLOCKS) hi = N_BLOCKS;
  int s = 0;
  for (int i = lo; i < hi; i++) s += hist[i];
  ps[t] = s;
  __syncthreads();
  for (int off = 1; off < 256; off <<= 1){
    int v = (t >= off) ? ps[t - off] : 0;
    __syncthreads();
    ps[t] += v;
    __syncthreads();
  }
  int base = (t == 0) ? 0 : ps[t - 1];
  for (int i = lo; i < hi; i++){ estart[i] = base; ecur[i] = base; base += hist[i]; }
  if (t == 255) estart[N_BLOCKS] = base;
}

// scatter into sorted order; sattr padded: 32 u16/edge = [0, attr0..15, 0 x15]
__global__ void scatter_kernel(const int* __restrict__ edges, const float* __restrict__ attr,
                               int* __restrict__ ecur,
                               int* __restrict__ srow, int* __restrict__ scol,
                               ushortT* __restrict__ sattr){
  int e = blockIdx.x * 256 + threadIdx.x;
  if (e >= N_EDGES) return;
  int r = edges[e], c = edges[N_EDGES + e];
  int p = atomicAdd(&ecur[r], 1);
  srow[p] = r; scol[p] = c;
  ushortT buf[32];
  buf[0] = 0;
#pragma unroll
  for (int k = 0; k < 16; k++) buf[k + 1] = f2bf(attr[(size_t)e * 16 + k]);
#pragma unroll
  for (int k = 17; k < 32; k++) buf[k] = 0;
  // copy ALL 32 ushorts = 16 uints (round-4 bug: only 8 were copied)
#pragma unroll
  for (int k = 0; k < 16; k++)
    reinterpret_cast<uint*>(sattr + (size_t)p * 32)[k] = reinterpret_cast<uint*>(buf)[k];
}

__global__ void pool_kernel(const float* __restrict__ H, const float* __restrict__ Z,
                            const int* __restrict__ start,
                            float* __restrict__ Hm, float* __restrict__ x){
  int b = blockIdx.x;
  int t = threadIdx.x;            // 128 threads
  int s = start[b], e = start[b + 1];
  float inv = 1.f / (float)((e - s) > 0 ? (e - s) : 1);
  float sum = 0.f;
  for (int a = s; a < e; a++) sum += H[(size_t)a * HS + t];
  Hm[(size_t)b * HS + t] = sum * inv;
  if (t < 3){
    float sz = 0.f;
    for (int a = s; a < e; a++) sz += Z[a * 3 + t];
    x[b * 3 + t] = sz * inv;
  }
}

// ---- generic MFMA GEMM (used for emb_in only)
__global__ __launch_bounds__(256) void gemm_kernel(
    const float* __restrict__ A,
    const ushortT* __restrict__ Wt, const float* __restrict__ bias,
    float* __restrict__ Cf){
  int t = threadIdx.x; int lane = t & 63; int wv = t >> 6;
  int l15 = lane & 15, lg = lane >> 4;
  int base = blockIdx.x * 64 + wv * 16;
  f32x4 zero = {0.f, 0.f, 0.f, 0.f};
  f32x4 acc[8];
#pragma unroll
  for (int n = 0; n < 8; n++) acc[n] = zero;
  int row = base + l15;
#pragma unroll
  for (int ks = 0; ks < 4; ks++){
    int k0 = ks * 32 + lg * 8;
    bf16x8 af = load8f_bf(A + (size_t)row * HS + k0);
#pragma unroll
    for (int n = 0; n < 8; n++){
      bf16x8 bf = load8bf(Wt + (size_t)(16 * n + l15) * HS + k0);
      acc[n] = __builtin_amdgcn_mfma_f32_16x16x32_bf16(af, bf, acc[n], 0, 0, 0);
    }
  }
#pragma unroll
  for (int n = 0; n < 8; n++){
    int col = 16 * n + l15;
    float bv = bias[col];
#pragma unroll
    for (int r = 0; r < 4; r++){
      int ro = base + lg * 4 + r;
      Cf[(size_t)ro * HS + col] = acc[n][r] + bv;
    }
  }
}

// ---- fused P/Q kernel: P = h@W1a + b1 (pi cols), Q = h@W1b (pi cols), bf16 out
__global__ __launch_bounds__(256) void pq_kernel(
    const float* __restrict__ h,
    const ushortT* __restrict__ Wa, const ushortT* __restrict__ Wb,
    const float* __restrict__ b1p,
    ushortT* __restrict__ Pbf, ushortT* __restrict__ Qbf){
  int t = threadIdx.x; int lane = t & 63; int wv = t >> 6;
  int l15 = lane & 15, lg = lane >> 4;
  int base = blockIdx.x * 64 + wv * 16;
  int row = base + l15;
  f32x4 zero = {0.f, 0.f, 0.f, 0.f};
  f32x4 accp[8], accq[8];
#pragma unroll
  for (int n = 0; n < 8; n++){ accp[n] = zero; accq[n] = zero; }
#pragma unroll
  for (int ks = 0; ks < 4; ks++){
    int k0 = ks * 32 + lg * 8;
    bf16x8 af = load8f_bf(h + (size_t)row * HS + k0);
#pragma unroll
    for (int n = 0; n < 8; n++){
      accp[n] = __builtin_amdgcn_mfma_f32_16x16x32_bf16(af, load8bf(Wa + (size_t)(16 * n + l15) * HS + k0), accp[n], 0, 0, 0);
      accq[n] = __builtin_amdgcn_mfma_f32_16x16x32_bf16(af, load8bf(Wb + (size_t)(16 * n + l15) * HS + k0), accq[n], 0, 0, 0);
    }
  }
#pragma unroll
  for (int n = 0; n < 8; n++){
    int col = 16 * n + l15;
    float bv = b1p[col];
#pragma unroll
    for (int r = 0; r < 4; r++){
      int ro = base + lg * 4 + r;
      Pbf[(size_t)ro * HS + col] = f2bff(accp[n][r] + bv);
      Qbf[(size_t)ro * HS + col] = f2bff(accq[n][r]);
    }
  }
}

// ---- fused node MLP: h += silu([h|agg]@W1 + b1) @ W2 + b2  (in place, rows wave-exclusive)
__global__ __launch_bounds__(256) void node_kernel(
    float* h, const float* __restrict__ agg,
    const ushortT* __restrict__ W1t, const ushortT* __restrict__ W2t,
    const float* __restrict__ b1, const float* __restrict__ b2){
  __shared__ __align__(16) ushortT t1_s[4][2048];
  int t = threadIdx.x; int lane = t & 63; int wv = t >> 6;
  int l15 = lane & 15, lg = lane >> 4;
  int base = blockIdx.x * 64 + wv * 16;
  int row = base + l15;
  ushortT* T1 = t1_s[wv];
  f32x4 zero = {0.f, 0.f, 0.f, 0.f};
  f32x4 acc[8];
#pragma unroll
  for (int n = 0; n < 8; n++) acc[n] = zero;
#pragma unroll
  for (int ks = 0; ks < 8; ks++){
    int k0 = ks * 32 + lg * 8;
    bf16x8 af = (k0 < 128) ? load8f_bf(h + (size_t)row * HS + k0)
                           : load8f_bf(agg + (size_t)row * HS + (k0 - 128));
#pragma unroll
    for (int n = 0; n < 8; n++){
      acc[n] = __builtin_amdgcn_mfma_f32_16x16x32_bf16(af, load8bf(W1t + (size_t)(16 * n + l15) * 256 + k0), acc[n], 0, 0, 0);
    }
  }
#pragma unroll
  for (int n = 0; n < 8; n++){
    int col = 16 * n + l15;
    float bv = b1[col];
#pragma unroll
    for (int r = 0; r < 4; r++){
      int er = lg * 4 + r;
      T1[(er * 128 + col) ^ ((er & 7) << 3)] = f2bff(silu(acc[n][r] + bv));
    }
  }
  // phase 2 (wave-private LDS, no barrier)
#pragma unroll
  for (int n = 0; n < 8; n++) acc[n] = zero;
#pragma unroll
  for (int ks = 0; ks < 4; ks++){
    int k0 = ks * 32 + lg * 8;
    bf16x8 af = load8bf(&T1[(l15 * 128 + k0) ^ ((l15 & 7) << 3)]);
#pragma unroll
    for (int n = 0; n < 8; n++){
      acc[n] = __builtin_amdgcn_mfma_f32_16x16x32_bf16(af, load8bf(W2t + (size_t)(16 * n + l15) * HS + k0), acc[n], 0, 0, 0);
    }
  }
#pragma unroll
  for (int n = 0; n < 8; n++){
    int col = 16 * n + l15;
    float bv = b2[col];
#pragma unroll
    for (int r = 0; r < 4; r++){
      int ro = base + lg * 4 + r;
      h[(size_t)ro * HS + col] += acc[n][r] + bv;
    }
  }
}

// ---- fused emb_out GEMM + block normalize + graph accumulate
__global__ __launch_bounds__(256) void emb_norm_kernel(
    const float* __restrict__ h, const ushortT* __restrict__ Wt,
    const float* __restrict__ bias, const int* __restrict__ batch_id,
    float* __restrict__ brep, float* __restrict__ gsum){
  int t = threadIdx.x; int lane = t & 63; int wv = t >> 6;
  int l15 = lane & 15, lg = lane >> 4;
  int base = blockIdx.x * 64 + wv * 16;
  int row = base + l15;
  f32x4 zero = {0.f, 0.f, 0.f, 0.f};
  f32x4 acc[8];
#pragma unroll
  for (int n = 0; n < 8; n++) acc[n] = zero;
#pragma unroll
  for (int ks = 0; ks < 4; ks++){
    int k0 = ks * 32 + lg * 8;
    bf16x8 af = load8f_bf(h + (size_t)row * HS + k0);
#pragma unroll
    for (int n = 0; n < 8; n++){
      acc[n] = __builtin_amdgcn_mfma_f32_16x16x32_bf16(af, load8bf(Wt + (size_t)(16 * n + l15) * HS + k0), acc[n], 0, 0, 0);
    }
  }
  // add bias, per-row sum of squares (reduce over l15 lanes)
#pragma unroll
  for (int n = 0; n < 8; n++){
    float bv = bias[16 * n + l15];
#pragma unroll
    for (int r = 0; r < 4; r++) acc[n][r] += bv;
  }
  float scl[4];
#pragma unroll
  for (int r = 0; r < 4; r++){
    float ss = 0.f;
#pragma unroll
    for (int n = 0; n < 8; n++) ss += acc[n][r] * acc[n][r];
#pragma unroll
    for (int o = 1; o < 16; o <<= 1) ss += __shfl_xor(ss, o, 64);
    scl[r] = 1.f / fmaxf(sqrtf(ss), 1e-12f);
  }
#pragma unroll
  for (int r = 0; r < 4; r++){
    int ro = base + lg * 4 + r;
    int g = batch_id[ro];
#pragma unroll
    for (int n = 0; n < 8; n++){
      int col = 16 * n + l15;
      float v = acc[n][r] * scl[r];
      brep[(size_t)ro * HS + col] = v;
      atomicAdd(&gsum[g * HS + col], v);
    }
  }
}

// ---- edge meta (all-register, prefetchable)
struct EMeta {
  int r, c;
  float dx, dy, dz, rad;
  ushort8 at;
  ushort8 p[4], q[4];
};

__device__ __forceinline__ EMeta load_meta(
    int e, int lg,
    const int* __restrict__ srow, const int* __restrict__ scol,
    const ushortT* __restrict__ sattr, const float* __restrict__ x,
    const ushortT* __restrict__ Pbf, const ushortT* __restrict__ Qbf){
  EMeta m;
  m.r = srow[e]; m.c = scol[e];
  m.at = __builtin_bit_cast(ushort8, load8bf(sattr + (size_t)e * 32 + lg * 8));
  float xr0 = x[m.r * 3 + 0], xr1 = x[m.r * 3 + 1], xr2 = x[m.r * 3 + 2];
  float xc0 = x[m.c * 3 + 0], xc1 = x[m.c * 3 + 1], xc2 = x[m.c * 3 + 2];
  m.dx = xr0 - xc0; m.dy = xr1 - xc1; m.dz = xr2 - xc2;
  m.rad = m.dx * m.dx + m.dy * m.dy + m.dz * m.dz;
#pragma unroll
  for (int ks = 0; ks < 4; ks++){
    m.p[ks] = __builtin_bit_cast(ushort8, load8bf(Pbf + (size_t)m.r * HS + ks * 32 + lg * 8));
    m.q[ks] = __builtin_bit_cast(ushort8, load8bf(Qbf + (size_t)m.c * HS + ks * 32 + lg * 8));
  }
  return m;
}

// ---- fused edge kernel v4: 64 sorted edges per wave (4 tiles x 16), register meta
// with next-tile prefetch, no per-tile barriers, carried segmented flush.
__global__ __launch_bounds__(256) void edge_kernel(
    const int* __restrict__ srow, const int* __restrict__ scol,
    const ushortT* __restrict__ sattr,
    const float* __restrict__ x,
    const ushortT* __restrict__ Pbf, const ushortT* __restrict__ Qbf,
    const ushortT* __restrict__ W1ct, const ushortT* __restrict__ W2tp,
    const ushortT* __restrict__ CW1tp,
    const float* __restrict__ b2, const float* __restrict__ cb1,
    const float* __restrict__ cw3,
    float* __restrict__ xacc, float* __restrict__ agg){
  __shared__ float bias_l[3][128];
  __shared__ float dif_s[4][16][3];
  __shared__ float wsh_s[4][16];
  __shared__ __align__(16) ushortT s2_s[4][2048];

  const int t = threadIdx.x;
  const int lane = t & 63;
  const int wv = t >> 6;
  const int l15 = lane & 15, lg = lane >> 4;
  if (t < 128){ bias_l[0][t] = b2[t]; bias_l[1][t] = cb1[t]; bias_l[2][t] = cw3[t]; }
  __syncthreads();

  ushortT* S2 = s2_s[wv];
  const int wbase = blockIdx.x * 256 + wv * 64;
  const f32x4 zero = {0.f, 0.f, 0.f, 0.f};

  EMeta cur = load_meta(wbase + l15, lg, srow, scol, sattr, x, Pbf, Qbf);
  int prev = __builtin_amdgcn_readfirstlane(__shfl(cur.r, 0, 64));
  float run0 = 0.f, run1 = 0.f, runc = 0.f;

#pragma unroll
  for (int tt = 0; tt < TILES; tt++){
    EMeta nxt = cur;
    if (tt + 1 < TILES)
      nxt = load_meta(wbase + (tt + 1) * 16 + l15, lg, srow, scol, sattr, x, Pbf, Qbf);

    // --- tail MFMA: accT[n] = W1c @ atail^T  (C col = edge l15, natural chan rows)
    ushort8 at8 = cur.at;
    at8[0] = (lg == 0) ? f2bff(cur.rad) : at8[0];
    bf16x8 atb = __builtin_bit_cast(bf16x8, at8);
    f32x4 accT[8];
#pragma unroll
    for (int n = 0; n < 8; n++){
      bf16x8 wf = load8bf(W1ct + (size_t)(16 * n + l15) * 32 + lg * 8);
      accT[n] = __builtin_amdgcn_mfma_f32_16x16x32_bf16(wf, atb, zero, 0, 0, 0);
    }

    // --- GEMM2 (swapped): m1 = silu(P[r] + Q[c] + tail) built per-ks in pi order
    f32x4 acc2[8];
#pragma unroll
    for (int n = 0; n < 8; n++) acc2[n] = zero;
#pragma unroll
    for (int ks = 0; ks < 4; ks++){
      ushort8 af;
#pragma unroll
      for (int j = 0; j < 8; j++){
        float v = accT[ks * 2 + (j >> 2)][j & 3] + bf2f(cur.p[ks][j]) + bf2f(cur.q[ks][j]);
        af[j] = f2bff(silu(v));
      }
      bf16x8 afb = __builtin_bit_cast(bf16x8, af);
#pragma unroll
      for (int n = 0; n < 8; n++){
        bf16x8 wf = load8bf(W2tp + (size_t)(16 * n + l15) * HS + ks * 32 + lg * 8);
        acc2[n] = __builtin_amdgcn_mfma_f32_16x16x32_bf16(wf, afb, acc2[n], 0, 0, 0);
      }
    }

    // --- m = silu(acc2 + b2): coord B-frags (pi order) + S2 (natural order, swizzled)
    ushort8 mfb[4];
#pragma unroll
    for (int ks = 0; ks < 4; ks++){
      float4 bA = *reinterpret_cast<const float4*>(&bias_l[0][ks * 32 + lg * 4]);
      float4 bB = *reinterpret_cast<const float4*>(&bias_l[0][ks * 32 + 16 + lg * 4]);
      ushort8 mm;
#pragma unroll
      for (int j = 0; j < 4; j++) mm[j]     = f2bff(silu(acc2[2 * ks][j]     + (&bA.x)[j]));
#pragma unroll
      for (int j = 0; j < 4; j++) mm[j + 4] = f2bff(silu(acc2[2 * ks + 1][j] + (&bB.x)[j]));
      mfb[ks] = mm;
      uint4 u = __builtin_bit_cast(uint4, mm);
      int i0 = (l15 * 128 + ks * 32 + lg * 4) ^ ((l15 & 7) << 3);
      int i1 = (l15 * 128 + ks * 32 + 16 + lg * 4) ^ ((l15 & 7) << 3);
      *reinterpret_cast<uint2*>(&S2[i0]) = make_uint2(u.x, u.y);
      *reinterpret_cast<uint2*>(&S2[i1]) = make_uint2(u.z, u.w);
    }

    // --- coord GEMM (swapped) + w reduction
    f32x4 acc3[8];
#pragma unroll
    for (int n = 0; n < 8; n++) acc3[n] = zero;
#pragma unroll
    for (int ks = 0; ks < 4; ks++){
      bf16x8 mb = __builtin_bit_cast(bf16x8, mfb[ks]);
#pragma unroll
      for (int n = 0; n < 8; n++){
        bf16x8 wf = load8bf(CW1tp + (size_t)(16 * n + l15) * HS + ks * 32 + lg * 8);
        acc3[n] = __builtin_amdgcn_mfma_f32_16x16x32_bf16(wf, mb, acc3[n], 0, 0, 0);
      }
    }
    {
      float wsum = 0.f;
#pragma unroll
      for (int n = 0; n < 8; n++){
        float4 cbv = *reinterpret_cast<const float4*>(&bias_l[1][16 * n + lg * 4]);
        float4 cwv = *reinterpret_cast<const float4*>(&bias_l[2][16 * n + lg * 4]);
#pragma unroll
        for (int r = 0; r < 4; r++) wsum += silu(acc3[n][r] + (&cbv.x)[r]) * (&cwv.x)[r];
      }
      wsum += __shfl_xor(wsum, 16, 64);
      wsum += __shfl_xor(wsum, 32, 64);
      if (lg == 0){
        wsh_s[wv][l15] = wsum;
        dif_s[wv][l15][0] = cur.dx; dif_s[wv][l15][1] = cur.dy; dif_s[wv][l15][2] = cur.dz;
      }
    }

    // --- carried segmented flush (agg cols lane & lane+64; xacc lanes 0..2)
#pragma unroll
    for (int e = 0; e < 16; e++){
      int re = __builtin_amdgcn_readfirstlane(__shfl(cur.r, e, 64));
      if (re != prev){
        atomicAdd(&agg[(size_t)prev * HS + lane], run0);
        atomicAdd(&agg[(size_t)prev * HS + 64 + lane], run1);
        if (lane < 3) atomicAdd(&xacc[(size_t)prev * 3 + lane], runc);
        run0 = 0.f; run1 = 0.f; runc = 0.f; prev = re;
      }
      run0 += bf2f(S2[(e * 128 + lane) ^ ((e & 7) << 3)]);
      run1 += bf2f(S2[(e * 128 + 64 + lane) ^ ((e & 7) << 3)]);
      if (lane < 3) runc += dif_s[wv][e][lane] * wsh_s[wv][e];
    }
    cur = nxt;
  }
  atomicAdd(&agg[(size_t)prev * HS + lane], run0);
  atomicAdd(&agg[(size_t)prev * HS + 64 + lane], run1);
  if (lane < 3) atomicAdd(&xacc[(size_t)prev * 3 + lane], runc);
}

__global__ void x_update_kernel(float* __restrict__ x, const float* __restrict__ xacc,
                                const int* __restrict__ estart){
  int i = blockIdx.x * 256 + threadIdx.x;
  if (i < N_BLOCKS * 3){
    int b = i / 3;
    int c = estart[b + 1] - estart[b];
    x[i] += xacc[i] / (float)(c > 0 ? c : 1);
  }
}

__global__ void norm_graph_kernel(const float* __restrict__ gsum, float* __restrict__ grep){
  int wv = threadIdx.x >> 6, lane = threadIdx.x & 63;
  int g = blockIdx.x * 4 + wv;
  if (g >= N_GRAPHS) return;
  float v0 = gsum[g * HS + lane];
  float v1 = gsum[g * HS + 64 + lane];
  float ss = v0 * v0 + v1 * v1;
#pragma unroll
  for (int o = 1; o < 64; o <<= 1) ss += __shfl_xor(ss, o, 64);
  float s = 1.f / fmaxf(sqrtf(ss), 1e-12f);
  grep[(size_t)g * HS + lane] = v0 * s;
  grep[(size_t)g * HS + 64 + lane] = v1 * s;
}

extern "C" void kernel_launch(void* const* d_in, const int* in_sizes, int n_in,
                              void* d_out, int out_size, void* d_ws, size_t ws_size,
                              hipStream_t stream){
  const float* H         = (const float*)d_in[0];
  const float* Z         = (const float*)d_in[1];
  const int*   block_id  = (const int*)d_in[2];
  const int*   batch_id  = (const int*)d_in[3];
  const int*   edges     = (const int*)d_in[4];
  const float* edge_attr = (const float*)d_in[5];
  const float* emb_in_w  = (const float*)d_in[6];
  const float* emb_in_b  = (const float*)d_in[7];
  const float* emb_out_w = (const float*)d_in[8];
  const float* emb_out_b = (const float*)d_in[9];
  const float* edge_w1   = (const float*)d_in[10];
  const float* edge_b1   = (const float*)d_in[11];
  const float* edge_w2   = (const float*)d_in[12];
  const float* edge_b2   = (const float*)d_in[13];
  const float* node_w1   = (const float*)d_in[14];
  const float* node_b1   = (const float*)d_in[15];
  const float* node_w2   = (const float*)d_in[16];
  const float* node_b2   = (const float*)d_in[17];
  const float* coord_w1  = (const float*)d_in[18];
  const float* coord_b1  = (const float*)d_in[19];
  const float* coord_w3  = (const float*)d_in[20];

  float* out  = (float*)d_out;
  float* Hm   = out;                               // [16000 x 128]
  float* brep = out + (size_t)N_BLOCKS * HS;       // [16000 x 128]
  float* grep = out + (size_t)2 * N_BLOCKS * HS;   // [128 x 128]

  char* base = (char*)d_ws;
  size_t off = 0;
  auto take = [&](size_t bytes) -> char* {
    char* p = base + off;
    off += (bytes + 255) & ~(size_t)255;
    return p;
  };
  float*   x     = (float*)  take((size_t)N_BLOCKS * 3 * 4);
  float*   xacc  = (float*)  take((size_t)N_BLOCKS * 3 * 4);
  float*   h     = (float*)  take((size_t)N_BLOCKS * HS * 4);
  float*   agg   = (float*)  take((size_t)N_BLOCKS * HS * 4);
  float*   gsum  = (float*)  take((size_t)N_GRAPHS * HS * 4);
  int*     bstart= (int*)    take((size_t)(N_BLOCKS + 1) * 4);
  int*     hist  = (int*)    take((size_t)N_BLOCKS * 4);
  int*     estart= (int*)    take((size_t)(N_BLOCKS + 1) * 4);
  int*     ecur  = (int*)    take((size_t)N_BLOCKS * 4);
  int*     srow  = (int*)    take((size_t)N_EDGES * 4);
  int*     scol  = (int*)    take((size_t)N_EDGES * 4);
  ushortT* sattr = (ushortT*)take((size_t)N_EDGES * 32 * 2);
  ushortT* Pbf   = (ushortT*)take((size_t)N_BLOCKS * HS * 2);
  ushortT* Qbf   = (ushortT*)take((size_t)N_BLOCKS * HS * 2);
  ushortT* W1atp = (ushortT*)take((size_t)3 * 128 * 128 * 2);
  ushortT* W1btp = (ushortT*)take((size_t)3 * 128 * 128 * 2);
  ushortT* W1ct  = (ushortT*)take((size_t)3 * 128 * 32 * 2);
  ushortT* W2tp  = (ushortT*)take((size_t)3 * 128 * 128 * 2);
  ushortT* CW1tp = (ushortT*)take((size_t)3 * 128 * 128 * 2);
  ushortT* NW1t  = (ushortT*)take((size_t)3 * 128 * 256 * 2);
  ushortT* NW2t  = (ushortT*)take((size_t)3 * 128 * 128 * 2);
  ushortT* Eint  = (ushortT*)take((size_t)128 * 128 * 2);
  ushortT* Eoutt = (ushortT*)take((size_t)128 * 128 * 2);
  float*   b1p   = (float*)  take((size_t)3 * 128 * 4);

  // weight prep
  transpose_cvt_kernel<<<(3*128*128 + 255)/256, 256, 0, stream>>>(edge_w1, W1atp, 273,   0, 128, 128, 128, 3, 1, 0);
  transpose_cvt_kernel<<<(3*128*128 + 255)/256, 256, 0, stream>>>(edge_w1, W1btp, 273, 128, 128, 128, 128, 3, 1, 0);
  transpose_cvt_kernel<<<(3*128*32  + 255)/256, 256, 0, stream>>>(edge_w1, W1ct,  273, 256,  17, 128,  32, 3, 0, 0);
  transpose_cvt_kernel<<<(3*128*128 + 255)/256, 256, 0, stream>>>(edge_w2, W2tp,  128,   0, 128, 128, 128, 3, 0, 1);
  transpose_cvt_kernel<<<(3*128*128 + 255)/256, 256, 0, stream>>>(coord_w1, CW1tp,128,   0, 128, 128, 128, 3, 0, 1);
  transpose_cvt_kernel<<<(3*128*256 + 255)/256, 256, 0, stream>>>(node_w1, NW1t,  256,   0, 256, 128, 256, 3, 0, 0);
  transpose_cvt_kernel<<<(3*128*128 + 255)/256, 256, 0, stream>>>(node_w2, NW2t,  128,   0, 128, 128, 128, 3, 0, 0);
  transpose_cvt_kernel<<<(128*128 + 255)/256, 256, 0, stream>>>(emb_in_w,  Eint,  128,   0, 128, 128, 128, 1, 0, 0);
  transpose_cvt_kernel<<<(128*128 + 255)/256, 256, 0, stream>>>(emb_out_w, Eoutt, 128,   0, 128, 128, 128, 1, 0, 0);
  perm_bias_kernel<<<2, 256, 0, stream>>>(edge_b1, b1p, 3);

  // edge counting-sort by row
  hipMemsetAsync(hist, 0, (size_t)N_BLOCKS * 4, stream);
  hist_kernel<<<N_EDGES / 256, 256, 0, stream>>>(edges, hist);
  scan_kernel<<<1, 256, 0, stream>>>(hist, estart, ecur);
  scatter_kernel<<<N_EDGES / 256, 256, 0, stream>>>(edges, edge_attr, ecur, srow, scol, sattr);

  block_start_kernel<<<(N_BLOCKS + 1 + 255) / 256, 256, 0, stream>>>(block_id, bstart);
  pool_kernel<<<N_BLOCKS, 128, 0, stream>>>(H, Z, bstart, Hm, x);

  // h = Hm @ emb_in_w + b
  gemm_kernel<<<N_BLOCKS / 64, 256, 0, stream>>>(Hm, Eint, emb_in_b, h);

  for (int l = 0; l < 3; l++){
    pq_kernel<<<N_BLOCKS / 64, 256, 0, stream>>>(h, W1atp + (size_t)l * 128 * 128,
                                                 W1btp + (size_t)l * 128 * 128,
                                                 b1p + l * 128, Pbf, Qbf);
    hipMemsetAsync(agg, 0, (size_t)N_BLOCKS * HS * 4, stream);
    hipMemsetAsync(xacc, 0, (size_t)N_BLOCKS * 3 * 4, stream);
    edge_kernel<<<N_EDGES / 256, 256, 0, stream>>>(
        srow, scol, sattr, x, Pbf, Qbf,
        W1ct + (size_t)l * 128 * 32, W2tp + (size_t)l * 128 * 128, CW1tp + (size_t)l * 128 * 128,
        edge_b2 + l * 128, coord_b1 + l * 128, coord_w3 + l * 128,
        xacc, agg);
    x_update_kernel<<<(N_BLOCKS * 3 + 255) / 256, 256, 0, stream>>>(x, xacc, estart);
    node_kernel<<<N_BLOCKS / 64, 256, 0, stream>>>(h, agg, NW1t + (size_t)l * 128 * 256,
                                                   NW2t + (size_t)l * 128 * 128,
                                                   node_b1 + l * 128, node_b2 + l * 128);
  }

  hipMemsetAsync(gsum, 0, (size_t)N_GRAPHS * HS * 4, stream);
  emb_norm_kernel<<<N_BLOCKS / 64, 256, 0, stream>>>(h, Eoutt, emb_out_b, batch_id, brep, gsum);
  norm_graph_kernel<<<N_GRAPHS / 4, 256, 0, stream>>>(gsum, grep);
}

// Round 6
// 799.171 us; speedup vs baseline: 1.5765x; 1.2296x over previous
//
#include <hip/hip_runtime.h>

#define N_ATOMS  80000
#define N_BLOCKS 16000
#define N_EDGES  320000
#define N_GRAPHS 128
#define HS       128

typedef unsigned short ushortT;
typedef __attribute__((ext_vector_type(8))) __bf16 bf16x8;
typedef __attribute__((ext_vector_type(8))) unsigned short ushort8;
typedef __attribute__((ext_vector_type(4))) float f32x4;

__device__ __forceinline__ unsigned short f2bf(float f){
  unsigned int u = __builtin_bit_cast(unsigned int, f);
  u = (u + 0x7FFFu + ((u >> 16) & 1u)) >> 16;
  return (unsigned short)u;
}
// native cvt (RNE on gfx950)
__device__ __forceinline__ ushortT f2bff(float f){
  __bf16 b = (__bf16)f;
  return __builtin_bit_cast(ushortT, b);
}
__device__ __forceinline__ float bf2f(ushortT u){
  unsigned int v = ((unsigned int)u) << 16;
  return __builtin_bit_cast(float, v);
}
__device__ __forceinline__ bf16x8 load8bf(const ushortT* p){
  uint4 u = *reinterpret_cast<const uint4*>(p);
  return __builtin_bit_cast(bf16x8, u);
}
__device__ __forceinline__ bf16x8 load8f_bf(const float* p){
  float4 a = *reinterpret_cast<const float4*>(p);
  float4 b = *reinterpret_cast<const float4*>(p + 4);
  ushort8 u = { f2bff(a.x), f2bff(a.y), f2bff(a.z), f2bff(a.w),
                f2bff(b.x), f2bff(b.y), f2bff(b.z), f2bff(b.w) };
  return __builtin_bit_cast(bf16x8, u);
}
__device__ __forceinline__ float silu(float v){ return v / (1.f + __expf(-v)); }

// pi-permutation: C-fragment register (n,r) of lane-group lg holds natural col
// c = 16n + lg*4 + r; B-fragment position p = ks*32 + lg*8 + j, n = 2ks + (j>>2), r = j&3.
__device__ __forceinline__ int c_of_p(int p){
  int ks = p >> 5, lg = (p >> 3) & 3, j = p & 7;
  return 16 * (ks * 2 + (j >> 2)) + lg * 4 + (j & 3);
}

// ---- weight transpose + bf16 convert
__global__ void transpose_cvt_kernel(const float* __restrict__ src, ushortT* __restrict__ dst,
                                     int srcK, int row_off, int K, int N, int Kpad, int L,
                                     int perm_n, int perm_k){
  int idx = blockIdx.x * 256 + threadIdx.x;
  int tot = L * N * Kpad;
  if (idx >= tot) return;
  int k = idx % Kpad;
  int rem = idx / Kpad;
  int n = rem % N;
  int l = rem / N;
  float v = 0.f;
  if (k < K){
    int kk = perm_k ? c_of_p(k) : k;
    int nn = perm_n ? c_of_p(n) : n;
    v = src[((size_t)l * srcK + row_off + kk) * N + nn];
  }
  dst[idx] = f2bf(v);
}

__global__ void perm_bias_kernel(const float* __restrict__ src, float* __restrict__ dst, int L){
  int i = blockIdx.x * 256 + threadIdx.x;
  if (i >= L * 128) return;
  int l = i >> 7, p = i & 127;
  dst[i] = src[l * 128 + c_of_p(p)];
}

__global__ void block_start_kernel(const int* __restrict__ bid, int* __restrict__ start){
  int b = blockIdx.x * 256 + threadIdx.x;
  if (b > N_BLOCKS) return;
  int lo = 0, hi = N_ATOMS;
  while (lo < hi){ int mid = (lo + hi) >> 1; if (bid[mid] < b) lo = mid + 1; else hi = mid; }
  start[b] = lo;
}

__global__ void hist_kernel(const int* __restrict__ edges, int* __restrict__ hist){
  int e = blockIdx.x * 256 + threadIdx.x;
  if (e < N_EDGES) atomicAdd(&hist[edges[e]], 1);
}

__global__ void scan_kernel(const int* __restrict__ hist, int* __restrict__ estart,
                            int* __restrict__ ecur){
  __shared__ int ps[256];
  int t = threadIdx.x;
  const int chunk = (N_BLOCKS + 255) / 256;
  int lo = t * chunk, hi = lo + chunk;
  if (hi > N_BLOCKS) hi = N_BLOCKS;
  int s = 0;
  for (int i = lo; i < hi; i++) s += hist[i];
  ps[t] = s;
  __syncthreads();
  for (int off = 1; off < 256; off <<= 1){
    int v = (t >= off) ? ps[t - off] : 0;
    __syncthreads();
    ps[t] += v;
    __syncthreads();
  }
  int base = (t == 0) ? 0 : ps[t - 1];
  for (int i = lo; i < hi; i++){ estart[i] = base; ecur[i] = base; base += hist[i]; }
  if (t == 255) estart[N_BLOCKS] = base;
}

// scatter into sorted order; sattr padded: 32 u16/edge = [0, attr0..15, 0 x15]
__global__ void scatter_kernel(const int* __restrict__ edges, const float* __restrict__ attr,
                               int* __restrict__ ecur,
                               int* __restrict__ srow, int* __restrict__ scol,
                               ushortT* __restrict__ sattr){
  int e = blockIdx.x * 256 + threadIdx.x;
  if (e >= N_EDGES) return;
  int r = edges[e], c = edges[N_EDGES + e];
  int p = atomicAdd(&ecur[r], 1);
  srow[p] = r; scol[p] = c;
  ushortT buf[32];
  buf[0] = 0;
#pragma unroll
  for (int k = 0; k < 16; k++) buf[k + 1] = f2bf(attr[(size_t)e * 16 + k]);
#pragma unroll
  for (int k = 17; k < 32; k++) buf[k] = 0;
#pragma unroll
  for (int k = 0; k < 16; k++)
    reinterpret_cast<uint*>(sattr + (size_t)p * 32)[k] = reinterpret_cast<uint*>(buf)[k];
}

__global__ void pool_kernel(const float* __restrict__ H, const float* __restrict__ Z,
                            const int* __restrict__ start,
                            float* __restrict__ Hm, float* __restrict__ x){
  int b = blockIdx.x;
  int t = threadIdx.x;            // 128 threads
  int s = start[b], e = start[b + 1];
  float inv = 1.f / (float)((e - s) > 0 ? (e - s) : 1);
  float sum = 0.f;
  for (int a = s; a < e; a++) sum += H[(size_t)a * HS + t];
  Hm[(size_t)b * HS + t] = sum * inv;
  if (t < 3){
    float sz = 0.f;
    for (int a = s; a < e; a++) sz += Z[a * 3 + t];
    x[b * 3 + t] = sz * inv;
  }
}

// ---- generic MFMA GEMM (used for emb_in only)
__global__ __launch_bounds__(256) void gemm_kernel(
    const float* __restrict__ A,
    const ushortT* __restrict__ Wt, const float* __restrict__ bias,
    float* __restrict__ Cf){
  int t = threadIdx.x; int lane = t & 63; int wv = t >> 6;
  int l15 = lane & 15, lg = lane >> 4;
  int base = blockIdx.x * 64 + wv * 16;
  f32x4 zero = {0.f, 0.f, 0.f, 0.f};
  f32x4 acc[8];
#pragma unroll
  for (int n = 0; n < 8; n++) acc[n] = zero;
  int row = base + l15;
#pragma unroll
  for (int ks = 0; ks < 4; ks++){
    int k0 = ks * 32 + lg * 8;
    bf16x8 af = load8f_bf(A + (size_t)row * HS + k0);
#pragma unroll
    for (int n = 0; n < 8; n++){
      bf16x8 bf = load8bf(Wt + (size_t)(16 * n + l15) * HS + k0);
      acc[n] = __builtin_amdgcn_mfma_f32_16x16x32_bf16(af, bf, acc[n], 0, 0, 0);
    }
  }
#pragma unroll
  for (int n = 0; n < 8; n++){
    int col = 16 * n + l15;
    float bv = bias[col];
#pragma unroll
    for (int r = 0; r < 4; r++){
      int ro = base + lg * 4 + r;
      Cf[(size_t)ro * HS + col] = acc[n][r] + bv;
    }
  }
}

// ---- fused P/Q kernel: P = h@W1a + b1 (pi cols), Q = h@W1b (pi cols), bf16 out.
// Also zeroes this block's 64-row slice of agg and xacc (replaces memsets).
__global__ __launch_bounds__(256) void pq_kernel(
    const float* __restrict__ h,
    const ushortT* __restrict__ Wa, const ushortT* __restrict__ Wb,
    const float* __restrict__ b1p,
    ushortT* __restrict__ Pbf, ushortT* __restrict__ Qbf,
    float* __restrict__ agg, float* __restrict__ xacc){
  int t = threadIdx.x; int lane = t & 63; int wv = t >> 6;
  int l15 = lane & 15, lg = lane >> 4;
  int base = blockIdx.x * 64 + wv * 16;
  int row = base + l15;
  // zero agg slice [blockIdx*64, +64) x 128 and xacc slice
  {
    float4 z4 = {0.f, 0.f, 0.f, 0.f};
    float4* aggp = reinterpret_cast<float4*>(agg + (size_t)blockIdx.x * 64 * HS);
#pragma unroll
    for (int i = 0; i < 8; i++) aggp[t + 256 * i] = z4;
    if (t < 192) xacc[blockIdx.x * 192 + t] = 0.f;
  }
  f32x4 zero = {0.f, 0.f, 0.f, 0.f};
  f32x4 accp[8], accq[8];
#pragma unroll
  for (int n = 0; n < 8; n++){ accp[n] = zero; accq[n] = zero; }
#pragma unroll
  for (int ks = 0; ks < 4; ks++){
    int k0 = ks * 32 + lg * 8;
    bf16x8 af = load8f_bf(h + (size_t)row * HS + k0);
#pragma unroll
    for (int n = 0; n < 8; n++){
      accp[n] = __builtin_amdgcn_mfma_f32_16x16x32_bf16(af, load8bf(Wa + (size_t)(16 * n + l15) * HS + k0), accp[n], 0, 0, 0);
      accq[n] = __builtin_amdgcn_mfma_f32_16x16x32_bf16(af, load8bf(Wb + (size_t)(16 * n + l15) * HS + k0), accq[n], 0, 0, 0);
    }
  }
#pragma unroll
  for (int n = 0; n < 8; n++){
    int col = 16 * n + l15;
    float bv = b1p[col];
#pragma unroll
    for (int r = 0; r < 4; r++){
      int ro = base + lg * 4 + r;
      Pbf[(size_t)ro * HS + col] = f2bff(accp[n][r] + bv);
      Qbf[(size_t)ro * HS + col] = f2bff(accq[n][r]);
    }
  }
}

// ---- fused node MLP: h += silu([h|agg]@W1 + b1) @ W2 + b2  (in place, rows wave-exclusive)
__global__ __launch_bounds__(256) void node_kernel(
    float* h, const float* __restrict__ agg,
    const ushortT* __restrict__ W1t, const ushortT* __restrict__ W2t,
    const float* __restrict__ b1, const float* __restrict__ b2){
  __shared__ __align__(16) ushortT t1_s[4][2048];
  int t = threadIdx.x; int lane = t & 63; int wv = t >> 6;
  int l15 = lane & 15, lg = lane >> 4;
  int base = blockIdx.x * 64 + wv * 16;
  int row = base + l15;
  ushortT* T1 = t1_s[wv];
  f32x4 zero = {0.f, 0.f, 0.f, 0.f};
  f32x4 acc[8];
#pragma unroll
  for (int n = 0; n < 8; n++) acc[n] = zero;
#pragma unroll
  for (int ks = 0; ks < 8; ks++){
    int k0 = ks * 32 + lg * 8;
    bf16x8 af = (k0 < 128) ? load8f_bf(h + (size_t)row * HS + k0)
                           : load8f_bf(agg + (size_t)row * HS + (k0 - 128));
#pragma unroll
    for (int n = 0; n < 8; n++){
      acc[n] = __builtin_amdgcn_mfma_f32_16x16x32_bf16(af, load8bf(W1t + (size_t)(16 * n + l15) * 256 + k0), acc[n], 0, 0, 0);
    }
  }
#pragma unroll
  for (int n = 0; n < 8; n++){
    int col = 16 * n + l15;
    float bv = b1[col];
#pragma unroll
    for (int r = 0; r < 4; r++){
      int er = lg * 4 + r;
      T1[(er * 128 + col) ^ ((er & 7) << 3)] = f2bff(silu(acc[n][r] + bv));
    }
  }
#pragma unroll
  for (int n = 0; n < 8; n++) acc[n] = zero;
#pragma unroll
  for (int ks = 0; ks < 4; ks++){
    int k0 = ks * 32 + lg * 8;
    bf16x8 af = load8bf(&T1[(l15 * 128 + k0) ^ ((l15 & 7) << 3)]);
#pragma unroll
    for (int n = 0; n < 8; n++){
      acc[n] = __builtin_amdgcn_mfma_f32_16x16x32_bf16(af, load8bf(W2t + (size_t)(16 * n + l15) * HS + k0), acc[n], 0, 0, 0);
    }
  }
#pragma unroll
  for (int n = 0; n < 8; n++){
    int col = 16 * n + l15;
    float bv = b2[col];
#pragma unroll
    for (int r = 0; r < 4; r++){
      int ro = base + lg * 4 + r;
      h[(size_t)ro * HS + col] += acc[n][r] + bv;
    }
  }
}

// ---- fused emb_out GEMM + block normalize + graph accumulate
__global__ __launch_bounds__(256) void emb_norm_kernel(
    const float* __restrict__ h, const ushortT* __restrict__ Wt,
    const float* __restrict__ bias, const int* __restrict__ batch_id,
    float* __restrict__ brep, float* __restrict__ gsum){
  int t = threadIdx.x; int lane = t & 63; int wv = t >> 6;
  int l15 = lane & 15, lg = lane >> 4;
  int base = blockIdx.x * 64 + wv * 16;
  int row = base + l15;
  f32x4 zero = {0.f, 0.f, 0.f, 0.f};
  f32x4 acc[8];
#pragma unroll
  for (int n = 0; n < 8; n++) acc[n] = zero;
#pragma unroll
  for (int ks = 0; ks < 4; ks++){
    int k0 = ks * 32 + lg * 8;
    bf16x8 af = load8f_bf(h + (size_t)row * HS + k0);
#pragma unroll
    for (int n = 0; n < 8; n++){
      acc[n] = __builtin_amdgcn_mfma_f32_16x16x32_bf16(af, load8bf(Wt + (size_t)(16 * n + l15) * HS + k0), acc[n], 0, 0, 0);
    }
  }
#pragma unroll
  for (int n = 0; n < 8; n++){
    float bv = bias[16 * n + l15];
#pragma unroll
    for (int r = 0; r < 4; r++) acc[n][r] += bv;
  }
  float scl[4];
#pragma unroll
  for (int r = 0; r < 4; r++){
    float ss = 0.f;
#pragma unroll
    for (int n = 0; n < 8; n++) ss += acc[n][r] * acc[n][r];
#pragma unroll
    for (int o = 1; o < 16; o <<= 1) ss += __shfl_xor(ss, o, 64);
    scl[r] = 1.f / fmaxf(sqrtf(ss), 1e-12f);
  }
#pragma unroll
  for (int r = 0; r < 4; r++){
    int ro = base + lg * 4 + r;
    int g = batch_id[ro];
#pragma unroll
    for (int n = 0; n < 8; n++){
      int col = 16 * n + l15;
      float v = acc[n][r] * scl[r];
      brep[(size_t)ro * HS + col] = v;
      atomicAdd(&gsum[g * HS + col], v);
    }
  }
}

// ---- fused edge kernel v5: 16 edges/wave, per-ks tail interleave, P/Q loaded per-ks,
// minimal registers, no barriers after bias stage, segmented atomic flush.
__global__ __launch_bounds__(256, 4) void edge_kernel(
    const int* __restrict__ srow, const int* __restrict__ scol,
    const ushortT* __restrict__ sattr,
    const float* __restrict__ x,
    const ushortT* __restrict__ Pbf, const ushortT* __restrict__ Qbf,
    const ushortT* __restrict__ W1ct, const ushortT* __restrict__ W2tp,
    const ushortT* __restrict__ CW1tp,
    const float* __restrict__ b2, const float* __restrict__ cb1,
    const float* __restrict__ cw3,
    float* __restrict__ xacc, float* __restrict__ agg){
  __shared__ float bias_l[3][128];
  __shared__ float dif_s[4][16][3];
  __shared__ float wsh_s[4][16];
  __shared__ __align__(16) ushortT s2_s[4][2048];

  const int t = threadIdx.x;
  const int lane = t & 63;
  const int wv = t >> 6;
  const int l15 = lane & 15, lg = lane >> 4;
  if (t < 128){ bias_l[0][t] = b2[t]; bias_l[1][t] = cb1[t]; bias_l[2][t] = cw3[t]; }
  __syncthreads();

  ushortT* S2 = s2_s[wv];
  const int e = blockIdx.x * 64 + wv * 16 + l15;   // this lane's edge
  const f32x4 zero = {0.f, 0.f, 0.f, 0.f};

  const int r = srow[e], c = scol[e];
  const float dx = x[r * 3 + 0] - x[c * 3 + 0];
  const float dy = x[r * 3 + 1] - x[c * 3 + 1];
  const float dz = x[r * 3 + 2] - x[c * 3 + 2];
  const float rad = dx * dx + dy * dy + dz * dz;
  ushort8 at8 = __builtin_bit_cast(ushort8, load8bf(sattr + (size_t)e * 32 + lg * 8));
  if (lg == 0) at8[0] = f2bff(rad);
  const bf16x8 atb = __builtin_bit_cast(bf16x8, at8);

  // --- GEMM2 (swapped) with per-ks tail MFMA + P/Q fragment loads
  f32x4 acc2[8];
#pragma unroll
  for (int n = 0; n < 8; n++) acc2[n] = zero;
#pragma unroll
  for (int ks = 0; ks < 4; ks++){
    f32x4 a0 = __builtin_amdgcn_mfma_f32_16x16x32_bf16(
        load8bf(W1ct + (size_t)(16 * (2 * ks)     + l15) * 32 + lg * 8), atb, zero, 0, 0, 0);
    f32x4 a1 = __builtin_amdgcn_mfma_f32_16x16x32_bf16(
        load8bf(W1ct + (size_t)(16 * (2 * ks + 1) + l15) * 32 + lg * 8), atb, zero, 0, 0, 0);
    ushort8 pv = __builtin_bit_cast(ushort8, load8bf(Pbf + (size_t)r * HS + ks * 32 + lg * 8));
    ushort8 qv = __builtin_bit_cast(ushort8, load8bf(Qbf + (size_t)c * HS + ks * 32 + lg * 8));
    ushort8 af;
#pragma unroll
    for (int j = 0; j < 4; j++)
      af[j] = f2bff(silu(a0[j] + bf2f(pv[j]) + bf2f(qv[j])));
#pragma unroll
    for (int j = 4; j < 8; j++)
      af[j] = f2bff(silu(a1[j - 4] + bf2f(pv[j]) + bf2f(qv[j])));
    bf16x8 afb = __builtin_bit_cast(bf16x8, af);
#pragma unroll
    for (int n = 0; n < 8; n++){
      bf16x8 wf = load8bf(W2tp + (size_t)(16 * n + l15) * HS + ks * 32 + lg * 8);
      acc2[n] = __builtin_amdgcn_mfma_f32_16x16x32_bf16(wf, afb, acc2[n], 0, 0, 0);
    }
  }

  // --- m = silu(acc2 + b2): coord B-frags (pi order) + S2 (natural order, swizzled)
  ushort8 mfb[4];
#pragma unroll
  for (int ks = 0; ks < 4; ks++){
    float4 bA = *reinterpret_cast<const float4*>(&bias_l[0][ks * 32 + lg * 4]);
    float4 bB = *reinterpret_cast<const float4*>(&bias_l[0][ks * 32 + 16 + lg * 4]);
    ushort8 mm;
#pragma unroll
    for (int j = 0; j < 4; j++) mm[j]     = f2bff(silu(acc2[2 * ks][j]     + (&bA.x)[j]));
#pragma unroll
    for (int j = 0; j < 4; j++) mm[j + 4] = f2bff(silu(acc2[2 * ks + 1][j] + (&bB.x)[j]));
    mfb[ks] = mm;
    uint4 u = __builtin_bit_cast(uint4, mm);
    int i0 = (l15 * 128 + ks * 32 + lg * 4) ^ ((l15 & 7) << 3);
    int i1 = (l15 * 128 + ks * 32 + 16 + lg * 4) ^ ((l15 & 7) << 3);
    *reinterpret_cast<uint2*>(&S2[i0]) = make_uint2(u.x, u.y);
    *reinterpret_cast<uint2*>(&S2[i1]) = make_uint2(u.z, u.w);
  }

  // --- coord GEMM (swapped) + w reduction
  f32x4 acc3[8];
#pragma unroll
  for (int n = 0; n < 8; n++) acc3[n] = zero;
#pragma unroll
  for (int ks = 0; ks < 4; ks++){
    bf16x8 mb = __builtin_bit_cast(bf16x8, mfb[ks]);
#pragma unroll
    for (int n = 0; n < 8; n++){
      bf16x8 wf = load8bf(CW1tp + (size_t)(16 * n + l15) * HS + ks * 32 + lg * 8);
      acc3[n] = __builtin_amdgcn_mfma_f32_16x16x32_bf16(wf, mb, acc3[n], 0, 0, 0);
    }
  }
  {
    float wsum = 0.f;
#pragma unroll
    for (int n = 0; n < 8; n++){
      float4 cbv = *reinterpret_cast<const float4*>(&bias_l[1][16 * n + lg * 4]);
      float4 cwv = *reinterpret_cast<const float4*>(&bias_l[2][16 * n + lg * 4]);
#pragma unroll
      for (int rr = 0; rr < 4; rr++) wsum += silu(acc3[n][rr] + (&cbv.x)[rr]) * (&cwv.x)[rr];
    }
    wsum += __shfl_xor(wsum, 16, 64);
    wsum += __shfl_xor(wsum, 32, 64);
    if (lg == 0){
      wsh_s[wv][l15] = wsum;
      dif_s[wv][l15][0] = dx; dif_s[wv][l15][1] = dy; dif_s[wv][l15][2] = dz;
    }
  }

  // --- segmented flush (agg cols lane & lane+64; xacc lanes 0..2)
  {
    float run0 = 0.f, run1 = 0.f, runc = 0.f;
    int prev = __builtin_amdgcn_readfirstlane(__shfl(r, 0, 64));
#pragma unroll
    for (int e2 = 0; e2 < 16; e2++){
      int re = __builtin_amdgcn_readfirstlane(__shfl(r, e2, 64));
      if (re != prev){
        atomicAdd(&agg[(size_t)prev * HS + lane], run0);
        atomicAdd(&agg[(size_t)prev * HS + 64 + lane], run1);
        if (lane < 3) atomicAdd(&xacc[(size_t)prev * 3 + lane], runc);
        run0 = 0.f; run1 = 0.f; runc = 0.f; prev = re;
      }
      run0 += bf2f(S2[(e2 * 128 + lane) ^ ((e2 & 7) << 3)]);
      run1 += bf2f(S2[(e2 * 128 + 64 + lane) ^ ((e2 & 7) << 3)]);
      if (lane < 3) runc += dif_s[wv][e2][lane] * wsh_s[wv][e2];
    }
    atomicAdd(&agg[(size_t)prev * HS + lane], run0);
    atomicAdd(&agg[(size_t)prev * HS + 64 + lane], run1);
    if (lane < 3) atomicAdd(&xacc[(size_t)prev * 3 + lane], runc);
  }
}

__global__ void x_update_kernel(float* __restrict__ x, const float* __restrict__ xacc,
                                const int* __restrict__ estart){
  int i = blockIdx.x * 256 + threadIdx.x;
  if (i < N_BLOCKS * 3){
    int b = i / 3;
    int c = estart[b + 1] - estart[b];
    x[i] += xacc[i] / (float)(c > 0 ? c : 1);
  }
}

__global__ void norm_graph_kernel(const float* __restrict__ gsum, float* __restrict__ grep){
  int wv = threadIdx.x >> 6, lane = threadIdx.x & 63;
  int g = blockIdx.x * 4 + wv;
  if (g >= N_GRAPHS) return;
  float v0 = gsum[g * HS + lane];
  float v1 = gsum[g * HS + 64 + lane];
  float ss = v0 * v0 + v1 * v1;
#pragma unroll
  for (int o = 1; o < 64; o <<= 1) ss += __shfl_xor(ss, o, 64);
  float s = 1.f / fmaxf(sqrtf(ss), 1e-12f);
  grep[(size_t)g * HS + lane] = v0 * s;
  grep[(size_t)g * HS + 64 + lane] = v1 * s;
}

extern "C" void kernel_launch(void* const* d_in, const int* in_sizes, int n_in,
                              void* d_out, int out_size, void* d_ws, size_t ws_size,
                              hipStream_t stream){
  const float* H         = (const float*)d_in[0];
  const float* Z         = (const float*)d_in[1];
  const int*   block_id  = (const int*)d_in[2];
  const int*   batch_id  = (const int*)d_in[3];
  const int*   edges     = (const int*)d_in[4];
  const float* edge_attr = (const float*)d_in[5];
  const float* emb_in_w  = (const float*)d_in[6];
  const float* emb_in_b  = (const float*)d_in[7];
  const float* emb_out_w = (const float*)d_in[8];
  const float* emb_out_b = (const float*)d_in[9];
  const float* edge_w1   = (const float*)d_in[10];
  const float* edge_b1   = (const float*)d_in[11];
  const float* edge_w2   = (const float*)d_in[12];
  const float* edge_b2   = (const float*)d_in[13];
  const float* node_w1   = (const float*)d_in[14];
  const float* node_b1   = (const float*)d_in[15];
  const float* node_w2   = (const float*)d_in[16];
  const float* node_b2   = (const float*)d_in[17];
  const float* coord_w1  = (const float*)d_in[18];
  const float* coord_b1  = (const float*)d_in[19];
  const float* coord_w3  = (const float*)d_in[20];

  float* out  = (float*)d_out;
  float* Hm   = out;                               // [16000 x 128]
  float* brep = out + (size_t)N_BLOCKS * HS;       // [16000 x 128]
  float* grep = out + (size_t)2 * N_BLOCKS * HS;   // [128 x 128]

  char* base = (char*)d_ws;
  size_t off = 0;
  auto take = [&](size_t bytes) -> char* {
    char* p = base + off;
    off += (bytes + 255) & ~(size_t)255;
    return p;
  };
  float*   x     = (float*)  take((size_t)N_BLOCKS * 3 * 4);
  float*   xacc  = (float*)  take((size_t)N_BLOCKS * 3 * 4);
  float*   h     = (float*)  take((size_t)N_BLOCKS * HS * 4);
  float*   agg   = (float*)  take((size_t)N_BLOCKS * HS * 4);
  float*   gsum  = (float*)  take((size_t)N_GRAPHS * HS * 4);
  int*     bstart= (int*)    take((size_t)(N_BLOCKS + 1) * 4);
  int*     hist  = (int*)    take((size_t)N_BLOCKS * 4);
  int*     estart= (int*)    take((size_t)(N_BLOCKS + 1) * 4);
  int*     ecur  = (int*)    take((size_t)N_BLOCKS * 4);
  int*     srow  = (int*)    take((size_t)N_EDGES * 4);
  int*     scol  = (int*)    take((size_t)N_EDGES * 4);
  ushortT* sattr = (ushortT*)take((size_t)N_EDGES * 32 * 2);
  ushortT* Pbf   = (ushortT*)take((size_t)N_BLOCKS * HS * 2);
  ushortT* Qbf   = (ushortT*)take((size_t)N_BLOCKS * HS * 2);
  ushortT* W1atp = (ushortT*)take((size_t)3 * 128 * 128 * 2);
  ushortT* W1btp = (ushortT*)take((size_t)3 * 128 * 128 * 2);
  ushortT* W1ct  = (ushortT*)take((size_t)3 * 128 * 32 * 2);
  ushortT* W2tp  = (ushortT*)take((size_t)3 * 128 * 128 * 2);
  ushortT* CW1tp = (ushortT*)take((size_t)3 * 128 * 128 * 2);
  ushortT* NW1t  = (ushortT*)take((size_t)3 * 128 * 256 * 2);
  ushortT* NW2t  = (ushortT*)take((size_t)3 * 128 * 128 * 2);
  ushortT* Eint  = (ushortT*)take((size_t)128 * 128 * 2);
  ushortT* Eoutt = (ushortT*)take((size_t)128 * 128 * 2);
  float*   b1p   = (float*)  take((size_t)3 * 128 * 4);

  // weight prep
  transpose_cvt_kernel<<<(3*128*128 + 255)/256, 256, 0, stream>>>(edge_w1, W1atp, 273,   0, 128, 128, 128, 3, 1, 0);
  transpose_cvt_kernel<<<(3*128*128 + 255)/256, 256, 0, stream>>>(edge_w1, W1btp, 273, 128, 128, 128, 128, 3, 1, 0);
  transpose_cvt_kernel<<<(3*128*32  + 255)/256, 256, 0, stream>>>(edge_w1, W1ct,  273, 256,  17, 128,  32, 3, 0, 0);
  transpose_cvt_kernel<<<(3*128*128 + 255)/256, 256, 0, stream>>>(edge_w2, W2tp,  128,   0, 128, 128, 128, 3, 0, 1);
  transpose_cvt_kernel<<<(3*128*128 + 255)/256, 256, 0, stream>>>(coord_w1, CW1tp,128,   0, 128, 128, 128, 3, 0, 1);
  transpose_cvt_kernel<<<(3*128*256 + 255)/256, 256, 0, stream>>>(node_w1, NW1t,  256,   0, 256, 128, 256, 3, 0, 0);
  transpose_cvt_kernel<<<(3*128*128 + 255)/256, 256, 0, stream>>>(node_w2, NW2t,  128,   0, 128, 128, 128, 3, 0, 0);
  transpose_cvt_kernel<<<(128*128 + 255)/256, 256, 0, stream>>>(emb_in_w,  Eint,  128,   0, 128, 128, 128, 1, 0, 0);
  transpose_cvt_kernel<<<(128*128 + 255)/256, 256, 0, stream>>>(emb_out_w, Eoutt, 128,   0, 128, 128, 128, 1, 0, 0);
  perm_bias_kernel<<<2, 256, 0, stream>>>(edge_b1, b1p, 3);

  // edge counting-sort by row
  hipMemsetAsync(hist, 0, (size_t)N_BLOCKS * 4, stream);
  hist_kernel<<<N_EDGES / 256, 256, 0, stream>>>(edges, hist);
  scan_kernel<<<1, 256, 0, stream>>>(hist, estart, ecur);
  scatter_kernel<<<N_EDGES / 256, 256, 0, stream>>>(edges, edge_attr, ecur, srow, scol, sattr);

  block_start_kernel<<<(N_BLOCKS + 1 + 255) / 256, 256, 0, stream>>>(block_id, bstart);
  pool_kernel<<<N_BLOCKS, 128, 0, stream>>>(H, Z, bstart, Hm, x);

  // h = Hm @ emb_in_w + b
  gemm_kernel<<<N_BLOCKS / 64, 256, 0, stream>>>(Hm, Eint, emb_in_b, h);

  for (int l = 0; l < 3; l++){
    pq_kernel<<<N_BLOCKS / 64, 256, 0, stream>>>(h, W1atp + (size_t)l * 128 * 128,
                                                 W1btp + (size_t)l * 128 * 128,
                                                 b1p + l * 128, Pbf, Qbf, agg, xacc);
    edge_kernel<<<N_EDGES / 64, 256, 0, stream>>>(
        srow, scol, sattr, x, Pbf, Qbf,
        W1ct + (size_t)l * 128 * 32, W2tp + (size_t)l * 128 * 128, CW1tp + (size_t)l * 128 * 128,
        edge_b2 + l * 128, coord_b1 + l * 128, coord_w3 + l * 128,
        xacc, agg);
    x_update_kernel<<<(N_BLOCKS * 3 + 255) / 256, 256, 0, stream>>>(x, xacc, estart);
    node_kernel<<<N_BLOCKS / 64, 256, 0, stream>>>(h, agg, NW1t + (size_t)l * 128 * 256,
                                                   NW2t + (size_t)l * 128 * 128,
                                                   node_b1 + l * 128, node_b2 + l * 128);
  }

  hipMemsetAsync(gsum, 0, (size_t)N_GRAPHS * HS * 4, stream);
  emb_norm_kernel<<<N_BLOCKS / 64, 256, 0, stream>>>(h, Eoutt, emb_out_b, batch_id, brep, gsum);
  norm_graph_kernel<<<N_GRAPHS / 4, 256, 0, stream>>>(gsum, grep);
}

// Round 7
// 611.479 us; speedup vs baseline: 2.0604x; 1.3069x over previous
//
#include <hip/hip_runtime.h>

#define N_ATOMS  80000
#define N_BLOCKS 16000
#define N_EDGES  320000
#define N_GRAPHS 128
#define HS       128

typedef unsigned short ushortT;
typedef __attribute__((ext_vector_type(8))) __bf16 bf16x8;
typedef __attribute__((ext_vector_type(8))) unsigned short ushort8;
typedef __attribute__((ext_vector_type(4))) float f32x4;

__device__ __forceinline__ unsigned short f2bf(float f){
  unsigned int u = __builtin_bit_cast(unsigned int, f);
  u = (u + 0x7FFFu + ((u >> 16) & 1u)) >> 16;
  return (unsigned short)u;
}
// native cvt (RNE on gfx950)
__device__ __forceinline__ ushortT f2bff(float f){
  __bf16 b = (__bf16)f;
  return __builtin_bit_cast(ushortT, b);
}
__device__ __forceinline__ float bf2f(ushortT u){
  unsigned int v = ((unsigned int)u) << 16;
  return __builtin_bit_cast(float, v);
}
__device__ __forceinline__ bf16x8 load8bf(const ushortT* p){
  uint4 u = *reinterpret_cast<const uint4*>(p);
  return __builtin_bit_cast(bf16x8, u);
}
__device__ __forceinline__ bf16x8 load8f_bf(const float* p){
  float4 a = *reinterpret_cast<const float4*>(p);
  float4 b = *reinterpret_cast<const float4*>(p + 4);
  ushort8 u = { f2bff(a.x), f2bff(a.y), f2bff(a.z), f2bff(a.w),
                f2bff(b.x), f2bff(b.y), f2bff(b.z), f2bff(b.w) };
  return __builtin_bit_cast(bf16x8, u);
}
__device__ __forceinline__ float silu(float v){ return v / (1.f + __expf(-v)); }

// pi-permutation: C-fragment register (n,r) of lane-group lg holds natural col
// c = 16n + lg*4 + r; B-fragment position p = ks*32 + lg*8 + j, n = 2ks + (j>>2), r = j&3.
__device__ __forceinline__ int c_of_p(int p){
  int ks = p >> 5, lg = (p >> 3) & 3, j = p & 7;
  return 16 * (ks * 2 + (j >> 2)) + lg * 4 + (j & 3);
}

// ---- weight transpose + bf16 convert
__global__ void transpose_cvt_kernel(const float* __restrict__ src, ushortT* __restrict__ dst,
                                     int srcK, int row_off, int K, int N, int Kpad, int L,
                                     int perm_n, int perm_k){
  int idx = blockIdx.x * 256 + threadIdx.x;
  int tot = L * N * Kpad;
  if (idx >= tot) return;
  int k = idx % Kpad;
  int rem = idx / Kpad;
  int n = rem % N;
  int l = rem / N;
  float v = 0.f;
  if (k < K){
    int kk = perm_k ? c_of_p(k) : k;
    int nn = perm_n ? c_of_p(n) : n;
    v = src[((size_t)l * srcK + row_off + kk) * N + nn];
  }
  dst[idx] = f2bf(v);
}

__global__ void perm_bias_kernel(const float* __restrict__ src, float* __restrict__ dst, int L){
  int i = blockIdx.x * 256 + threadIdx.x;
  if (i >= L * 128) return;
  int l = i >> 7, p = i & 127;
  dst[i] = src[l * 128 + c_of_p(p)];
}

__global__ void block_start_kernel(const int* __restrict__ bid, int* __restrict__ start){
  int b = blockIdx.x * 256 + threadIdx.x;
  if (b > N_BLOCKS) return;
  int lo = 0, hi = N_ATOMS;
  while (lo < hi){ int mid = (lo + hi) >> 1; if (bid[mid] < b) lo = mid + 1; else hi = mid; }
  start[b] = lo;
}

__global__ void hist_kernel(const int* __restrict__ edges, int* __restrict__ hist){
  int e = blockIdx.x * 256 + threadIdx.x;
  if (e < N_EDGES) atomicAdd(&hist[edges[e]], 1);
}

__global__ void scan_kernel(const int* __restrict__ hist, int* __restrict__ estart,
                            int* __restrict__ ecur){
  __shared__ int ps[256];
  int t = threadIdx.x;
  const int chunk = (N_BLOCKS + 255) / 256;
  int lo = t * chunk, hi = lo + chunk;
  if (hi > N_BLOCKS) hi = N_BLOCKS;
  int s = 0;
  for (int i = lo; i < hi; i++) s += hist[i];
  ps[t] = s;
  __syncthreads();
  for (int off = 1; off < 256; off <<= 1){
    int v = (t >= off) ? ps[t - off] : 0;
    __syncthreads();
    ps[t] += v;
    __syncthreads();
  }
  int base = (t == 0) ? 0 : ps[t - 1];
  for (int i = lo; i < hi; i++){ estart[i] = base; ecur[i] = base; base += hist[i]; }
  if (t == 255) estart[N_BLOCKS] = base;
}

// scatter into sorted order; sattr padded: 32 u16/edge = [0, attr0..15, 0 x15]
__global__ void scatter_kernel(const int* __restrict__ edges, const float* __restrict__ attr,
                               int* __restrict__ ecur,
                               int* __restrict__ srow, int* __restrict__ scol,
                               ushortT* __restrict__ sattr){
  int e = blockIdx.x * 256 + threadIdx.x;
  if (e >= N_EDGES) return;
  int r = edges[e], c = edges[N_EDGES + e];
  int p = atomicAdd(&ecur[r], 1);
  srow[p] = r; scol[p] = c;
  ushortT buf[32];
  buf[0] = 0;
#pragma unroll
  for (int k = 0; k < 16; k++) buf[k + 1] = f2bf(attr[(size_t)e * 16 + k]);
#pragma unroll
  for (int k = 17; k < 32; k++) buf[k] = 0;
#pragma unroll
  for (int k = 0; k < 16; k++)
    reinterpret_cast<uint*>(sattr + (size_t)p * 32)[k] = reinterpret_cast<uint*>(buf)[k];
}

__global__ void pool_kernel(const float* __restrict__ H, const float* __restrict__ Z,
                            const int* __restrict__ start,
                            float* __restrict__ Hm, float* __restrict__ x){
  int b = blockIdx.x;
  int t = threadIdx.x;            // 128 threads
  int s = start[b], e = start[b + 1];
  float inv = 1.f / (float)((e - s) > 0 ? (e - s) : 1);
  float sum = 0.f;
  for (int a = s; a < e; a++) sum += H[(size_t)a * HS + t];
  Hm[(size_t)b * HS + t] = sum * inv;
  if (t < 3){
    float sz = 0.f;
    for (int a = s; a < e; a++) sz += Z[a * 3 + t];
    x[b * 3 + t] = sz * inv;
  }
}

// ---- generic MFMA GEMM (used for emb_in only)
__global__ __launch_bounds__(256) void gemm_kernel(
    const float* __restrict__ A,
    const ushortT* __restrict__ Wt, const float* __restrict__ bias,
    float* __restrict__ Cf){
  int t = threadIdx.x; int lane = t & 63; int wv = t >> 6;
  int l15 = lane & 15, lg = lane >> 4;
  int base = blockIdx.x * 64 + wv * 16;
  f32x4 zero = {0.f, 0.f, 0.f, 0.f};
  f32x4 acc[8];
#pragma unroll
  for (int n = 0; n < 8; n++) acc[n] = zero;
  int row = base + l15;
#pragma unroll
  for (int ks = 0; ks < 4; ks++){
    int k0 = ks * 32 + lg * 8;
    bf16x8 af = load8f_bf(A + (size_t)row * HS + k0);
#pragma unroll
    for (int n = 0; n < 8; n++){
      bf16x8 bf = load8bf(Wt + (size_t)(16 * n + l15) * HS + k0);
      acc[n] = __builtin_amdgcn_mfma_f32_16x16x32_bf16(af, bf, acc[n], 0, 0, 0);
    }
  }
#pragma unroll
  for (int n = 0; n < 8; n++){
    int col = 16 * n + l15;
    float bv = bias[col];
#pragma unroll
    for (int r = 0; r < 4; r++){
      int ro = base + lg * 4 + r;
      Cf[(size_t)ro * HS + col] = acc[n][r] + bv;
    }
  }
}

// ---- fused P/Q kernel: P = h@W1a + b1 (pi cols), Q = h@W1b (pi cols), bf16 out.
// Also zeroes this block's 64-row slice of agg and xacc (replaces memsets).
__global__ __launch_bounds__(256) void pq_kernel(
    const float* __restrict__ h,
    const ushortT* __restrict__ Wa, const ushortT* __restrict__ Wb,
    const float* __restrict__ b1p,
    ushortT* __restrict__ Pbf, ushortT* __restrict__ Qbf,
    float* __restrict__ agg, float* __restrict__ xacc){
  int t = threadIdx.x; int lane = t & 63; int wv = t >> 6;
  int l15 = lane & 15, lg = lane >> 4;
  int base = blockIdx.x * 64 + wv * 16;
  int row = base + l15;
  {
    float4 z4 = {0.f, 0.f, 0.f, 0.f};
    float4* aggp = reinterpret_cast<float4*>(agg + (size_t)blockIdx.x * 64 * HS);
#pragma unroll
    for (int i = 0; i < 8; i++) aggp[t + 256 * i] = z4;
    if (t < 192) xacc[blockIdx.x * 192 + t] = 0.f;
  }
  f32x4 zero = {0.f, 0.f, 0.f, 0.f};
  f32x4 accp[8], accq[8];
#pragma unroll
  for (int n = 0; n < 8; n++){ accp[n] = zero; accq[n] = zero; }
#pragma unroll
  for (int ks = 0; ks < 4; ks++){
    int k0 = ks * 32 + lg * 8;
    bf16x8 af = load8f_bf(h + (size_t)row * HS + k0);
#pragma unroll
    for (int n = 0; n < 8; n++){
      accp[n] = __builtin_amdgcn_mfma_f32_16x16x32_bf16(af, load8bf(Wa + (size_t)(16 * n + l15) * HS + k0), accp[n], 0, 0, 0);
      accq[n] = __builtin_amdgcn_mfma_f32_16x16x32_bf16(af, load8bf(Wb + (size_t)(16 * n + l15) * HS + k0), accq[n], 0, 0, 0);
    }
  }
#pragma unroll
  for (int n = 0; n < 8; n++){
    int col = 16 * n + l15;
    float bv = b1p[col];
#pragma unroll
    for (int r = 0; r < 4; r++){
      int ro = base + lg * 4 + r;
      Pbf[(size_t)ro * HS + col] = f2bff(accp[n][r] + bv);
      Qbf[(size_t)ro * HS + col] = f2bff(accq[n][r]);
    }
  }
}

// ---- fused node MLP: h += silu([h|agg]@W1 + b1) @ W2 + b2  (in place, rows wave-exclusive)
__global__ __launch_bounds__(256) void node_kernel(
    float* h, const float* __restrict__ agg,
    const ushortT* __restrict__ W1t, const ushortT* __restrict__ W2t,
    const float* __restrict__ b1, const float* __restrict__ b2){
  __shared__ __align__(16) ushortT t1_s[4][2048];
  int t = threadIdx.x; int lane = t & 63; int wv = t >> 6;
  int l15 = lane & 15, lg = lane >> 4;
  int base = blockIdx.x * 64 + wv * 16;
  int row = base + l15;
  ushortT* T1 = t1_s[wv];
  f32x4 zero = {0.f, 0.f, 0.f, 0.f};
  f32x4 acc[8];
#pragma unroll
  for (int n = 0; n < 8; n++) acc[n] = zero;
#pragma unroll
  for (int ks = 0; ks < 8; ks++){
    int k0 = ks * 32 + lg * 8;
    bf16x8 af = (k0 < 128) ? load8f_bf(h + (size_t)row * HS + k0)
                           : load8f_bf(agg + (size_t)row * HS + (k0 - 128));
#pragma unroll
    for (int n = 0; n < 8; n++){
      acc[n] = __builtin_amdgcn_mfma_f32_16x16x32_bf16(af, load8bf(W1t + (size_t)(16 * n + l15) * 256 + k0), acc[n], 0, 0, 0);
    }
  }
#pragma unroll
  for (int n = 0; n < 8; n++){
    int col = 16 * n + l15;
    float bv = b1[col];
#pragma unroll
    for (int r = 0; r < 4; r++){
      int er = lg * 4 + r;
      T1[(er * 128 + col) ^ ((er & 7) << 3)] = f2bff(silu(acc[n][r] + bv));
    }
  }
#pragma unroll
  for (int n = 0; n < 8; n++) acc[n] = zero;
#pragma unroll
  for (int ks = 0; ks < 4; ks++){
    int k0 = ks * 32 + lg * 8;
    bf16x8 af = load8bf(&T1[(l15 * 128 + k0) ^ ((l15 & 7) << 3)]);
#pragma unroll
    for (int n = 0; n < 8; n++){
      acc[n] = __builtin_amdgcn_mfma_f32_16x16x32_bf16(af, load8bf(W2t + (size_t)(16 * n + l15) * HS + k0), acc[n], 0, 0, 0);
    }
  }
#pragma unroll
  for (int n = 0; n < 8; n++){
    int col = 16 * n + l15;
    float bv = b2[col];
#pragma unroll
    for (int r = 0; r < 4; r++){
      int ro = base + lg * 4 + r;
      h[(size_t)ro * HS + col] += acc[n][r] + bv;
    }
  }
}

// ---- fused emb_out GEMM + block normalize + graph accumulate
__global__ __launch_bounds__(256) void emb_norm_kernel(
    const float* __restrict__ h, const ushortT* __restrict__ Wt,
    const float* __restrict__ bias, const int* __restrict__ batch_id,
    float* __restrict__ brep, float* __restrict__ gsum){
  int t = threadIdx.x; int lane = t & 63; int wv = t >> 6;
  int l15 = lane & 15, lg = lane >> 4;
  int base = blockIdx.x * 64 + wv * 16;
  int row = base + l15;
  f32x4 zero = {0.f, 0.f, 0.f, 0.f};
  f32x4 acc[8];
#pragma unroll
  for (int n = 0; n < 8; n++) acc[n] = zero;
#pragma unroll
  for (int ks = 0; ks < 4; ks++){
    int k0 = ks * 32 + lg * 8;
    bf16x8 af = load8f_bf(h + (size_t)row * HS + k0);
#pragma unroll
    for (int n = 0; n < 8; n++){
      acc[n] = __builtin_amdgcn_mfma_f32_16x16x32_bf16(af, load8bf(Wt + (size_t)(16 * n + l15) * HS + k0), acc[n], 0, 0, 0);
    }
  }
#pragma unroll
  for (int n = 0; n < 8; n++){
    float bv = bias[16 * n + l15];
#pragma unroll
    for (int r = 0; r < 4; r++) acc[n][r] += bv;
  }
  float scl[4];
#pragma unroll
  for (int r = 0; r < 4; r++){
    float ss = 0.f;
#pragma unroll
    for (int n = 0; n < 8; n++) ss += acc[n][r] * acc[n][r];
#pragma unroll
    for (int o = 1; o < 16; o <<= 1) ss += __shfl_xor(ss, o, 64);
    scl[r] = 1.f / fmaxf(sqrtf(ss), 1e-12f);
  }
#pragma unroll
  for (int r = 0; r < 4; r++){
    int ro = base + lg * 4 + r;
    int g = batch_id[ro];
#pragma unroll
    for (int n = 0; n < 8; n++){
      int col = 16 * n + l15;
      float v = acc[n][r] * scl[r];
      brep[(size_t)ro * HS + col] = v;
      atomicAdd(&gsum[g * HS + col], v);
    }
  }
}

// ---- fused edge kernel v6: WG-cooperative channel-split.
// 64 edges/WG. Phase A: each wave builds m1 for its 16 edges -> S1 (pi-order).
// Phase B: each wave computes 2/8 output chan-groups of GEMM2 for ALL 64 edges -> S2.
// Phase C: same split for coord GEMM; xacc flushed as per-wave partials (atomics commute).
// Agg flush per wave over its own 16 edges, reading S2 full-chan via b32 pairs.
__global__ __launch_bounds__(256, 4) void edge_kernel(
    const int* __restrict__ srow, const int* __restrict__ scol,
    const ushortT* __restrict__ sattr,
    const float* __restrict__ x,
    const ushortT* __restrict__ Pbf, const ushortT* __restrict__ Qbf,
    const ushortT* __restrict__ W1ct, const ushortT* __restrict__ W2tp,
    const ushortT* __restrict__ CW1tp,
    const float* __restrict__ b2, const float* __restrict__ cb1,
    const float* __restrict__ cw3,
    float* __restrict__ xacc, float* __restrict__ agg){
  __shared__ float bias_l[3][128];
  __shared__ int   rid_s[64];
  __shared__ float dif_s[64][3];
  __shared__ __align__(16) ushortT S1[64 * 128];   // m1, pi-order, swizzled
  __shared__ __align__(16) ushortT S2[64 * 128];   // m,  pi-order, swizzled

  const int t = threadIdx.x;
  const int lane = t & 63;
  const int wv = t >> 6;
  const int l15 = lane & 15, lg = lane >> 4;
  const f32x4 zero = {0.f, 0.f, 0.f, 0.f};

  if (t < 128){ bias_l[0][t] = b2[t]; bias_l[1][t] = cb1[t]; bias_l[2][t] = cw3[t]; }

  // ---------- phase A: m1 for this wave's 16 edges ----------
  const int erow = wv * 16 + l15;                    // edge index within WG
  const int e = blockIdx.x * 64 + erow;
  const int r = srow[e], c = scol[e];
  const float dx = x[r * 3 + 0] - x[c * 3 + 0];
  const float dy = x[r * 3 + 1] - x[c * 3 + 1];
  const float dz = x[r * 3 + 2] - x[c * 3 + 2];
  const float rad = dx * dx + dy * dy + dz * dz;
  if (lg == 0){
    rid_s[erow] = r;
    dif_s[erow][0] = dx; dif_s[erow][1] = dy; dif_s[erow][2] = dz;
  }
  ushort8 at8 = __builtin_bit_cast(ushort8, load8bf(sattr + (size_t)e * 32 + lg * 8));
  if (lg == 0) at8[0] = f2bff(rad);
  const bf16x8 atb = __builtin_bit_cast(bf16x8, at8);

#pragma unroll
  for (int ks = 0; ks < 4; ks++){
    f32x4 a0 = __builtin_amdgcn_mfma_f32_16x16x32_bf16(
        load8bf(W1ct + (size_t)(16 * (2 * ks)     + l15) * 32 + lg * 8), atb, zero, 0, 0, 0);
    f32x4 a1 = __builtin_amdgcn_mfma_f32_16x16x32_bf16(
        load8bf(W1ct + (size_t)(16 * (2 * ks + 1) + l15) * 32 + lg * 8), atb, zero, 0, 0, 0);
    ushort8 pv = __builtin_bit_cast(ushort8, load8bf(Pbf + (size_t)r * HS + ks * 32 + lg * 8));
    ushort8 qv = __builtin_bit_cast(ushort8, load8bf(Qbf + (size_t)c * HS + ks * 32 + lg * 8));
    ushort8 af;
#pragma unroll
    for (int j = 0; j < 4; j++)
      af[j] = f2bff(silu(a0[j] + bf2f(pv[j]) + bf2f(qv[j])));
#pragma unroll
    for (int j = 4; j < 8; j++)
      af[j] = f2bff(silu(a1[j - 4] + bf2f(pv[j]) + bf2f(qv[j])));
    // write 16B to S1 row=erow, byte col = ks*64 + lg*16, swizzled
    int byte = (erow * 256 + ks * 64 + lg * 16) ^ ((erow & 7) << 4);
    *reinterpret_cast<uint4*>(reinterpret_cast<char*>(S1) + byte) = __builtin_bit_cast(uint4, af);
  }
  __syncthreads();   // bar1: S1 + rid + dif + biases ready

  // ---------- phase B: GEMM2 chan-split (groups 2wv, 2wv+1; all 64 edges) ----------
  f32x4 acc2[4][2];
#pragma unroll
  for (int et = 0; et < 4; et++){ acc2[et][0] = zero; acc2[et][1] = zero; }
#pragma unroll
  for (int ks = 0; ks < 4; ks++){
    bf16x8 wf0 = load8bf(W2tp + (size_t)(16 * (2 * wv)     + l15) * HS + ks * 32 + lg * 8);
    bf16x8 wf1 = load8bf(W2tp + (size_t)(16 * (2 * wv + 1) + l15) * HS + ks * 32 + lg * 8);
#pragma unroll
    for (int et = 0; et < 4; et++){
      int row2 = et * 16 + l15;
      int byte = (row2 * 256 + ks * 64 + lg * 16) ^ ((row2 & 7) << 4);
      bf16x8 mb = __builtin_bit_cast(bf16x8,
          *reinterpret_cast<const uint4*>(reinterpret_cast<const char*>(S1) + byte));
      acc2[et][0] = __builtin_amdgcn_mfma_f32_16x16x32_bf16(wf0, mb, acc2[et][0], 0, 0, 0);
      acc2[et][1] = __builtin_amdgcn_mfma_f32_16x16x32_bf16(wf1, mb, acc2[et][1], 0, 0, 0);
    }
  }
  // m-epilogue: silu + b2 -> S2 (pi positions), b64 writes
#pragma unroll
  for (int g = 0; g < 2; g++){
    int n = 2 * wv + g;
    float4 bv = *reinterpret_cast<const float4*>(&bias_l[0][16 * n + lg * 4]);
    int pbyte = ((n >> 1) * 32 + lg * 8 + (n & 1) * 4) * 2;
#pragma unroll
    for (int et = 0; et < 4; et++){
      ushortT mm[4];
#pragma unroll
      for (int rr = 0; rr < 4; rr++)
        mm[rr] = f2bff(silu(acc2[et][g][rr] + (&bv.x)[rr]));
      int row2 = et * 16 + l15;
      int byte = (row2 * 256 + pbyte) ^ ((row2 & 7) << 4);
      *reinterpret_cast<uint2*>(reinterpret_cast<char*>(S2) + byte) =
          *reinterpret_cast<uint2*>(mm);
    }
  }
  __syncthreads();   // bar2: S2 ready

  // ---------- phase C: coord GEMM chan-split ----------
  f32x4 acc3[4][2];
#pragma unroll
  for (int et = 0; et < 4; et++){ acc3[et][0] = zero; acc3[et][1] = zero; }
#pragma unroll
  for (int ks = 0; ks < 4; ks++){
    bf16x8 wf0 = load8bf(CW1tp + (size_t)(16 * (2 * wv)     + l15) * HS + ks * 32 + lg * 8);
    bf16x8 wf1 = load8bf(CW1tp + (size_t)(16 * (2 * wv + 1) + l15) * HS + ks * 32 + lg * 8);
#pragma unroll
    for (int et = 0; et < 4; et++){
      int row2 = et * 16 + l15;
      int byte = (row2 * 256 + ks * 64 + lg * 16) ^ ((row2 & 7) << 4);
      bf16x8 mb = __builtin_bit_cast(bf16x8,
          *reinterpret_cast<const uint4*>(reinterpret_cast<const char*>(S2) + byte));
      acc3[et][0] = __builtin_amdgcn_mfma_f32_16x16x32_bf16(wf0, mb, acc3[et][0], 0, 0, 0);
      acc3[et][1] = __builtin_amdgcn_mfma_f32_16x16x32_bf16(wf1, mb, acc3[et][1], 0, 0, 0);
    }
  }
  // per-wave partial w (32 chans) for all 64 edges
  float wpart[4];
#pragma unroll
  for (int et = 0; et < 4; et++){
    float ws = 0.f;
#pragma unroll
    for (int g = 0; g < 2; g++){
      int n = 2 * wv + g;
      float4 cbv = *reinterpret_cast<const float4*>(&bias_l[1][16 * n + lg * 4]);
      float4 cwv = *reinterpret_cast<const float4*>(&bias_l[2][16 * n + lg * 4]);
#pragma unroll
      for (int rr = 0; rr < 4; rr++)
        ws += silu(acc3[et][g][rr] + (&cbv.x)[rr]) * (&cwv.x)[rr];
    }
    ws += __shfl_xor(ws, 16, 64);
    ws += __shfl_xor(ws, 32, 64);     // all lanes now hold partial for edge (et,l15)
    wpart[et] = ws;
  }

  // ---------- agg flush: this wave's own 16 edges, full chans from S2 (b32 pairs) ----------
  {
    const int c0 = c_of_p(2 * lane), c1 = c_of_p(2 * lane + 1);
    float run0 = 0.f, run1 = 0.f;
    int prev = __builtin_amdgcn_readfirstlane(__shfl(r, 0, 64));
#pragma unroll
    for (int e2 = 0; e2 < 16; e2++){
      int re = __builtin_amdgcn_readfirstlane(__shfl(r, e2, 64));
      if (re != prev){
        atomicAdd(&agg[(size_t)prev * HS + c0], run0);
        atomicAdd(&agg[(size_t)prev * HS + c1], run1);
        run0 = 0.f; run1 = 0.f; prev = re;
      }
      int row2 = wv * 16 + e2;
      int byte = (row2 * 256 + lane * 4) ^ ((row2 & 7) << 4);
      uint u = *reinterpret_cast<const uint*>(reinterpret_cast<const char*>(S2) + byte);
      run0 += bf2f((ushortT)(u & 0xFFFF));
      run1 += bf2f((ushortT)(u >> 16));
    }
    atomicAdd(&agg[(size_t)prev * HS + c0], run0);
    atomicAdd(&agg[(size_t)prev * HS + c1], run1);
  }

  // ---------- xacc flush: per-wave PARTIAL w over all 64 edges ----------
  {
    float runc = 0.f;
    int prev = rid_s[0];
#pragma unroll 16
    for (int e2 = 0; e2 < 64; e2++){
      int re = rid_s[e2];
      float w = __shfl(wpart[e2 >> 4], e2 & 15, 64);
      if (re != prev){
        if (lane < 3) atomicAdd(&xacc[(size_t)prev * 3 + lane], runc);
        runc = 0.f; prev = re;
      }
      if (lane < 3) runc += dif_s[e2][lane] * w;
    }
    if (lane < 3) atomicAdd(&xacc[(size_t)prev * 3 + lane], runc);
  }
}

__global__ void x_update_kernel(float* __restrict__ x, const float* __restrict__ xacc,
                                const int* __restrict__ estart){
  int i = blockIdx.x * 256 + threadIdx.x;
  if (i < N_BLOCKS * 3){
    int b = i / 3;
    int c = estart[b + 1] - estart[b];
    x[i] += xacc[i] / (float)(c > 0 ? c : 1);
  }
}

__global__ void norm_graph_kernel(const float* __restrict__ gsum, float* __restrict__ grep){
  int wv = threadIdx.x >> 6, lane = threadIdx.x & 63;
  int g = blockIdx.x * 4 + wv;
  if (g >= N_GRAPHS) return;
  float v0 = gsum[g * HS + lane];
  float v1 = gsum[g * HS + 64 + lane];
  float ss = v0 * v0 + v1 * v1;
#pragma unroll
  for (int o = 1; o < 64; o <<= 1) ss += __shfl_xor(ss, o, 64);
  float s = 1.f / fmaxf(sqrtf(ss), 1e-12f);
  grep[(size_t)g * HS + lane] = v0 * s;
  grep[(size_t)g * HS + 64 + lane] = v1 * s;
}

extern "C" void kernel_launch(void* const* d_in, const int* in_sizes, int n_in,
                              void* d_out, int out_size, void* d_ws, size_t ws_size,
                              hipStream_t stream){
  const float* H         = (const float*)d_in[0];
  const float* Z         = (const float*)d_in[1];
  const int*   block_id  = (const int*)d_in[2];
  const int*   batch_id  = (const int*)d_in[3];
  const int*   edges     = (const int*)d_in[4];
  const float* edge_attr = (const float*)d_in[5];
  const float* emb_in_w  = (const float*)d_in[6];
  const float* emb_in_b  = (const float*)d_in[7];
  const float* emb_out_w = (const float*)d_in[8];
  const float* emb_out_b = (const float*)d_in[9];
  const float* edge_w1   = (const float*)d_in[10];
  const float* edge_b1   = (const float*)d_in[11];
  const float* edge_w2   = (const float*)d_in[12];
  const float* edge_b2   = (const float*)d_in[13];
  const float* node_w1   = (const float*)d_in[14];
  const float* node_b1   = (const float*)d_in[15];
  const float* node_w2   = (const float*)d_in[16];
  const float* node_b2   = (const float*)d_in[17];
  const float* coord_w1  = (const float*)d_in[18];
  const float* coord_b1  = (const float*)d_in[19];
  const float* coord_w3  = (const float*)d_in[20];

  float* out  = (float*)d_out;
  float* Hm   = out;                               // [16000 x 128]
  float* brep = out + (size_t)N_BLOCKS * HS;       // [16000 x 128]
  float* grep = out + (size_t)2 * N_BLOCKS * HS;   // [128 x 128]

  char* base = (char*)d_ws;
  size_t off = 0;
  auto take = [&](size_t bytes) -> char* {
    char* p = base + off;
    off += (bytes + 255) & ~(size_t)255;
    return p;
  };
  float*   x     = (float*)  take((size_t)N_BLOCKS * 3 * 4);
  float*   xacc  = (float*)  take((size_t)N_BLOCKS * 3 * 4);
  float*   h     = (float*)  take((size_t)N_BLOCKS * HS * 4);
  float*   agg   = (float*)  take((size_t)N_BLOCKS * HS * 4);
  float*   gsum  = (float*)  take((size_t)N_GRAPHS * HS * 4);
  int*     bstart= (int*)    take((size_t)(N_BLOCKS + 1) * 4);
  int*     hist  = (int*)    take((size_t)N_BLOCKS * 4);
  int*     estart= (int*)    take((size_t)(N_BLOCKS + 1) * 4);
  int*     ecur  = (int*)    take((size_t)N_BLOCKS * 4);
  int*     srow  = (int*)    take((size_t)N_EDGES * 4);
  int*     scol  = (int*)    take((size_t)N_EDGES * 4);
  ushortT* sattr = (ushortT*)take((size_t)N_EDGES * 32 * 2);
  ushortT* Pbf   = (ushortT*)take((size_t)N_BLOCKS * HS * 2);
  ushortT* Qbf   = (ushortT*)take((size_t)N_BLOCKS * HS * 2);
  ushortT* W1atp = (ushortT*)take((size_t)3 * 128 * 128 * 2);
  ushortT* W1btp = (ushortT*)take((size_t)3 * 128 * 128 * 2);
  ushortT* W1ct  = (ushortT*)take((size_t)3 * 128 * 32 * 2);
  ushortT* W2tp  = (ushortT*)take((size_t)3 * 128 * 128 * 2);
  ushortT* CW1tp = (ushortT*)take((size_t)3 * 128 * 128 * 2);
  ushortT* NW1t  = (ushortT*)take((size_t)3 * 128 * 256 * 2);
  ushortT* NW2t  = (ushortT*)take((size_t)3 * 128 * 128 * 2);
  ushortT* Eint  = (ushortT*)take((size_t)128 * 128 * 2);
  ushortT* Eoutt = (ushortT*)take((size_t)128 * 128 * 2);
  float*   b1p   = (float*)  take((size_t)3 * 128 * 4);

  // weight prep
  transpose_cvt_kernel<<<(3*128*128 + 255)/256, 256, 0, stream>>>(edge_w1, W1atp, 273,   0, 128, 128, 128, 3, 1, 0);
  transpose_cvt_kernel<<<(3*128*128 + 255)/256, 256, 0, stream>>>(edge_w1, W1btp, 273, 128, 128, 128, 128, 3, 1, 0);
  transpose_cvt_kernel<<<(3*128*32  + 255)/256, 256, 0, stream>>>(edge_w1, W1ct,  273, 256,  17, 128,  32, 3, 0, 0);
  transpose_cvt_kernel<<<(3*128*128 + 255)/256, 256, 0, stream>>>(edge_w2, W2tp,  128,   0, 128, 128, 128, 3, 0, 1);
  transpose_cvt_kernel<<<(3*128*128 + 255)/256, 256, 0, stream>>>(coord_w1, CW1tp,128,   0, 128, 128, 128, 3, 0, 1);
  transpose_cvt_kernel<<<(3*128*256 + 255)/256, 256, 0, stream>>>(node_w1, NW1t,  256,   0, 256, 128, 256, 3, 0, 0);
  transpose_cvt_kernel<<<(3*128*128 + 255)/256, 256, 0, stream>>>(node_w2, NW2t,  128,   0, 128, 128, 128, 3, 0, 0);
  transpose_cvt_kernel<<<(128*128 + 255)/256, 256, 0, stream>>>(emb_in_w,  Eint,  128,   0, 128, 128, 128, 1, 0, 0);
  transpose_cvt_kernel<<<(128*128 + 255)/256, 256, 0, stream>>>(emb_out_w, Eoutt, 128,   0, 128, 128, 128, 1, 0, 0);
  perm_bias_kernel<<<2, 256, 0, stream>>>(edge_b1, b1p, 3);

  // edge counting-sort by row
  hipMemsetAsync(hist, 0, (size_t)N_BLOCKS * 4, stream);
  hist_kernel<<<N_EDGES / 256, 256, 0, stream>>>(edges, hist);
  scan_kernel<<<1, 256, 0, stream>>>(hist, estart, ecur);
  scatter_kernel<<<N_EDGES / 256, 256, 0, stream>>>(edges, edge_attr, ecur, srow, scol, sattr);

  block_start_kernel<<<(N_BLOCKS + 1 + 255) / 256, 256, 0, stream>>>(block_id, bstart);
  pool_kernel<<<N_BLOCKS, 128, 0, stream>>>(H, Z, bstart, Hm, x);

  // h = Hm @ emb_in_w + b
  gemm_kernel<<<N_BLOCKS / 64, 256, 0, stream>>>(Hm, Eint, emb_in_b, h);

  for (int l = 0; l < 3; l++){
    pq_kernel<<<N_BLOCKS / 64, 256, 0, stream>>>(h, W1atp + (size_t)l * 128 * 128,
                                                 W1btp + (size_t)l * 128 * 128,
                                                 b1p + l * 128, Pbf, Qbf, agg, xacc);
    edge_kernel<<<N_EDGES / 64, 256, 0, stream>>>(
        srow, scol, sattr, x, Pbf, Qbf,
        W1ct + (size_t)l * 128 * 32, W2tp + (size_t)l * 128 * 128, CW1tp + (size_t)l * 128 * 128,
        edge_b2 + l * 128, coord_b1 + l * 128, coord_w3 + l * 128,
        xacc, agg);
    x_update_kernel<<<(N_BLOCKS * 3 + 255) / 256, 256, 0, stream>>>(x, xacc, estart);
    node_kernel<<<N_BLOCKS / 64, 256, 0, stream>>>(h, agg, NW1t + (size_t)l * 128 * 256,
                                                   NW2t + (size_t)l * 128 * 128,
                                                   node_b1 + l * 128, node_b2 + l * 128);
  }

  hipMemsetAsync(gsum, 0, (size_t)N_GRAPHS * HS * 4, stream);
  emb_norm_kernel<<<N_BLOCKS / 64, 256, 0, stream>>>(h, Eoutt, emb_out_b, batch_id, brep, gsum);
  norm_graph_kernel<<<N_GRAPHS / 4, 256, 0, stream>>>(gsum, grep);
}

// Round 8
// 558.423 us; speedup vs baseline: 2.2562x; 1.0950x over previous
//
#include <hip/hip_runtime.h>

#define N_ATOMS  80000
#define N_BLOCKS 16000
#define N_EDGES  320000
#define N_GRAPHS 128
#define HS       128

typedef unsigned short ushortT;
typedef __attribute__((ext_vector_type(8))) __bf16 bf16x8;
typedef __attribute__((ext_vector_type(8))) unsigned short ushort8;
typedef __attribute__((ext_vector_type(4))) float f32x4;

__device__ __forceinline__ unsigned short f2bf(float f){
  unsigned int u = __builtin_bit_cast(unsigned int, f);
  u = (u + 0x7FFFu + ((u >> 16) & 1u)) >> 16;
  return (unsigned short)u;
}
// native cvt (RNE on gfx950)
__device__ __forceinline__ ushortT f2bff(float f){
  __bf16 b = (__bf16)f;
  return __builtin_bit_cast(ushortT, b);
}
__device__ __forceinline__ float bf2f(ushortT u){
  unsigned int v = ((unsigned int)u) << 16;
  return __builtin_bit_cast(float, v);
}
__device__ __forceinline__ bf16x8 load8bf(const ushortT* p){
  uint4 u = *reinterpret_cast<const uint4*>(p);
  return __builtin_bit_cast(bf16x8, u);
}
__device__ __forceinline__ bf16x8 load8f_bf(const float* p){
  float4 a = *reinterpret_cast<const float4*>(p);
  float4 b = *reinterpret_cast<const float4*>(p + 4);
  ushort8 u = { f2bff(a.x), f2bff(a.y), f2bff(a.z), f2bff(a.w),
                f2bff(b.x), f2bff(b.y), f2bff(b.z), f2bff(b.w) };
  return __builtin_bit_cast(bf16x8, u);
}
// fast silu: v * rcp(1+exp(-v)); rcp approx ~1ulp, fine for bf16 downstream.
// exp overflow: v<-88 -> exp=inf -> rcp=0 -> result 0 (correct).
__device__ __forceinline__ float silu(float v){
  return v * __builtin_amdgcn_rcpf(1.f + __expf(-v));
}

// pi-permutation: C-fragment register (n,r) of lane-group lg holds natural col
// c = 16n + lg*4 + r; B-fragment position p = ks*32 + lg*8 + j, n = 2ks + (j>>2), r = j&3.
__device__ __forceinline__ int c_of_p(int p){
  int ks = p >> 5, lg = (p >> 3) & 3, j = p & 7;
  return 16 * (ks * 2 + (j >> 2)) + lg * 4 + (j & 3);
}

// ---- weight transpose + bf16 convert
__global__ void transpose_cvt_kernel(const float* __restrict__ src, ushortT* __restrict__ dst,
                                     int srcK, int row_off, int K, int N, int Kpad, int L,
                                     int perm_n, int perm_k){
  int idx = blockIdx.x * 256 + threadIdx.x;
  int tot = L * N * Kpad;
  if (idx >= tot) return;
  int k = idx % Kpad;
  int rem = idx / Kpad;
  int n = rem % N;
  int l = rem / N;
  float v = 0.f;
  if (k < K){
    int kk = perm_k ? c_of_p(k) : k;
    int nn = perm_n ? c_of_p(n) : n;
    v = src[((size_t)l * srcK + row_off + kk) * N + nn];
  }
  dst[idx] = f2bf(v);
}

__global__ void perm_bias_kernel(const float* __restrict__ src, float* __restrict__ dst, int L){
  int i = blockIdx.x * 256 + threadIdx.x;
  if (i >= L * 128) return;
  int l = i >> 7, p = i & 127;
  dst[i] = src[l * 128 + c_of_p(p)];
}

__global__ void block_start_kernel(const int* __restrict__ bid, int* __restrict__ start){
  int b = blockIdx.x * 256 + threadIdx.x;
  if (b > N_BLOCKS) return;
  int lo = 0, hi = N_ATOMS;
  while (lo < hi){ int mid = (lo + hi) >> 1; if (bid[mid] < b) lo = mid + 1; else hi = mid; }
  start[b] = lo;
}

__global__ void hist_kernel(const int* __restrict__ edges, int* __restrict__ hist){
  int e = blockIdx.x * 256 + threadIdx.x;
  if (e < N_EDGES) atomicAdd(&hist[edges[e]], 1);
}

__global__ void scan_kernel(const int* __restrict__ hist, int* __restrict__ estart,
                            int* __restrict__ ecur){
  __shared__ int ps[256];
  int t = threadIdx.x;
  const int chunk = (N_BLOCKS + 255) / 256;
  int lo = t * chunk, hi = lo + chunk;
  if (hi > N_BLOCKS) hi = N_BLOCKS;
  int s = 0;
  for (int i = lo; i < hi; i++) s += hist[i];
  ps[t] = s;
  __syncthreads();
  for (int off = 1; off < 256; off <<= 1){
    int v = (t >= off) ? ps[t - off] : 0;
    __syncthreads();
    ps[t] += v;
    __syncthreads();
  }
  int base = (t == 0) ? 0 : ps[t - 1];
  for (int i = lo; i < hi; i++){ estart[i] = base; ecur[i] = base; base += hist[i]; }
  if (t == 255) estart[N_BLOCKS] = base;
}

// scatter into sorted order; sattr padded: 32 u16/edge = [0, attr0..15, 0 x15]
__global__ void scatter_kernel(const int* __restrict__ edges, const float* __restrict__ attr,
                               int* __restrict__ ecur,
                               int* __restrict__ srow, int* __restrict__ scol,
                               ushortT* __restrict__ sattr){
  int e = blockIdx.x * 256 + threadIdx.x;
  if (e >= N_EDGES) return;
  int r = edges[e], c = edges[N_EDGES + e];
  int p = atomicAdd(&ecur[r], 1);
  srow[p] = r; scol[p] = c;
  ushortT buf[32];
  buf[0] = 0;
#pragma unroll
  for (int k = 0; k < 16; k++) buf[k + 1] = f2bf(attr[(size_t)e * 16 + k]);
#pragma unroll
  for (int k = 17; k < 32; k++) buf[k] = 0;
#pragma unroll
  for (int k = 0; k < 16; k++)
    reinterpret_cast<uint*>(sattr + (size_t)p * 32)[k] = reinterpret_cast<uint*>(buf)[k];
}

__global__ void pool_kernel(const float* __restrict__ H, const float* __restrict__ Z,
                            const int* __restrict__ start,
                            float* __restrict__ Hm, float* __restrict__ x){
  int b = blockIdx.x;
  int t = threadIdx.x;            // 128 threads
  int s = start[b], e = start[b + 1];
  float inv = 1.f / (float)((e - s) > 0 ? (e - s) : 1);
  float sum = 0.f;
  for (int a = s; a < e; a++) sum += H[(size_t)a * HS + t];
  Hm[(size_t)b * HS + t] = sum * inv;
  if (t < 3){
    float sz = 0.f;
    for (int a = s; a < e; a++) sz += Z[a * 3 + t];
    x[b * 3 + t] = sz * inv;
  }
}

// ---- fused emb_in GEMM + layer-0 P/Q + zero agg/xacc slices
__global__ __launch_bounds__(256) void gemm_pq_kernel(
    const float* __restrict__ A,
    const ushortT* __restrict__ Wt, const float* __restrict__ bias,
    float* __restrict__ Cf,
    const ushortT* __restrict__ Wa, const ushortT* __restrict__ Wb,
    const float* __restrict__ b1p,
    ushortT* __restrict__ Pbf, ushortT* __restrict__ Qbf,
    float* __restrict__ agg, float* __restrict__ xacc){
  __shared__ __align__(16) ushortT t1_s[4][2048];
  int t = threadIdx.x; int lane = t & 63; int wv = t >> 6;
  int l15 = lane & 15, lg = lane >> 4;
  int base = blockIdx.x * 64 + wv * 16;
  int row = base + l15;
  // zero agg/xacc slices for layer 0
  {
    float4 z4 = {0.f, 0.f, 0.f, 0.f};
    float4* aggp = reinterpret_cast<float4*>(agg + (size_t)blockIdx.x * 64 * HS);
#pragma unroll
    for (int i = 0; i < 8; i++) aggp[t + 256 * i] = z4;
    if (t < 192) xacc[blockIdx.x * 192 + t] = 0.f;
  }
  ushortT* T1 = t1_s[wv];
  f32x4 zero = {0.f, 0.f, 0.f, 0.f};
  f32x4 acc[8];
#pragma unroll
  for (int n = 0; n < 8; n++) acc[n] = zero;
#pragma unroll
  for (int ks = 0; ks < 4; ks++){
    int k0 = ks * 32 + lg * 8;
    bf16x8 af = load8f_bf(A + (size_t)row * HS + k0);
#pragma unroll
    for (int n = 0; n < 8; n++){
      bf16x8 bf = load8bf(Wt + (size_t)(16 * n + l15) * HS + k0);
      acc[n] = __builtin_amdgcn_mfma_f32_16x16x32_bf16(af, bf, acc[n], 0, 0, 0);
    }
  }
#pragma unroll
  for (int n = 0; n < 8; n++){
    int col = 16 * n + l15;
    float bv = bias[col];
#pragma unroll
    for (int r = 0; r < 4; r++){
      int ro = base + lg * 4 + r;
      int er = lg * 4 + r;
      float hv = acc[n][r] + bv;
      Cf[(size_t)ro * HS + col] = hv;
      T1[(er * 128 + col) ^ ((er & 7) << 3)] = f2bff(hv);
    }
  }
  // P/Q from T1 (wave-private, no barrier)
  f32x4 accp[8], accq[8];
#pragma unroll
  for (int n = 0; n < 8; n++){ accp[n] = zero; accq[n] = zero; }
#pragma unroll
  for (int ks = 0; ks < 4; ks++){
    int k0 = ks * 32 + lg * 8;
    bf16x8 af = load8bf(&T1[(l15 * 128 + k0) ^ ((l15 & 7) << 3)]);
#pragma unroll
    for (int n = 0; n < 8; n++){
      accp[n] = __builtin_amdgcn_mfma_f32_16x16x32_bf16(af, load8bf(Wa + (size_t)(16 * n + l15) * HS + k0), accp[n], 0, 0, 0);
      accq[n] = __builtin_amdgcn_mfma_f32_16x16x32_bf16(af, load8bf(Wb + (size_t)(16 * n + l15) * HS + k0), accq[n], 0, 0, 0);
    }
  }
#pragma unroll
  for (int n = 0; n < 8; n++){
    int col = 16 * n + l15;
    float bv = b1p[col];
#pragma unroll
    for (int r = 0; r < 4; r++){
      int ro = base + lg * 4 + r;
      Pbf[(size_t)ro * HS + col] = f2bff(accp[n][r] + bv);
      Qbf[(size_t)ro * HS + col] = f2bff(accq[n][r]);
    }
  }
}

// ---- fused node MLP (+ optional x_update + zero-next + next-layer P/Q)
template<bool PQ>
__global__ __launch_bounds__(256) void node_kernel(
    float* __restrict__ h, float* __restrict__ agg,
    const ushortT* __restrict__ W1t, const ushortT* __restrict__ W2t,
    const float* __restrict__ b1, const float* __restrict__ b2,
    const ushortT* __restrict__ Wa, const ushortT* __restrict__ Wb,
    const float* __restrict__ b1p,
    ushortT* __restrict__ Pbf, ushortT* __restrict__ Qbf,
    float* __restrict__ x, float* __restrict__ xacc, const int* __restrict__ estart){
  __shared__ __align__(16) ushortT t1_s[4][2048];
  int t = threadIdx.x; int lane = t & 63; int wv = t >> 6;
  int l15 = lane & 15, lg = lane >> 4;
  int base = blockIdx.x * 64 + wv * 16;
  int row = base + l15;
  ushortT* T1 = t1_s[wv];
  f32x4 zero = {0.f, 0.f, 0.f, 0.f};

  if (PQ){
    // x update (reads xacc) then zero xacc — same thread, same element
    if (t < 192){
      int i = blockIdx.x * 192 + t;
      int b = i / 3;
      int cnt = estart[b + 1] - estart[b];
      x[i] += xacc[i] / (float)(cnt > 0 ? cnt : 1);
      xacc[i] = 0.f;
    }
  }

  // node phase 1: silu([h|agg] @ W1 + b1) -> T1
  f32x4 acc[8];
#pragma unroll
  for (int n = 0; n < 8; n++) acc[n] = zero;
#pragma unroll
  for (int ks = 0; ks < 8; ks++){
    int k0 = ks * 32 + lg * 8;
    bf16x8 af = (k0 < 128) ? load8f_bf(h + (size_t)row * HS + k0)
                           : load8f_bf(agg + (size_t)row * HS + (k0 - 128));
#pragma unroll
    for (int n = 0; n < 8; n++){
      acc[n] = __builtin_amdgcn_mfma_f32_16x16x32_bf16(af, load8bf(W1t + (size_t)(16 * n + l15) * 256 + k0), acc[n], 0, 0, 0);
    }
  }
  if (PQ){
    // all agg reads of this block drained (syncthreads waits vmem); zero agg for next layer
    __syncthreads();
    float4 z4 = {0.f, 0.f, 0.f, 0.f};
    float4* aggp = reinterpret_cast<float4*>(agg + (size_t)blockIdx.x * 64 * HS);
#pragma unroll
    for (int i = 0; i < 8; i++) aggp[t + 256 * i] = z4;
  }
#pragma unroll
  for (int n = 0; n < 8; n++){
    int col = 16 * n + l15;
    float bv = b1[col];
#pragma unroll
    for (int r = 0; r < 4; r++){
      int er = lg * 4 + r;
      T1[(er * 128 + col) ^ ((er & 7) << 3)] = f2bff(silu(acc[n][r] + bv));
    }
  }
  // phase 2: h += T1 @ W2 + b2
#pragma unroll
  for (int n = 0; n < 8; n++) acc[n] = zero;
#pragma unroll
  for (int ks = 0; ks < 4; ks++){
    int k0 = ks * 32 + lg * 8;
    bf16x8 af = load8bf(&T1[(l15 * 128 + k0) ^ ((l15 & 7) << 3)]);
#pragma unroll
    for (int n = 0; n < 8; n++){
      acc[n] = __builtin_amdgcn_mfma_f32_16x16x32_bf16(af, load8bf(W2t + (size_t)(16 * n + l15) * HS + k0), acc[n], 0, 0, 0);
    }
  }
#pragma unroll
  for (int n = 0; n < 8; n++){
    int col = 16 * n + l15;
    float bv = b2[col];
#pragma unroll
    for (int r = 0; r < 4; r++){
      int ro = base + lg * 4 + r;
      int er = lg * 4 + r;
      float hv = h[(size_t)ro * HS + col] + acc[n][r] + bv;
      h[(size_t)ro * HS + col] = hv;
      if (PQ) T1[(er * 128 + col) ^ ((er & 7) << 3)] = f2bff(hv);
    }
  }
  if (PQ){
    // next-layer P/Q from T1 (wave-private; wave-order LDS ensures reads-before-writes done)
    f32x4 accp[8], accq[8];
#pragma unroll
    for (int n = 0; n < 8; n++){ accp[n] = zero; accq[n] = zero; }
#pragma unroll
    for (int ks = 0; ks < 4; ks++){
      int k0 = ks * 32 + lg * 8;
      bf16x8 af = load8bf(&T1[(l15 * 128 + k0) ^ ((l15 & 7) << 3)]);
#pragma unroll
      for (int n = 0; n < 8; n++){
        accp[n] = __builtin_amdgcn_mfma_f32_16x16x32_bf16(af, load8bf(Wa + (size_t)(16 * n + l15) * HS + k0), accp[n], 0, 0, 0);
        accq[n] = __builtin_amdgcn_mfma_f32_16x16x32_bf16(af, load8bf(Wb + (size_t)(16 * n + l15) * HS + k0), accq[n], 0, 0, 0);
      }
    }
#pragma unroll
    for (int n = 0; n < 8; n++){
      int col = 16 * n + l15;
      float bv = b1p[col];
#pragma unroll
      for (int r = 0; r < 4; r++){
        int ro = base + lg * 4 + r;
        Pbf[(size_t)ro * HS + col] = f2bff(accp[n][r] + bv);
        Qbf[(size_t)ro * HS + col] = f2bff(accq[n][r]);
      }
    }
  }
}

// ---- fused emb_out GEMM + block normalize + graph accumulate
__global__ __launch_bounds__(256) void emb_norm_kernel(
    const float* __restrict__ h, const ushortT* __restrict__ Wt,
    const float* __restrict__ bias, const int* __restrict__ batch_id,
    float* __restrict__ brep, float* __restrict__ gsum){
  int t = threadIdx.x; int lane = t & 63; int wv = t >> 6;
  int l15 = lane & 15, lg = lane >> 4;
  int base = blockIdx.x * 64 + wv * 16;
  int row = base + l15;
  f32x4 zero = {0.f, 0.f, 0.f, 0.f};
  f32x4 acc[8];
#pragma unroll
  for (int n = 0; n < 8; n++) acc[n] = zero;
#pragma unroll
  for (int ks = 0; ks < 4; ks++){
    int k0 = ks * 32 + lg * 8;
    bf16x8 af = load8f_bf(h + (size_t)row * HS + k0);
#pragma unroll
    for (int n = 0; n < 8; n++){
      acc[n] = __builtin_amdgcn_mfma_f32_16x16x32_bf16(af, load8bf(Wt + (size_t)(16 * n + l15) * HS + k0), acc[n], 0, 0, 0);
    }
  }
#pragma unroll
  for (int n = 0; n < 8; n++){
    float bv = bias[16 * n + l15];
#pragma unroll
    for (int r = 0; r < 4; r++) acc[n][r] += bv;
  }
  float scl[4];
#pragma unroll
  for (int r = 0; r < 4; r++){
    float ss = 0.f;
#pragma unroll
    for (int n = 0; n < 8; n++) ss += acc[n][r] * acc[n][r];
#pragma unroll
    for (int o = 1; o < 16; o <<= 1) ss += __shfl_xor(ss, o, 64);
    scl[r] = 1.f / fmaxf(sqrtf(ss), 1e-12f);
  }
#pragma unroll
  for (int r = 0; r < 4; r++){
    int ro = base + lg * 4 + r;
    int g = batch_id[ro];
#pragma unroll
    for (int n = 0; n < 8; n++){
      int col = 16 * n + l15;
      float v = acc[n][r] * scl[r];
      brep[(size_t)ro * HS + col] = v;
      atomicAdd(&gsum[g * HS + col], v);
    }
  }
}

// ---- fused edge kernel v7: WG-cooperative channel-split, COORD templated.
template<int COORD>
__global__ __launch_bounds__(256, 4) void edge_kernel(
    const int* __restrict__ srow, const int* __restrict__ scol,
    const ushortT* __restrict__ sattr,
    const float* __restrict__ x,
    const ushortT* __restrict__ Pbf, const ushortT* __restrict__ Qbf,
    const ushortT* __restrict__ W1ct, const ushortT* __restrict__ W2tp,
    const ushortT* __restrict__ CW1tp,
    const float* __restrict__ b2, const float* __restrict__ cb1,
    const float* __restrict__ cw3,
    float* __restrict__ xacc, float* __restrict__ agg){
  __shared__ float bias_l[3][128];
  __shared__ int   rid_s[64];
  __shared__ float dif_s[COORD ? 64 : 1][3];
  __shared__ float wall[COORD ? 4 : 1][COORD ? 64 : 1];
  __shared__ __align__(16) ushortT S1[64 * 128];   // m1, pi-order, swizzled
  __shared__ __align__(16) ushortT S2[64 * 128];   // m,  pi-order, swizzled

  const int t = threadIdx.x;
  const int lane = t & 63;
  const int wv = t >> 6;
  const int l15 = lane & 15, lg = lane >> 4;
  const f32x4 zero = {0.f, 0.f, 0.f, 0.f};

  if (t < 128){
    bias_l[0][t] = b2[t];
    if (COORD){ bias_l[1][t] = cb1[t]; bias_l[2][t] = cw3[t]; }
  }

  // ---------- phase A: m1 for this wave's 16 edges ----------
  const int erow = wv * 16 + l15;
  const int e = blockIdx.x * 64 + erow;
  const int r = srow[e], c = scol[e];
  const float dx = x[r * 3 + 0] - x[c * 3 + 0];
  const float dy = x[r * 3 + 1] - x[c * 3 + 1];
  const float dz = x[r * 3 + 2] - x[c * 3 + 2];
  const float rad = dx * dx + dy * dy + dz * dz;
  if (lg == 0){
    rid_s[erow] = r;
    if (COORD){ dif_s[erow][0] = dx; dif_s[erow][1] = dy; dif_s[erow][2] = dz; }
  }
  ushort8 at8 = __builtin_bit_cast(ushort8, load8bf(sattr + (size_t)e * 32 + lg * 8));
  if (lg == 0) at8[0] = f2bff(rad);
  const bf16x8 atb = __builtin_bit_cast(bf16x8, at8);

#pragma unroll
  for (int ks = 0; ks < 4; ks++){
    f32x4 a0 = __builtin_amdgcn_mfma_f32_16x16x32_bf16(
        load8bf(W1ct + (size_t)(16 * (2 * ks)     + l15) * 32 + lg * 8), atb, zero, 0, 0, 0);
    f32x4 a1 = __builtin_amdgcn_mfma_f32_16x16x32_bf16(
        load8bf(W1ct + (size_t)(16 * (2 * ks + 1) + l15) * 32 + lg * 8), atb, zero, 0, 0, 0);
    ushort8 pv = __builtin_bit_cast(ushort8, load8bf(Pbf + (size_t)r * HS + ks * 32 + lg * 8));
    ushort8 qv = __builtin_bit_cast(ushort8, load8bf(Qbf + (size_t)c * HS + ks * 32 + lg * 8));
    ushort8 af;
#pragma unroll
    for (int j = 0; j < 4; j++)
      af[j] = f2bff(silu(a0[j] + bf2f(pv[j]) + bf2f(qv[j])));
#pragma unroll
    for (int j = 4; j < 8; j++)
      af[j] = f2bff(silu(a1[j - 4] + bf2f(pv[j]) + bf2f(qv[j])));
    int byte = (erow * 256 + ks * 64 + lg * 16) ^ ((erow & 7) << 4);
    *reinterpret_cast<uint4*>(reinterpret_cast<char*>(S1) + byte) = __builtin_bit_cast(uint4, af);
  }
  __syncthreads();   // bar1: S1 + rid + dif + biases ready

  // ---------- phase B: GEMM2 chan-split (groups 2wv, 2wv+1; all 64 edges) ----------
  f32x4 acc2[4][2];
#pragma unroll
  for (int et = 0; et < 4; et++){ acc2[et][0] = zero; acc2[et][1] = zero; }
#pragma unroll
  for (int ks = 0; ks < 4; ks++){
    bf16x8 wf0 = load8bf(W2tp + (size_t)(16 * (2 * wv)     + l15) * HS + ks * 32 + lg * 8);
    bf16x8 wf1 = load8bf(W2tp + (size_t)(16 * (2 * wv + 1) + l15) * HS + ks * 32 + lg * 8);
#pragma unroll
    for (int et = 0; et < 4; et++){
      int row2 = et * 16 + l15;
      int byte = (row2 * 256 + ks * 64 + lg * 16) ^ ((row2 & 7) << 4);
      bf16x8 mb = __builtin_bit_cast(bf16x8,
          *reinterpret_cast<const uint4*>(reinterpret_cast<const char*>(S1) + byte));
      acc2[et][0] = __builtin_amdgcn_mfma_f32_16x16x32_bf16(wf0, mb, acc2[et][0], 0, 0, 0);
      acc2[et][1] = __builtin_amdgcn_mfma_f32_16x16x32_bf16(wf1, mb, acc2[et][1], 0, 0, 0);
    }
  }
  // m-epilogue: silu + b2 -> S2 (pi positions), b64 writes
#pragma unroll
  for (int g = 0; g < 2; g++){
    int n = 2 * wv + g;
    float4 bv = *reinterpret_cast<const float4*>(&bias_l[0][16 * n + lg * 4]);
    int pbyte = ((n >> 1) * 32 + lg * 8 + (n & 1) * 4) * 2;
#pragma unroll
    for (int et = 0; et < 4; et++){
      ushortT mm[4];
#pragma unroll
      for (int rr = 0; rr < 4; rr++)
        mm[rr] = f2bff(silu(acc2[et][g][rr] + (&bv.x)[rr]));
      int row2 = et * 16 + l15;
      int byte = (row2 * 256 + pbyte) ^ ((row2 & 7) << 4);
      *reinterpret_cast<uint2*>(reinterpret_cast<char*>(S2) + byte) =
          *reinterpret_cast<uint2*>(mm);
    }
  }
  __syncthreads();   // bar2: S2 ready

  if (COORD){
    // ---------- phase C: coord GEMM chan-split ----------
    f32x4 acc3[4][2];
#pragma unroll
    for (int et = 0; et < 4; et++){ acc3[et][0] = zero; acc3[et][1] = zero; }
#pragma unroll
    for (int ks = 0; ks < 4; ks++){
      bf16x8 wf0 = load8bf(CW1tp + (size_t)(16 * (2 * wv)     + l15) * HS + ks * 32 + lg * 8);
      bf16x8 wf1 = load8bf(CW1tp + (size_t)(16 * (2 * wv + 1) + l15) * HS + ks * 32 + lg * 8);
#pragma unroll
      for (int et = 0; et < 4; et++){
        int row2 = et * 16 + l15;
        int byte = (row2 * 256 + ks * 64 + lg * 16) ^ ((row2 & 7) << 4);
        bf16x8 mb = __builtin_bit_cast(bf16x8,
            *reinterpret_cast<const uint4*>(reinterpret_cast<const char*>(S2) + byte));
        acc3[et][0] = __builtin_amdgcn_mfma_f32_16x16x32_bf16(wf0, mb, acc3[et][0], 0, 0, 0);
        acc3[et][1] = __builtin_amdgcn_mfma_f32_16x16x32_bf16(wf1, mb, acc3[et][1], 0, 0, 0);
      }
    }
    // per-wave partial w -> wall
#pragma unroll
    for (int et = 0; et < 4; et++){
      float ws = 0.f;
#pragma unroll
      for (int g = 0; g < 2; g++){
        int n = 2 * wv + g;
        float4 cbv = *reinterpret_cast<const float4*>(&bias_l[1][16 * n + lg * 4]);
        float4 cwv = *reinterpret_cast<const float4*>(&bias_l[2][16 * n + lg * 4]);
#pragma unroll
        for (int rr = 0; rr < 4; rr++)
          ws += silu(acc3[et][g][rr] + (&cbv.x)[rr]) * (&cwv.x)[rr];
      }
      ws += __shfl_xor(ws, 16, 64);
      ws += __shfl_xor(ws, 32, 64);
      if (lg == 0) wall[wv][et * 16 + l15] = ws;
    }
  }

  // ---------- agg flush: this wave's own 16 edges, full chans from S2 (b32 pairs) ----------
  {
    const int c0 = c_of_p(2 * lane), c1 = c_of_p(2 * lane + 1);
    float run0 = 0.f, run1 = 0.f;
    int prev = __builtin_amdgcn_readfirstlane(rid_s[wv * 16]);
#pragma unroll
    for (int e2 = 0; e2 < 16; e2++){
      int re = __builtin_amdgcn_readfirstlane(rid_s[wv * 16 + e2]);
      if (re != prev){
        atomicAdd(&agg[(size_t)prev * HS + c0], run0);
        atomicAdd(&agg[(size_t)prev * HS + c1], run1);
        run0 = 0.f; run1 = 0.f; prev = re;
      }
      int row2 = wv * 16 + e2;
      int byte = (row2 * 256 + lane * 4) ^ ((row2 & 7) << 4);
      uint u = *reinterpret_cast<const uint*>(reinterpret_cast<const char*>(S2) + byte);
      run0 += bf2f((ushortT)(u & 0xFFFF));
      run1 += bf2f((ushortT)(u >> 16));
    }
    atomicAdd(&agg[(size_t)prev * HS + c0], run0);
    atomicAdd(&agg[(size_t)prev * HS + c1], run1);
  }

  if (COORD){
    __syncthreads();   // bar3: wall complete
    // ---------- xacc: parallel scatter, per-WG summed w, one atomic per (edge,coord) ----------
    if (t < 192){
      int e2 = t / 3, cd = t % 3;
      float w = wall[0][e2] + wall[1][e2] + wall[2][e2] + wall[3][e2];
      atomicAdd(&xacc[(size_t)rid_s[e2] * 3 + cd], dif_s[e2][cd] * w);
    }
  }
}

__global__ void norm_graph_kernel(const float* __restrict__ gsum, float* __restrict__ grep){
  int wv = threadIdx.x >> 6, lane = threadIdx.x & 63;
  int g = blockIdx.x * 4 + wv;
  if (g >= N_GRAPHS) return;
  float v0 = gsum[g * HS + lane];
  float v1 = gsum[g * HS + 64 + lane];
  float ss = v0 * v0 + v1 * v1;
#pragma unroll
  for (int o = 1; o < 64; o <<= 1) ss += __shfl_xor(ss, o, 64);
  float s = 1.f / fmaxf(sqrtf(ss), 1e-12f);
  grep[(size_t)g * HS + lane] = v0 * s;
  grep[(size_t)g * HS + 64 + lane] = v1 * s;
}

extern "C" void kernel_launch(void* const* d_in, const int* in_sizes, int n_in,
                              void* d_out, int out_size, void* d_ws, size_t ws_size,
                              hipStream_t stream){
  const float* H         = (const float*)d_in[0];
  const float* Z         = (const float*)d_in[1];
  const int*   block_id  = (const int*)d_in[2];
  const int*   batch_id  = (const int*)d_in[3];
  const int*   edges     = (const int*)d_in[4];
  const float* edge_attr = (const float*)d_in[5];
  const float* emb_in_w  = (const float*)d_in[6];
  const float* emb_in_b  = (const float*)d_in[7];
  const float* emb_out_w = (const float*)d_in[8];
  const float* emb_out_b = (const float*)d_in[9];
  const float* edge_w1   = (const float*)d_in[10];
  const float* edge_b1   = (const float*)d_in[11];
  const float* edge_w2   = (const float*)d_in[12];
  const float* edge_b2   = (const float*)d_in[13];
  const float* node_w1   = (const float*)d_in[14];
  const float* node_b1   = (const float*)d_in[15];
  const float* node_w2   = (const float*)d_in[16];
  const float* node_b2   = (const float*)d_in[17];
  const float* coord_w1  = (const float*)d_in[18];
  const float* coord_b1  = (const float*)d_in[19];
  const float* coord_w3  = (const float*)d_in[20];

  float* out  = (float*)d_out;
  float* Hm   = out;                               // [16000 x 128]
  float* brep = out + (size_t)N_BLOCKS * HS;       // [16000 x 128]
  float* grep = out + (size_t)2 * N_BLOCKS * HS;   // [128 x 128]

  char* base = (char*)d_ws;
  size_t off = 0;
  auto take = [&](size_t bytes) -> char* {
    char* p = base + off;
    off += (bytes + 255) & ~(size_t)255;
    return p;
  };
  float*   x     = (float*)  take((size_t)N_BLOCKS * 3 * 4);
  float*   xacc  = (float*)  take((size_t)N_BLOCKS * 3 * 4);
  float*   h     = (float*)  take((size_t)N_BLOCKS * HS * 4);
  float*   agg   = (float*)  take((size_t)N_BLOCKS * HS * 4);
  float*   gsum  = (float*)  take((size_t)N_GRAPHS * HS * 4);
  int*     bstart= (int*)    take((size_t)(N_BLOCKS + 1) * 4);
  int*     hist  = (int*)    take((size_t)N_BLOCKS * 4);
  int*     estart= (int*)    take((size_t)(N_BLOCKS + 1) * 4);
  int*     ecur  = (int*)    take((size_t)N_BLOCKS * 4);
  int*     srow  = (int*)    take((size_t)N_EDGES * 4);
  int*     scol  = (int*)    take((size_t)N_EDGES * 4);
  ushortT* sattr = (ushortT*)take((size_t)N_EDGES * 32 * 2);
  ushortT* Pbf   = (ushortT*)take((size_t)N_BLOCKS * HS * 2);
  ushortT* Qbf   = (ushortT*)take((size_t)N_BLOCKS * HS * 2);
  ushortT* W1atp = (ushortT*)take((size_t)3 * 128 * 128 * 2);
  ushortT* W1btp = (ushortT*)take((size_t)3 * 128 * 128 * 2);
  ushortT* W1ct  = (ushortT*)take((size_t)3 * 128 * 32 * 2);
  ushortT* W2tp  = (ushortT*)take((size_t)3 * 128 * 128 * 2);
  ushortT* CW1tp = (ushortT*)take((size_t)3 * 128 * 128 * 2);
  ushortT* NW1t  = (ushortT*)take((size_t)3 * 128 * 256 * 2);
  ushortT* NW2t  = (ushortT*)take((size_t)3 * 128 * 128 * 2);
  ushortT* Eint  = (ushortT*)take((size_t)128 * 128 * 2);
  ushortT* Eoutt = (ushortT*)take((size_t)128 * 128 * 2);
  float*   b1p   = (float*)  take((size_t)3 * 128 * 4);

  // weight prep
  transpose_cvt_kernel<<<(3*128*128 + 255)/256, 256, 0, stream>>>(edge_w1, W1atp, 273,   0, 128, 128, 128, 3, 1, 0);
  transpose_cvt_kernel<<<(3*128*128 + 255)/256, 256, 0, stream>>>(edge_w1, W1btp, 273, 128, 128, 128, 128, 3, 1, 0);
  transpose_cvt_kernel<<<(3*128*32  + 255)/256, 256, 0, stream>>>(edge_w1, W1ct,  273, 256,  17, 128,  32, 3, 0, 0);
  transpose_cvt_kernel<<<(3*128*128 + 255)/256, 256, 0, stream>>>(edge_w2, W2tp,  128,   0, 128, 128, 128, 3, 0, 1);
  transpose_cvt_kernel<<<(3*128*128 + 255)/256, 256, 0, stream>>>(coord_w1, CW1tp,128,   0, 128, 128, 128, 3, 0, 1);
  transpose_cvt_kernel<<<(3*128*256 + 255)/256, 256, 0, stream>>>(node_w1, NW1t,  256,   0, 256, 128, 256, 3, 0, 0);
  transpose_cvt_kernel<<<(3*128*128 + 255)/256, 256, 0, stream>>>(node_w2, NW2t,  128,   0, 128, 128, 128, 3, 0, 0);
  transpose_cvt_kernel<<<(128*128 + 255)/256, 256, 0, stream>>>(emb_in_w,  Eint,  128,   0, 128, 128, 128, 1, 0, 0);
  transpose_cvt_kernel<<<(128*128 + 255)/256, 256, 0, stream>>>(emb_out_w, Eoutt, 128,   0, 128, 128, 128, 1, 0, 0);
  perm_bias_kernel<<<2, 256, 0, stream>>>(edge_b1, b1p, 3);

  // edge counting-sort by row
  hipMemsetAsync(hist, 0, (size_t)N_BLOCKS * 4, stream);
  hist_kernel<<<N_EDGES / 256, 256, 0, stream>>>(edges, hist);
  scan_kernel<<<1, 256, 0, stream>>>(hist, estart, ecur);
  scatter_kernel<<<N_EDGES / 256, 256, 0, stream>>>(edges, edge_attr, ecur, srow, scol, sattr);

  block_start_kernel<<<(N_BLOCKS + 1 + 255) / 256, 256, 0, stream>>>(block_id, bstart);
  pool_kernel<<<N_BLOCKS, 128, 0, stream>>>(H, Z, bstart, Hm, x);

  // h = Hm @ emb_in_w + b ; P/Q layer 0 ; zero agg/xacc
  gemm_pq_kernel<<<N_BLOCKS / 64, 256, 0, stream>>>(Hm, Eint, emb_in_b, h,
                                                    W1atp, W1btp, b1p, Pbf, Qbf, agg, xacc);

  for (int l = 0; l < 3; l++){
    if (l < 2){
      edge_kernel<1><<<N_EDGES / 64, 256, 0, stream>>>(
          srow, scol, sattr, x, Pbf, Qbf,
          W1ct + (size_t)l * 128 * 32, W2tp + (size_t)l * 128 * 128, CW1tp + (size_t)l * 128 * 128,
          edge_b2 + l * 128, coord_b1 + l * 128, coord_w3 + l * 128,
          xacc, agg);
      node_kernel<true><<<N_BLOCKS / 64, 256, 0, stream>>>(
          h, agg, NW1t + (size_t)l * 128 * 256, NW2t + (size_t)l * 128 * 128,
          node_b1 + l * 128, node_b2 + l * 128,
          W1atp + (size_t)(l + 1) * 128 * 128, W1btp + (size_t)(l + 1) * 128 * 128,
          b1p + (l + 1) * 128, Pbf, Qbf, x, xacc, estart);
    } else {
      edge_kernel<0><<<N_EDGES / 64, 256, 0, stream>>>(
          srow, scol, sattr, x, Pbf, Qbf,
          W1ct + (size_t)l * 128 * 32, W2tp + (size_t)l * 128 * 128, CW1tp + (size_t)l * 128 * 128,
          edge_b2 + l * 128, coord_b1 + l * 128, coord_w3 + l * 128,
          xacc, agg);
      node_kernel<false><<<N_BLOCKS / 64, 256, 0, stream>>>(
          h, agg, NW1t + (size_t)l * 128 * 256, NW2t + (size_t)l * 128 * 128,
          node_b1 + l * 128, node_b2 + l * 128,
          nullptr, nullptr, nullptr, nullptr, nullptr, nullptr, nullptr, nullptr);
    }
  }

  hipMemsetAsync(gsum, 0, (size_t)N_GRAPHS * HS * 4, stream);
  emb_norm_kernel<<<N_BLOCKS / 64, 256, 0, stream>>>(h, Eoutt, emb_out_b, batch_id, brep, gsum);
  norm_graph_kernel<<<N_GRAPHS / 4, 256, 0, stream>>>(gsum, grep);
}